// Round 15
// baseline (346.478 us; speedup 1.0000x reference)
//
#include <hip/hip_runtime.h>
#include <stdint.h>

typedef __bf16 bf16;
typedef __bf16 bf16x8 __attribute__((ext_vector_type(8)));
typedef __bf16 bf16x4 __attribute__((ext_vector_type(4)));
typedef float f32x4 __attribute__((ext_vector_type(4)));

#define DEVFN static __device__ __forceinline__

constexpr int S = 2048, Hdim = 2048, NH = 16, NKV = 4, HD = 128, RHD = 64, QC = 1536, KVC = 512;
constexpr int QKD = HD + RHD;                 // 192
constexpr int DN = 2112;                      // merged down-proj width: QC + KVC + RHD
constexpr float RMS_EPS = 1e-6f;
constexpr float ATT_SCALE = 0.07216878364870323f;  // 1/sqrt(192)

// ---------------- reductions ----------------
DEVFN float wave_sum(float v) {
#pragma unroll
  for (int o = 32; o > 0; o >>= 1) v += __shfl_xor(v, o, 64);
  return v;
}
DEVFN float block_sum(float v) {
  __shared__ float red_s[4];
  v = wave_sum(v);
  int lane = threadIdx.x & 63, wid = threadIdx.x >> 6;
  if (lane == 0) red_s[wid] = v;
  __syncthreads();
  v = red_s[0] + red_s[1] + red_s[2] + red_s[3];
  __syncthreads();
  return v;
}

DEVFN void lgkm_barrier() {
  asm volatile("s_waitcnt lgkmcnt(0)" ::: "memory");
  __builtin_amdgcn_s_barrier();
}

// ---------------- pipelined GEMM core: C = A[M,K] * Bt[N,K]^T ----------------
template <typename OT>
DEVFN void gemm_core_pipe(const bf16* __restrict__ A, const bf16* __restrict__ Bt,
                          OT* __restrict__ C, int N, int lda, int ldb, int ldc,
                          int m0, int n0, float scale, int kend) {
  __shared__ alignas(16) bf16 As[2][128 * 32];
  __shared__ alignas(16) bf16 Bs[2][128 * 32];
  const int t = threadIdx.x;
  const int lane = t & 63;
  const int wm = ((t >> 7) & 1) * 64;
  const int wn = ((t >> 6) & 1) * 64;
  const int lr = lane & 15;
  const int lk = (lane >> 4) * 8;
  const int srow = t >> 2;
  const int scol = (t & 3) * 8;
  const bf16* A0 = A + (size_t)(m0 + srow) * lda + scol;
  const bf16* A1 = A + (size_t)(m0 + 64 + srow) * lda + scol;
  const bf16* B0 = Bt + (size_t)(n0 + srow) * ldb + scol;
  const bf16* B1 = Bt + (size_t)(n0 + 64 + srow) * ldb + scol;

  f32x4 acc[4][4];
#pragma unroll
  for (int i = 0; i < 4; i++)
#pragma unroll
    for (int j = 0; j < 4; j++) { f32x4 z = {0.f, 0.f, 0.f, 0.f}; acc[i][j] = z; }

  bf16x8 ca0 = *reinterpret_cast<const bf16x8*>(A0);
  bf16x8 ca1 = *reinterpret_cast<const bf16x8*>(A1);
  bf16x8 cb0 = *reinterpret_cast<const bf16x8*>(B0);
  bf16x8 cb1 = *reinterpret_cast<const bf16x8*>(B1);
  int cur = 0;
  for (int kk = 0; kk < kend; kk += 32) {
    bf16x8 na0, na1, nb0, nb1;
    if (kk + 32 < kend) {
      na0 = *reinterpret_cast<const bf16x8*>(A0 + kk + 32);
      na1 = *reinterpret_cast<const bf16x8*>(A1 + kk + 32);
      nb0 = *reinterpret_cast<const bf16x8*>(B0 + kk + 32);
      nb1 = *reinterpret_cast<const bf16x8*>(B1 + kk + 32);
    }
    *reinterpret_cast<bf16x8*>(&As[cur][t * 8]) = ca0;
    *reinterpret_cast<bf16x8*>(&As[cur][t * 8 + 2048]) = ca1;
    *reinterpret_cast<bf16x8*>(&Bs[cur][t * 8]) = cb0;
    *reinterpret_cast<bf16x8*>(&Bs[cur][t * 8 + 2048]) = cb1;
    lgkm_barrier();
    bf16x8 a[4], b[4];
#pragma unroll
    for (int i = 0; i < 4; i++)
      a[i] = *reinterpret_cast<const bf16x8*>(&As[cur][(wm + i * 16 + lr) * 32 + lk]);
#pragma unroll
    for (int i = 0; i < 4; i++)
      b[i] = *reinterpret_cast<const bf16x8*>(&Bs[cur][(wn + i * 16 + lr) * 32 + lk]);
    __builtin_amdgcn_s_setprio(1);
#pragma unroll
    for (int i = 0; i < 4; i++)
#pragma unroll
      for (int j = 0; j < 4; j++)
        acc[i][j] = __builtin_amdgcn_mfma_f32_16x16x32_bf16(a[i], b[j], acc[i][j], 0, 0, 0);
    __builtin_amdgcn_s_setprio(0);
    ca0 = na0; ca1 = na1; cb0 = nb0; cb1 = nb1;
    cur ^= 1;
  }
  const int orow = (lane >> 4) * 4;
#pragma unroll
  for (int i = 0; i < 4; i++) {
#pragma unroll
    for (int j = 0; j < 4; j++) {
      int col = n0 + wn + j * 16 + lr;
      if (col < N) {
#pragma unroll
        for (int q = 0; q < 4; q++) {
          int row = m0 + wm + i * 16 + orow + q;
          C[(size_t)row * ldc + col] = (OT)(acc[i][j][q] * scale);
        }
      }
    }
  }
}

template <typename OT>
__global__ __launch_bounds__(256) void gemm_nt(const bf16* __restrict__ A, const bf16* __restrict__ Bt,
                                               OT* __restrict__ C, int N, int K, int lda,
                                               int ldb, int ldc, float scale) {
  gemm_core_pipe<OT>(A, Bt, C, N, lda, ldb, ldc, blockIdx.y * 128, blockIdx.x * 128, scale, K);
}

__global__ __launch_bounds__(256) void gemm_up_both(const bf16* __restrict__ cqb,
                                                    const bf16* __restrict__ ckvb,
                                                    const bf16* __restrict__ wt_up1,
                                                    const bf16* __restrict__ wt_up2,
                                                    bf16* __restrict__ up1,
                                                    bf16* __restrict__ up2) {
  int id = blockIdx.x;
  if (id < 384) {
    gemm_core_pipe<bf16>(cqb, wt_up1, up1, 3072, QC, QC, 3072, (id / 24) * 128, (id % 24) * 128, 1.f, QC);
  } else {
    id -= 384;
    gemm_core_pipe<bf16>(ckvb, wt_up2, up2, 1024, KVC, KVC, 1024, (id / 8) * 128, (id % 8) * 128, 1.f, KVC);
  }
}

// ============== Flash split-K pass A: partial per-row (m, l) ==============
// Grid (16, 2, NH), 512 threads. Block = (strip pair i, k-half). Each block
// processes its half of each strip's BK=64 tile range. Partial (m, l) ->
// stats2[half][h][row]. Ks-only LDS (52 KB) -> 2+ blocks/CU.
__global__ __launch_bounds__(512, 4) void fa_stats(const bf16* __restrict__ qpack,
                                                   const bf16* __restrict__ kpack,
                                                   float* __restrict__ stats2) {
  const int ib = blockIdx.x, half = blockIdx.y, h = blockIdx.z;
  const int g = h >> 2;
  __shared__ alignas(16) bf16 Ks[2][64 * 200];
  __shared__ float2 sb[128];

  const int t = threadIdx.x;
  const int lane = t & 63;
  const int w = t >> 6;
  const int wm = (w & 3) * 16;
  const int kh = w >> 2;
  const int lr = lane & 15;
  const int hi = lane >> 4;
  const int lk = hi * 8;
  const int kr0 = t / 24, kc0 = (t % 24) * 8;
  const int kr1 = (t + 512) / 24, kc1 = ((t + 512) % 24) * 8;
  const int kr2 = (t + 1024) / 24, kc2 = ((t + 1024) % 24) * 8;
  const bf16* Qg = qpack + (size_t)h * S * QKD;
  const bf16* Kg = kpack + (size_t)g * S * QKD;

  for (int sub = 0; sub < 2; ++sub) {
    const int m0 = sub ? (1984 - 64 * ib) : (64 * ib);
    const int ntF = sub ? (32 - ib) : (ib + 1);
    const int n0 = (ntF + 1) >> 1;
    const int t0 = half ? n0 : 0;
    const int t1 = half ? ntF : n0;
    __syncthreads();  // prev sub's sb reads / Ks reads done

    bf16x8 qf[6];
#pragma unroll
    for (int ks = 0; ks < 6; ++ks)
      qf[ks] = *reinterpret_cast<const bf16x8*>(&Qg[(size_t)(m0 + wm + lr) * QKD + ks * 32 + lk]);

    float mreg[4] = {-1e30f, -1e30f, -1e30f, -1e30f};
    float lreg[4] = {0.f, 0.f, 0.f, 0.f};
    if (t0 < t1) {
      bf16x8 ck0 = *reinterpret_cast<const bf16x8*>(&Kg[(size_t)(t0 * 64 + kr0) * QKD + kc0]);
      bf16x8 ck1 = *reinterpret_cast<const bf16x8*>(&Kg[(size_t)(t0 * 64 + kr1) * QKD + kc1]);
      bf16x8 ck2 = *reinterpret_cast<const bf16x8*>(&Kg[(size_t)(t0 * 64 + kr2) * QKD + kc2]);
      int cur = 0;
      for (int ti = t0; ti < t1; ++ti) {
        const int kt = ti * 64;
        bf16x8 nk0, nk1, nk2;
        if (ti + 1 < t1) {
          nk0 = *reinterpret_cast<const bf16x8*>(&Kg[(size_t)(kt + 64 + kr0) * QKD + kc0]);
          nk1 = *reinterpret_cast<const bf16x8*>(&Kg[(size_t)(kt + 64 + kr1) * QKD + kc1]);
          nk2 = *reinterpret_cast<const bf16x8*>(&Kg[(size_t)(kt + 64 + kr2) * QKD + kc2]);
        }
        *reinterpret_cast<bf16x8*>(&Ks[cur][kr0 * 200 + kc0]) = ck0;
        *reinterpret_cast<bf16x8*>(&Ks[cur][kr1 * 200 + kc1]) = ck1;
        *reinterpret_cast<bf16x8*>(&Ks[cur][kr2 * 200 + kc2]) = ck2;
        lgkm_barrier();
        f32x4 acc[2];
#pragma unroll
        for (int kb = 0; kb < 2; kb++) { f32x4 z = {0.f, 0.f, 0.f, 0.f}; acc[kb] = z; }
        __builtin_amdgcn_s_setprio(1);
#pragma unroll
        for (int ks = 0; ks < 6; ++ks) {
#pragma unroll
          for (int kb = 0; kb < 2; ++kb) {
            bf16x8 b = *reinterpret_cast<const bf16x8*>(&Ks[cur][(kh * 32 + kb * 16 + lr) * 200 + ks * 32 + lk]);
            acc[kb] = __builtin_amdgcn_mfma_f32_16x16x32_bf16(qf[ks], b, acc[kb], 0, 0, 0);
          }
        }
        __builtin_amdgcn_s_setprio(0);
        const int colb = kt + kh * 32 + lr;
#pragma unroll
        for (int q = 0; q < 4; ++q) {
          const int rowg = m0 + wm + hi * 4 + q;
          bool u0 = (colb <= rowg), u1 = (colb + 16 <= rowg);
          float s0 = u0 ? acc[0][q] * ATT_SCALE : -1e30f;
          float s1 = u1 ? acc[1][q] * ATT_SCALE : -1e30f;
          float nm = fmaxf(mreg[q], fmaxf(s0, s1));
          float e0 = u0 ? __expf(s0 - nm) : 0.f;
          float e1 = u1 ? __expf(s1 - nm) : 0.f;
          lreg[q] = lreg[q] * __expf(mreg[q] - nm) + e0 + e1;
          mreg[q] = nm;
        }
        ck0 = nk0; ck1 = nk1; ck2 = nk2;
        cur ^= 1;
      }
    }
    // cross-lane merge over lr bits
#pragma unroll
    for (int q = 0; q < 4; ++q) {
      float m = mreg[q], l = lreg[q];
#pragma unroll
      for (int o = 1; o < 16; o <<= 1) {
        float mo = __shfl_xor(m, o, 64);
        float lo = __shfl_xor(l, o, 64);
        float M = fmaxf(m, mo);
        l = l * __expf(m - M) + lo * __expf(mo - M);
        m = M;
      }
      mreg[q] = m; lreg[q] = l;
    }
    __syncthreads();
    if (lr == 0) {
#pragma unroll
      for (int q = 0; q < 4; ++q)
        sb[kh * 64 + wm + hi * 4 + q] = make_float2(mreg[q], lreg[q]);
    }
    __syncthreads();
    if (w < 4 && lr == 0) {
#pragma unroll
      for (int q = 0; q < 4; ++q) {
        int r = wm + hi * 4 + q;
        float2 a = sb[r], b = sb[64 + r];
        float M = fmaxf(a.x, b.x);
        float L = a.y * __expf(a.x - M) + b.y * __expf(b.x - M);
        stats2[(((size_t)half * NH + h) * S + m0 + r) * 2] = M;
        stats2[(((size_t)half * NH + h) * S + m0 + r) * 2 + 1] = L;
      }
    }
  }
}

// ============== Flash split-K pass B: normalize + attn write + partial PV ====
// Grid (16, 2, NH), 512 threads, BK=32. Merges both halves' stats inline,
// recomputes QK for its k-half, writes normalized fp32 attn (disjoint cols),
// deferred-PV single-barrier pipeline, partial O (fp32) -> octx[half].
// LDS 72 KB -> 2 blocks/CU.
__global__ __launch_bounds__(512, 4) void fa_pv(const bf16* __restrict__ qpack,
                                                const bf16* __restrict__ kpack,
                                                const bf16* __restrict__ vt,
                                                const float* __restrict__ stats2,
                                                float* __restrict__ attn,
                                                float* __restrict__ octxA,
                                                float* __restrict__ octxB) {
  const int ib = blockIdx.x, half = blockIdx.y, h = blockIdx.z;
  const int g = h >> 2;
  __shared__ alignas(16) bf16 Ks[2][32 * 200];
  __shared__ alignas(16) bf16 Vs[3][128 * 40];
  __shared__ alignas(16) bf16 Ps[3][64 * 40];

  const int t = threadIdx.x;
  const int lane = t & 63;
  const int w = t >> 6;
  const int wm = (w & 3) * 16;     // row-group
  const int kh = w >> 2;           // 16-col k-half (QK) / 64-d half (PV)
  const int lr = lane & 15;
  const int hi = lane >> 4;
  const int lk = hi * 8;
  // K staging: 32x192 = 768 chunks: c=t (all), c=t+512 (t<256)
  const int kr0 = t / 24, kc0 = (t % 24) * 8;
  const int kr1 = (t + 512) / 24, kc1 = ((t + 512) % 24) * 8;
  // V staging: 128x32 = 512 chunks: one per thread
  const int vr0 = t >> 2, vc0 = (t & 3) * 8;

  const bf16* Qg = qpack + (size_t)h * S * QKD;
  const bf16* Kg = kpack + (size_t)g * S * QKD;
  const bf16* Vg = vt + (size_t)g * HD * S;
  float* Ah = attn + (size_t)h * S * S;
  float* octx = half ? octxB : octxA;

  for (int sub = 0; sub < 2; ++sub) {
    const int m0 = sub ? (1984 - 64 * ib) : (64 * ib);
    const int ntF = sub ? (64 - 2 * ib) : (2 * ib + 2);  // BK=32 tiles
    const int nh = ntF >> 1;
    const int t0 = half * nh, t1 = t0 + nh;              // never empty
    const int kend = m0 + 64;
    __syncthreads();

    bf16x8 qf[6];
#pragma unroll
    for (int ks = 0; ks < 6; ++ks)
      qf[ks] = *reinterpret_cast<const bf16x8*>(&Qg[(size_t)(m0 + wm + lr) * QKD + ks * 32 + lk]);

    // merged global stats
    float mr[4], invl[4];
#pragma unroll
    for (int q = 0; q < 4; ++q) {
      const size_t rowg = (size_t)m0 + wm + hi * 4 + q;
      float2 a = *reinterpret_cast<const float2*>(&stats2[((size_t)h * S + rowg) * 2]);
      float2 b = *reinterpret_cast<const float2*>(&stats2[(((size_t)NH + h) * S + rowg) * 2]);
      float M = fmaxf(a.x, b.x);
      float L = a.y * __expf(a.x - M) + b.y * __expf(b.x - M);
      mr[q] = M; invl[q] = 1.0f / L;
    }

    f32x4 accp[4];
#pragma unroll
    for (int j = 0; j < 4; j++) { f32x4 z = {0.f, 0.f, 0.f, 0.f}; accp[j] = z; }

    bf16x8 ck0 = *reinterpret_cast<const bf16x8*>(&Kg[(size_t)(t0 * 32 + kr0) * QKD + kc0]);
    bf16x8 ck1 = *reinterpret_cast<const bf16x8*>(&Kg[(size_t)(t0 * 32 + kr1) * QKD + kc1]);
    bf16x8 cv0 = *reinterpret_cast<const bf16x8*>(&Vg[(size_t)vr0 * S + t0 * 32 + vc0]);
    int cur = 0, pb = 0;
    for (int ti = t0; ti < t1; ++ti) {
      const int kt = ti * 32;
      bf16x8 nk0, nk1, nv0;
      if (ti + 1 < t1) {
        nk0 = *reinterpret_cast<const bf16x8*>(&Kg[(size_t)(kt + 32 + kr0) * QKD + kc0]);
        nk1 = *reinterpret_cast<const bf16x8*>(&Kg[(size_t)(kt + 32 + kr1) * QKD + kc1]);
        nv0 = *reinterpret_cast<const bf16x8*>(&Vg[(size_t)vr0 * S + kt + 32 + vc0]);
      }
      *reinterpret_cast<bf16x8*>(&Ks[cur][kr0 * 200 + kc0]) = ck0;
      if (t < 256)
        *reinterpret_cast<bf16x8*>(&Ks[cur][kr1 * 200 + kc1]) = ck1;
      *reinterpret_cast<bf16x8*>(&Vs[pb][vr0 * 40 + vc0]) = cv0;
      lgkm_barrier();  // K, V(pb), Ps(prev) visible
      f32x4 acc = {0.f, 0.f, 0.f, 0.f};
      __builtin_amdgcn_s_setprio(1);
#pragma unroll
      for (int ks = 0; ks < 6; ++ks) {
        bf16x8 b = *reinterpret_cast<const bf16x8*>(&Ks[cur][(kh * 16 + lr) * 200 + ks * 32 + lk]);
        acc = __builtin_amdgcn_mfma_f32_16x16x32_bf16(qf[ks], b, acc, 0, 0, 0);
      }
      __builtin_amdgcn_s_setprio(0);
      const int col = kt + kh * 16 + lr;
#pragma unroll
      for (int q = 0; q < 4; ++q) {
        const int rloc = wm + hi * 4 + q;
        const int rowg = m0 + rloc;
        float s = acc[q] * ATT_SCALE;
        float p = (col <= rowg) ? __expf(s - mr[q]) * invl[q] : 0.f;
        Ah[(size_t)rowg * S + col] = p;
        Ps[pb][rloc * 40 + kh * 16 + lr] = (bf16)p;
      }
      if (ti > t0) {  // deferred PV for tile ti-1
        const int pp = (pb == 0) ? 2 : pb - 1;
        __builtin_amdgcn_s_setprio(1);
        bf16x8 a = *reinterpret_cast<const bf16x8*>(&Ps[pp][(wm + lr) * 40 + lk]);
#pragma unroll
        for (int j = 0; j < 4; ++j) {
          bf16x8 b = *reinterpret_cast<const bf16x8*>(&Vs[pp][(kh * 64 + j * 16 + lr) * 40 + lk]);
          accp[j] = __builtin_amdgcn_mfma_f32_16x16x32_bf16(a, b, accp[j], 0, 0, 0);
        }
        __builtin_amdgcn_s_setprio(0);
      }
      ck0 = nk0; ck1 = nk1; cv0 = nv0;
      cur ^= 1;
      pb = (pb == 2) ? 0 : pb + 1;
    }
    // final PV
    lgkm_barrier();
    {
      const int pp = (pb == 0) ? 2 : pb - 1;
      bf16x8 a = *reinterpret_cast<const bf16x8*>(&Ps[pp][(wm + lr) * 40 + lk]);
#pragma unroll
      for (int j = 0; j < 4; ++j) {
        bf16x8 b = *reinterpret_cast<const bf16x8*>(&Vs[pp][(kh * 64 + j * 16 + lr) * 40 + lk]);
        accp[j] = __builtin_amdgcn_mfma_f32_16x16x32_bf16(a, b, accp[j], 0, 0, 0);
      }
    }

    // zero-fill causal tail (half 1 only)
    if (half == 1) {
      const float4 zz = make_float4(0.f, 0.f, 0.f, 0.f);
      const int zr = t >> 3, zc0 = (t & 7) * 4;
      float* zrow = Ah + (size_t)(m0 + zr) * S;
      for (int k = kend + zc0; k < S; k += 32) *reinterpret_cast<float4*>(zrow + k) = zz;
    }

    // partial O (fp32), layout [s][h*HD+d] to match ctxb
#pragma unroll
    for (int j = 0; j < 4; ++j) {
      const int d = kh * 64 + j * 16 + lr;
#pragma unroll
      for (int q = 0; q < 4; ++q) {
        const int rowg = m0 + wm + hi * 4 + q;
        octx[(size_t)rowg * Hdim + h * HD + d] = accp[j][q];
      }
    }
  }
}

// combine: ctxb = bf16(octxA + octxB), linear over S*Hdim
__global__ __launch_bounds__(256) void combine_ctx(const float* __restrict__ a,
                                                   const float* __restrict__ b,
                                                   bf16* __restrict__ ctxb) {
  size_t i = ((size_t)blockIdx.x * 256 + threadIdx.x) * 8;
  float4 a0 = *reinterpret_cast<const float4*>(a + i);
  float4 a1 = *reinterpret_cast<const float4*>(a + i + 4);
  float4 b0 = *reinterpret_cast<const float4*>(b + i);
  float4 b1 = *reinterpret_cast<const float4*>(b + i + 4);
  bf16x8 o;
  o[0] = (bf16)(a0.x + b0.x); o[1] = (bf16)(a0.y + b0.y);
  o[2] = (bf16)(a0.z + b0.z); o[3] = (bf16)(a0.w + b0.w);
  o[4] = (bf16)(a1.x + b1.x); o[5] = (bf16)(a1.y + b1.y);
  o[6] = (bf16)(a1.z + b1.z); o[7] = (bf16)(a1.w + b1.w);
  *reinterpret_cast<bf16x8*>(ctxb + i) = o;
}

// ---------------- fused prep: X cast + 8 weight transposes ----------------
struct TJobs {
  const float* src[8];
  bf16* dst[8];
  int R[8], C[8], tiles[8];
};

__global__ __launch_bounds__(256) void prep(const float* __restrict__ Xf,
                                            bf16* __restrict__ Xb, TJobs J) {
  const int t = threadIdx.x;
  int id = blockIdx.x;
  if (id < 2048) {
    size_t i = (size_t)id * 256 + t;
    float4 f0 = *reinterpret_cast<const float4*>(Xf + i * 8);
    float4 f1 = *reinterpret_cast<const float4*>(Xf + i * 8 + 4);
    bf16x8 v;
    v[0] = (bf16)f0.x; v[1] = (bf16)f0.y; v[2] = (bf16)f0.z; v[3] = (bf16)f0.w;
    v[4] = (bf16)f1.x; v[5] = (bf16)f1.y; v[6] = (bf16)f1.z; v[7] = (bf16)f1.w;
    *reinterpret_cast<bf16x8*>(Xb + i * 8) = v;
    return;
  }
  int tile = id - 2048;
  int j = 0;
  while (tile >= J.tiles[j]) { tile -= J.tiles[j]; ++j; }
  const int C = J.C[j], R = J.R[j];
  int tcn = C >> 5;
  int rb = (tile / tcn) * 32, cb = (tile % tcn) * 32;
  const float* in = J.src[j];
  bf16* out = J.dst[j];
  __shared__ float tl[32][33];
  int tx = t & 31, ty = t >> 5;
#pragma unroll
  for (int q = 0; q < 32; q += 8)
    tl[ty + q][tx] = in[(size_t)(rb + ty + q) * C + cb + tx];
  __syncthreads();
#pragma unroll
  for (int q = 0; q < 32; q += 8)
    out[(size_t)(cb + ty + q) * R + rb + tx] = (bf16)tl[tx][ty + q];
}

// fused RMSNorm for cq (y==0) and ckv (y==1) reading merged dproj
__global__ __launch_bounds__(256) void rmsnorm_fused(const float* __restrict__ dproj,
                                                     const float* __restrict__ qw,
                                                     const float* __restrict__ kw,
                                                     bf16* __restrict__ cqb,
                                                     bf16* __restrict__ ckvb) {
  int row = blockIdx.x;
  bool isq = (blockIdx.y == 0);
  int C = isq ? QC : KVC;
  const float* p = dproj + (size_t)row * DN + (isq ? 0 : QC);
  const float* w = isq ? qw : kw;
  bf16* out = (isq ? cqb : ckvb) + (size_t)row * C;
  float ss = 0.f;
  for (int i = threadIdx.x * 4; i < C; i += 1024) {
    float4 v = *reinterpret_cast<const float4*>(p + i);
    ss += v.x * v.x + v.y * v.y + v.z * v.z + v.w * v.w;
  }
  ss = block_sum(ss);
  float r = rsqrtf(ss / (float)C + RMS_EPS);
  for (int i = threadIdx.x * 4; i < C; i += 1024) {
    float4 v = *reinterpret_cast<const float4*>(p + i);
    float4 g = *reinterpret_cast<const float4*>(w + i);
    bf16x4 o;
    o[0] = (bf16)(v.x * r * g.x); o[1] = (bf16)(v.y * r * g.y);
    o[2] = (bf16)(v.z * r * g.z); o[3] = (bf16)(v.w * r * g.w);
    *reinterpret_cast<bf16x4*>(out + i) = o;
  }
}

// ---------------- fused pack: qpack + kpack + V transpose ----------------
__global__ __launch_bounds__(256) void pack_all(const bf16* __restrict__ up1,
                                                const bf16* __restrict__ up2,
                                                const float* __restrict__ dproj,
                                                const float* __restrict__ cosp,
                                                const float* __restrict__ sinp,
                                                bf16* __restrict__ qpack,
                                                bf16* __restrict__ kpack,
                                                bf16* __restrict__ vt) {
  const int t = threadIdx.x;
  int id = blockIdx.x;
  if (id < 3072) {  // ---- qpack ----
    int idx = id * 256 + t;
    const int P = NH * S * 16;
    if (idx < P) {
      int d8 = idx & 15, s = (idx >> 4) & (S - 1), h = idx >> 15;
      int4 v = *reinterpret_cast<const int4*>(up1 + (size_t)s * 3072 + h * HD + d8 * 8);
      *reinterpret_cast<int4*>(qpack + ((size_t)h * S + s) * QKD + d8 * 8) = v;
    } else {
      int j = idx - P;
      int d0 = (j & 7) * 8, s = (j >> 3) & (S - 1), h = j >> 14;
      const bf16* xr = up1 + (size_t)s * 3072 + 2048 + h * RHD;
      bf16x8 xa = *reinterpret_cast<const bf16x8*>(xr + d0);
      bf16x8 xb = *reinterpret_cast<const bf16x8*>(xr + (d0 ^ 32));
      float sign = (d0 < 32) ? -1.f : 1.f;
      const float* cr = cosp + s * RHD + d0;
      const float* sr = sinp + s * RHD + d0;
      bf16x8 o;
#pragma unroll
      for (int i = 0; i < 8; i++)
        o[i] = (bf16)((float)xa[i] * cr[i] + sign * (float)xb[i] * sr[i]);
      *reinterpret_cast<bf16x8*>(qpack + ((size_t)h * S + s) * QKD + HD + d0) = o;
    }
    return;
  }
  if (id < 3648) {  // ---- kpack ----
    int idx = (id - 3072) * 256 + t;
    const int P = NKV * S * 16;
    if (idx < P) {
      int d8 = idx & 15, s = (idx >> 4) & (S - 1), g = idx >> 15;
      int4 v = *reinterpret_cast<const int4*>(up2 + (size_t)s * 1024 + g * HD + d8 * 8);
      *reinterpret_cast<int4*>(kpack + ((size_t)g * S + s) * QKD + d8 * 8) = v;
    } else {
      int j = idx - P;
      int d0 = (j & 7) * 8, s = j >> 3;
      const float* xr = dproj + (size_t)s * DN + 2048;
      float4 a0 = *reinterpret_cast<const float4*>(xr + d0);
      float4 a1 = *reinterpret_cast<const float4*>(xr + d0 + 4);
      float4 b0 = *reinterpret_cast<const float4*>(xr + (d0 ^ 32));
      float4 b1 = *reinterpret_cast<const float4*>(xr + (d0 ^ 32) + 4);
      float sign = (d0 < 32) ? -1.f : 1.f;
      const float* cr = cosp + s * RHD + d0;
      const float* sr = sinp + s * RHD + d0;
      float xa[8] = {a0.x, a0.y, a0.z, a0.w, a1.x, a1.y, a1.z, a1.w};
      float xb[8] = {b0.x, b0.y, b0.z, b0.w, b1.x, b1.y, b1.z, b1.w};
      bf16x8 o;
#pragma unroll
      for (int i = 0; i < 8; i++)
        o[i] = (bf16)(xa[i] * cr[i] + sign * xb[i] * sr[i]);
#pragma unroll
      for (int g = 0; g < NKV; g++)
        *reinterpret_cast<bf16x8*>(kpack + ((size_t)g * S + s) * QKD + HD + d0) = o;
    }
    return;
  }
  // ---- V transpose: up2[s][512+c] -> vt[c][s] ----
  int tile = id - 3648;
  int cb = (tile & 15) * 32;
  int rb = (tile >> 4) * 32;
  __shared__ float tl[32][33];
  int tx = t & 31, ty = t >> 5;
  const bf16* in = up2 + 512;
#pragma unroll
  for (int q = 0; q < 32; q += 8)
    tl[ty + q][tx] = (float)in[(size_t)(rb + ty + q) * 1024 + cb + tx];
  __syncthreads();
#pragma unroll
  for (int q = 0; q < 32; q += 8)
    vt[(size_t)(cb + ty + q) * S + rb + tx] = (bf16)tl[tx][ty + q];
}

// ---------------- launcher ----------------
extern "C" void kernel_launch(void* const* d_in, const int* in_sizes, int n_in, void* d_out,
                              int out_size, void* d_ws, size_t ws_size, hipStream_t stream) {
  const float* Xf = (const float*)d_in[0];
  const float* cosp = (const float*)d_in[1];
  const float* sinp = (const float*)d_in[2];
  const float* w_down_q = (const float*)d_in[4];
  const float* w_up_q = (const float*)d_in[5];
  const float* w_qr = (const float*)d_in[6];
  const float* w_down_kv = (const float*)d_in[7];
  const float* w_up_k = (const float*)d_in[8];
  const float* w_up_v = (const float*)d_in[9];
  const float* w_kr = (const float*)d_in[10];
  const float* w_o = (const float*)d_in[11];
  const float* q_norm_w = (const float*)d_in[12];
  const float* k_norm_w = (const float*)d_in[13];

  float* out0 = (float*)d_out;
  float* attn = out0 + (size_t)S * Hdim;

  char* base = (char*)d_ws;
  size_t off = 0;
  auto carve = [&](size_t bytes) -> void* {
    void* p = base + off;
    off += (bytes + 255) & ~(size_t)255;
    return p;
  };
  bf16* Xb      = (bf16*)carve((size_t)S * Hdim * 2);
  bf16* wt_down = (bf16*)carve((size_t)2176 * 2048 * 2);
  bf16* wt_up1  = (bf16*)carve((size_t)3072 * QC * 2);
  bf16* wt_up2  = (bf16*)carve((size_t)1024 * KVC * 2);
  bf16* wt_o    = (bf16*)carve((size_t)Hdim * Hdim * 2);
  float* dproj  = (float*)carve((size_t)S * DN * 4);
  bf16* cqb     = (bf16*)carve((size_t)S * QC * 2);
  bf16* ckvb    = (bf16*)carve((size_t)S * KVC * 2);
  bf16* up1     = (bf16*)carve((size_t)S * 3072 * 2);
  bf16* up2     = (bf16*)carve((size_t)S * 1024 * 2);
  bf16* qpack   = (bf16*)carve((size_t)NH * S * QKD * 2);
  bf16* kpack   = (bf16*)carve((size_t)NKV * S * QKD * 2);
  bf16* vt      = (bf16*)carve((size_t)NKV * HD * S * 2);
  bf16* ctxb    = (bf16*)carve((size_t)S * Hdim * 2);
  float* stats2 = (float*)carve((size_t)2 * NH * S * 2 * 4);
  float* octxA  = (float*)carve((size_t)S * Hdim * 4);
  float* octxB  = (float*)carve((size_t)S * Hdim * 4);
  (void)in_sizes; (void)n_in; (void)out_size; (void)ws_size;

  TJobs J;
  const float* srcs[8] = {w_down_q, w_down_kv, w_kr, w_up_q, w_qr, w_up_k, w_up_v, w_o};
  bf16* dsts[8] = {wt_down, wt_down + (size_t)QC * 2048, wt_down + (size_t)2048 * 2048,
                   wt_up1, wt_up1 + (size_t)2048 * QC, wt_up2, wt_up2 + (size_t)512 * KVC, wt_o};
  int Rs[8] = {2048, 2048, 2048, 1536, 1536, 512, 512, 2048};
  int Cs[8] = {1536, 512, 64, 2048, 1024, 512, 512, 2048};
  int total_tiles = 0;
  for (int j = 0; j < 8; j++) {
    J.src[j] = srcs[j]; J.dst[j] = dsts[j]; J.R[j] = Rs[j]; J.C[j] = Cs[j];
    J.tiles[j] = (Rs[j] / 32) * (Cs[j] / 32);
    total_tiles += J.tiles[j];
  }

  // 1. prep: X cast + all weight transposes
  prep<<<2048 + total_tiles, 256, 0, stream>>>(Xf, Xb, J);
  // 2. merged down projection
  gemm_nt<float><<<dim3(17, 16), 256, 0, stream>>>(Xb, wt_down, dproj, DN, Hdim, Hdim, Hdim, DN, 1.f);
  // 3. both RMSNorms
  rmsnorm_fused<<<dim3(S, 2), 256, 0, stream>>>(dproj, q_norm_w, k_norm_w, cqb, ckvb);
  // 4. both up projections
  gemm_up_both<<<512, 256, 0, stream>>>(cqb, ckvb, wt_up1, wt_up2, up1, up2);
  // 5. pack q/k + RoPE + V transpose
  pack_all<<<4672, 256, 0, stream>>>(up1, up2, dproj, cosp, sinp, qpack, kpack, vt);
  // 6. flash split-K: partial stats -> normalize+attn+partial PV -> combine
  fa_stats<<<dim3(16, 2, NH), 512, 0, stream>>>(qpack, kpack, stats2);
  fa_pv<<<dim3(16, 2, NH), 512, 0, stream>>>(qpack, kpack, vt, stats2, attn, octxA, octxB);
  combine_ctx<<<S * Hdim / 8 / 256, 256, 0, stream>>>(octxA, octxB, ctxb);
  // 7. output projection
  gemm_nt<float><<<dim3(16, 16), 256, 0, stream>>>(ctxb, wt_o, out0, Hdim, Hdim, Hdim, Hdim, Hdim, 1.f);
}

// Round 16
// 328.583 us; speedup vs baseline: 1.0545x; 1.0545x over previous
//
#include <hip/hip_runtime.h>
#include <stdint.h>

typedef __bf16 bf16;
typedef __bf16 bf16x8 __attribute__((ext_vector_type(8)));
typedef __bf16 bf16x4 __attribute__((ext_vector_type(4)));
typedef float f32x4 __attribute__((ext_vector_type(4)));

#define DEVFN static __device__ __forceinline__

constexpr int S = 2048, Hdim = 2048, NH = 16, NKV = 4, HD = 128, RHD = 64, QC = 1536, KVC = 512;
constexpr int QKD = HD + RHD;                 // 192
constexpr int DN = 2112;                      // merged down-proj width: QC + KVC + RHD
constexpr float RMS_EPS = 1e-6f;
constexpr float ATT_SCALE = 0.07216878364870323f;  // 1/sqrt(192)

// ---------------- reductions ----------------
DEVFN float wave_sum(float v) {
#pragma unroll
  for (int o = 32; o > 0; o >>= 1) v += __shfl_xor(v, o, 64);
  return v;
}
DEVFN float block_sum(float v) {
  __shared__ float red_s[4];
  v = wave_sum(v);
  int lane = threadIdx.x & 63, wid = threadIdx.x >> 6;
  if (lane == 0) red_s[wid] = v;
  __syncthreads();
  v = red_s[0] + red_s[1] + red_s[2] + red_s[3];
  __syncthreads();
  return v;
}

DEVFN void lgkm_barrier() {
  asm volatile("s_waitcnt lgkmcnt(0)" ::: "memory");
  __builtin_amdgcn_s_barrier();
}

// load 8 elems as bf16x8, converting from fp32 if needed
template <typename T>
DEVFN bf16x8 ld8cvt(const T* p) {
  if constexpr (sizeof(T) == 2) {
    return *reinterpret_cast<const bf16x8*>(p);
  } else {
    float4 f0 = *reinterpret_cast<const float4*>(p);
    float4 f1 = *reinterpret_cast<const float4*>(p + 4);
    bf16x8 v;
    v[0] = (bf16)f0.x; v[1] = (bf16)f0.y; v[2] = (bf16)f0.z; v[3] = (bf16)f0.w;
    v[4] = (bf16)f1.x; v[5] = (bf16)f1.y; v[6] = (bf16)f1.z; v[7] = (bf16)f1.w;
    return v;
  }
}

// ---------------- pipelined GEMM core: C = A[M,K] * Bt[N,K]^T ----------------
// 128x128 tile, BK=32, 4 waves 2x2. Reg-staged double-buffered staging:
// next K-step's global loads issue BEFORE this step's ds_writes; ONE
// lgkm-only barrier per step. A may be fp32 (converted during staging).
template <typename AT, typename OT>
DEVFN void gemm_core_pipe(const AT* __restrict__ A, const bf16* __restrict__ Bt,
                          OT* __restrict__ C, int N, int lda, int ldb, int ldc,
                          int m0, int n0, float scale, int kend) {
  __shared__ alignas(16) bf16 As[2][128 * 32];
  __shared__ alignas(16) bf16 Bs[2][128 * 32];
  const int t = threadIdx.x;
  const int lane = t & 63;
  const int wm = ((t >> 7) & 1) * 64;
  const int wn = ((t >> 6) & 1) * 64;
  const int lr = lane & 15;
  const int lk = (lane >> 4) * 8;
  const int srow = t >> 2;
  const int scol = (t & 3) * 8;
  const AT* A0 = A + (size_t)(m0 + srow) * lda + scol;
  const AT* A1 = A + (size_t)(m0 + 64 + srow) * lda + scol;
  const bf16* B0 = Bt + (size_t)(n0 + srow) * ldb + scol;
  const bf16* B1 = Bt + (size_t)(n0 + 64 + srow) * ldb + scol;

  f32x4 acc[4][4];
#pragma unroll
  for (int i = 0; i < 4; i++)
#pragma unroll
    for (int j = 0; j < 4; j++) { f32x4 z = {0.f, 0.f, 0.f, 0.f}; acc[i][j] = z; }

  bf16x8 ca0 = ld8cvt(A0);
  bf16x8 ca1 = ld8cvt(A1);
  bf16x8 cb0 = ld8cvt(B0);
  bf16x8 cb1 = ld8cvt(B1);
  int cur = 0;
  for (int kk = 0; kk < kend; kk += 32) {
    bf16x8 na0, na1, nb0, nb1;
    if (kk + 32 < kend) {
      na0 = ld8cvt(A0 + kk + 32);
      na1 = ld8cvt(A1 + kk + 32);
      nb0 = ld8cvt(B0 + kk + 32);
      nb1 = ld8cvt(B1 + kk + 32);
    }
    *reinterpret_cast<bf16x8*>(&As[cur][t * 8]) = ca0;
    *reinterpret_cast<bf16x8*>(&As[cur][t * 8 + 2048]) = ca1;
    *reinterpret_cast<bf16x8*>(&Bs[cur][t * 8]) = cb0;
    *reinterpret_cast<bf16x8*>(&Bs[cur][t * 8 + 2048]) = cb1;
    lgkm_barrier();
    bf16x8 a[4], b[4];
#pragma unroll
    for (int i = 0; i < 4; i++)
      a[i] = *reinterpret_cast<const bf16x8*>(&As[cur][(wm + i * 16 + lr) * 32 + lk]);
#pragma unroll
    for (int i = 0; i < 4; i++)
      b[i] = *reinterpret_cast<const bf16x8*>(&Bs[cur][(wn + i * 16 + lr) * 32 + lk]);
    __builtin_amdgcn_s_setprio(1);
#pragma unroll
    for (int i = 0; i < 4; i++)
#pragma unroll
      for (int j = 0; j < 4; j++)
        acc[i][j] = __builtin_amdgcn_mfma_f32_16x16x32_bf16(a[i], b[j], acc[i][j], 0, 0, 0);
    __builtin_amdgcn_s_setprio(0);
    ca0 = na0; ca1 = na1; cb0 = nb0; cb1 = nb1;
    cur ^= 1;
  }
  const int orow = (lane >> 4) * 4;
#pragma unroll
  for (int i = 0; i < 4; i++) {
#pragma unroll
    for (int j = 0; j < 4; j++) {
      int col = n0 + wn + j * 16 + lr;
      if (col < N) {
#pragma unroll
        for (int q = 0; q < 4; q++) {
          int row = m0 + wm + i * 16 + orow + q;
          C[(size_t)row * ldc + col] = (OT)(acc[i][j][q] * scale);
        }
      }
    }
  }
}

template <typename AT, typename OT>
__global__ __launch_bounds__(256) void gemm_nt(const AT* __restrict__ A, const bf16* __restrict__ Bt,
                                               OT* __restrict__ C, int N, int K, int lda,
                                               int ldb, int ldc, float scale) {
  gemm_core_pipe<AT, OT>(A, Bt, C, N, lda, ldb, ldc, blockIdx.y * 128, blockIdx.x * 128, scale, K);
}

// up1 (384 blocks) + up2 (128 blocks) in one launch
__global__ __launch_bounds__(256) void gemm_up_both(const bf16* __restrict__ cqb,
                                                    const bf16* __restrict__ ckvb,
                                                    const bf16* __restrict__ wt_up1,
                                                    const bf16* __restrict__ wt_up2,
                                                    bf16* __restrict__ up1,
                                                    bf16* __restrict__ up2) {
  int id = blockIdx.x;
  if (id < 384) {
    gemm_core_pipe<bf16, bf16>(cqb, wt_up1, up1, 3072, QC, QC, 3072, (id / 24) * 128, (id % 24) * 128, 1.f, QC);
  } else {
    id -= 384;
    gemm_core_pipe<bf16, bf16>(ckvb, wt_up2, up2, 1024, KVC, KVC, 1024, (id / 8) * 128, (id % 8) * 128, 1.f, KVC);
  }
}

// ============== Fused flash attention, deep-pipelined (round-13 proven) =====
// Grid (16, NH), 512 threads (8 waves: 4 row-groups x 2 k-halves).
// Block = balanced strip pair (64*i rows and 1984-64*i), 33 k-tiles total.
// Q fragments in REGISTERS; K double-buffered, V/Ps TRIPLE-buffered;
// reg-staged async split; deferred PV -> ONE lgkm barrier per tile.
__global__ __launch_bounds__(512) void fa_fused(const bf16* __restrict__ qpack,
                                                const bf16* __restrict__ kpack,
                                                const bf16* __restrict__ vt,
                                                float* __restrict__ attn,
                                                bf16* __restrict__ ctxb) {
  const int h = blockIdx.y;
  const int g = h >> 2;
  __shared__ alignas(16) bf16 Ks[2][64 * 200];
  __shared__ alignas(16) bf16 Vs[3][128 * 72];
  __shared__ alignas(16) bf16 Ps[3][64 * 72];
  float2* sb = reinterpret_cast<float2*>(&Vs[0][0]);   // [0..127] per-half merge
  float2* statf = sb + 128;                            // [0..63] final (m, 1/l)

  const int t = threadIdx.x;
  const int lane = t & 63;
  const int w = t >> 6;
  const int wm = (w & 3) * 16;
  const int kh = w >> 2;
  const int lr = lane & 15;
  const int hi = lane >> 4;
  const int lk = hi * 8;
  const int kr0 = t / 24, kc0 = (t % 24) * 8;
  const int kr1 = (t + 512) / 24, kc1 = ((t + 512) % 24) * 8;
  const int kr2 = (t + 1024) / 24, kc2 = ((t + 1024) % 24) * 8;
  const int vr0 = t >> 3, vc0 = (t & 7) * 8;
  const int vr1 = (t + 512) >> 3, vc1 = ((t + 512) & 7) * 8;

  const bf16* Qg = qpack + (size_t)h * S * QKD;
  const bf16* Kg = kpack + (size_t)g * S * QKD;
  const bf16* Vg = vt + (size_t)g * HD * S;
  float* Ah = attn + (size_t)h * S * S;
  bf16* C = ctxb + h * HD;

  for (int sub = 0; sub < 2; ++sub) {
    const int m0 = sub ? (1984 - 64 * blockIdx.x) : (64 * blockIdx.x);
    const int ntiles = sub ? (32 - blockIdx.x) : (blockIdx.x + 1);
    const int kend = m0 + 64;
    __syncthreads();

    bf16x8 qf[6];
#pragma unroll
    for (int ks = 0; ks < 6; ++ks)
      qf[ks] = *reinterpret_cast<const bf16x8*>(&Qg[(size_t)(m0 + wm + lr) * QKD + ks * 32 + lk]);

    // ---------- loop 1: stats ----------
    float mreg[4] = {-1e30f, -1e30f, -1e30f, -1e30f};
    float lreg[4] = {0.f, 0.f, 0.f, 0.f};
    bf16x8 ck0 = *reinterpret_cast<const bf16x8*>(&Kg[(size_t)kr0 * QKD + kc0]);
    bf16x8 ck1 = *reinterpret_cast<const bf16x8*>(&Kg[(size_t)kr1 * QKD + kc1]);
    bf16x8 ck2 = *reinterpret_cast<const bf16x8*>(&Kg[(size_t)kr2 * QKD + kc2]);
    int cur = 0;
    for (int ti = 0; ti < ntiles; ++ti) {
      const int kt = ti * 64;
      bf16x8 nk0, nk1, nk2;
      if (ti + 1 < ntiles) {
        nk0 = *reinterpret_cast<const bf16x8*>(&Kg[(size_t)(kt + 64 + kr0) * QKD + kc0]);
        nk1 = *reinterpret_cast<const bf16x8*>(&Kg[(size_t)(kt + 64 + kr1) * QKD + kc1]);
        nk2 = *reinterpret_cast<const bf16x8*>(&Kg[(size_t)(kt + 64 + kr2) * QKD + kc2]);
      }
      *reinterpret_cast<bf16x8*>(&Ks[cur][kr0 * 200 + kc0]) = ck0;
      *reinterpret_cast<bf16x8*>(&Ks[cur][kr1 * 200 + kc1]) = ck1;
      *reinterpret_cast<bf16x8*>(&Ks[cur][kr2 * 200 + kc2]) = ck2;
      lgkm_barrier();
      f32x4 acc[2];
#pragma unroll
      for (int kb = 0; kb < 2; kb++) { f32x4 z = {0.f, 0.f, 0.f, 0.f}; acc[kb] = z; }
      __builtin_amdgcn_s_setprio(1);
#pragma unroll
      for (int ks = 0; ks < 6; ++ks) {
#pragma unroll
        for (int kb = 0; kb < 2; ++kb) {
          bf16x8 b = *reinterpret_cast<const bf16x8*>(&Ks[cur][(kh * 32 + kb * 16 + lr) * 200 + ks * 32 + lk]);
          acc[kb] = __builtin_amdgcn_mfma_f32_16x16x32_bf16(qf[ks], b, acc[kb], 0, 0, 0);
        }
      }
      __builtin_amdgcn_s_setprio(0);
      const int colb = kt + kh * 32 + lr;
#pragma unroll
      for (int q = 0; q < 4; ++q) {
        const int rowg = m0 + wm + hi * 4 + q;
        bool u0 = (colb <= rowg), u1 = (colb + 16 <= rowg);
        float s0 = u0 ? acc[0][q] * ATT_SCALE : -1e30f;
        float s1 = u1 ? acc[1][q] * ATT_SCALE : -1e30f;
        float nm = fmaxf(mreg[q], fmaxf(s0, s1));
        float e0 = u0 ? __expf(s0 - nm) : 0.f;
        float e1 = u1 ? __expf(s1 - nm) : 0.f;
        lreg[q] = lreg[q] * __expf(mreg[q] - nm) + e0 + e1;
        mreg[q] = nm;
      }
      ck0 = nk0; ck1 = nk1; ck2 = nk2;
      cur ^= 1;
    }
#pragma unroll
    for (int q = 0; q < 4; ++q) {
      float m = mreg[q], l = lreg[q];
#pragma unroll
      for (int o = 1; o < 16; o <<= 1) {
        float mo = __shfl_xor(m, o, 64);
        float lo = __shfl_xor(l, o, 64);
        float M = fmaxf(m, mo);
        l = l * __expf(m - M) + lo * __expf(mo - M);
        m = M;
      }
      mreg[q] = m; lreg[q] = l;
    }
    __syncthreads();
    if (lr == 0) {
#pragma unroll
      for (int q = 0; q < 4; ++q)
        sb[kh * 64 + wm + hi * 4 + q] = make_float2(mreg[q], lreg[q]);
    }
    __syncthreads();
    if (w < 4 && lr == 0) {
#pragma unroll
      for (int q = 0; q < 4; ++q) {
        int r = wm + hi * 4 + q;
        float2 a = sb[r], b = sb[64 + r];
        float M = fmaxf(a.x, b.x);
        float L = a.y * __expf(a.x - M) + b.y * __expf(b.x - M);
        statf[r] = make_float2(M, 1.0f / L);
      }
    }
    __syncthreads();
    float mr[4], invl[4];
#pragma unroll
    for (int q = 0; q < 4; ++q) {
      float2 sv = statf[wm + hi * 4 + q];
      mr[q] = sv.x; invl[q] = sv.y;
    }
    __syncthreads();

    // ---------- loop 2: normalize + attn write + deferred PV ----------
    f32x4 accp[4];
#pragma unroll
    for (int j = 0; j < 4; j++) { f32x4 z = {0.f, 0.f, 0.f, 0.f}; accp[j] = z; }
    ck0 = *reinterpret_cast<const bf16x8*>(&Kg[(size_t)kr0 * QKD + kc0]);
    ck1 = *reinterpret_cast<const bf16x8*>(&Kg[(size_t)kr1 * QKD + kc1]);
    ck2 = *reinterpret_cast<const bf16x8*>(&Kg[(size_t)kr2 * QKD + kc2]);
    bf16x8 cv0 = *reinterpret_cast<const bf16x8*>(&Vg[(size_t)vr0 * S + vc0]);
    bf16x8 cv1 = *reinterpret_cast<const bf16x8*>(&Vg[(size_t)vr1 * S + vc1]);
    cur = 0;
    int pb = 0;
    for (int ti = 0; ti < ntiles; ++ti) {
      const int kt = ti * 64;
      bf16x8 nk0, nk1, nk2, nv0, nv1;
      if (ti + 1 < ntiles) {
        nk0 = *reinterpret_cast<const bf16x8*>(&Kg[(size_t)(kt + 64 + kr0) * QKD + kc0]);
        nk1 = *reinterpret_cast<const bf16x8*>(&Kg[(size_t)(kt + 64 + kr1) * QKD + kc1]);
        nk2 = *reinterpret_cast<const bf16x8*>(&Kg[(size_t)(kt + 64 + kr2) * QKD + kc2]);
        nv0 = *reinterpret_cast<const bf16x8*>(&Vg[(size_t)vr0 * S + kt + 64 + vc0]);
        nv1 = *reinterpret_cast<const bf16x8*>(&Vg[(size_t)vr1 * S + kt + 64 + vc1]);
      }
      *reinterpret_cast<bf16x8*>(&Ks[cur][kr0 * 200 + kc0]) = ck0;
      *reinterpret_cast<bf16x8*>(&Ks[cur][kr1 * 200 + kc1]) = ck1;
      *reinterpret_cast<bf16x8*>(&Ks[cur][kr2 * 200 + kc2]) = ck2;
      *reinterpret_cast<bf16x8*>(&Vs[pb][vr0 * 72 + vc0]) = cv0;
      *reinterpret_cast<bf16x8*>(&Vs[pb][vr1 * 72 + vc1]) = cv1;
      lgkm_barrier();
      f32x4 acc[2];
#pragma unroll
      for (int kb = 0; kb < 2; kb++) { f32x4 z = {0.f, 0.f, 0.f, 0.f}; acc[kb] = z; }
      __builtin_amdgcn_s_setprio(1);
#pragma unroll
      for (int ks = 0; ks < 6; ++ks) {
#pragma unroll
        for (int kb = 0; kb < 2; ++kb) {
          bf16x8 b = *reinterpret_cast<const bf16x8*>(&Ks[cur][(kh * 32 + kb * 16 + lr) * 200 + ks * 32 + lk]);
          acc[kb] = __builtin_amdgcn_mfma_f32_16x16x32_bf16(qf[ks], b, acc[kb], 0, 0, 0);
        }
      }
      __builtin_amdgcn_s_setprio(0);
      const int colb = kt + kh * 32 + lr;
#pragma unroll
      for (int kb = 0; kb < 2; ++kb) {
#pragma unroll
        for (int q = 0; q < 4; ++q) {
          const int rloc = wm + hi * 4 + q;
          const int rowg = m0 + rloc;
          const int col = colb + kb * 16;
          float s = acc[kb][q] * ATT_SCALE;
          float p = (col <= rowg) ? __expf(s - mr[q]) * invl[q] : 0.f;
          Ah[(size_t)rowg * S + col] = p;
          Ps[pb][rloc * 72 + kh * 32 + kb * 16 + lr] = (bf16)p;
        }
      }
      if (ti > 0) {
        const int pp = (pb == 0) ? 2 : pb - 1;
        __builtin_amdgcn_s_setprio(1);
#pragma unroll
        for (int ks = 0; ks < 2; ++ks) {
          bf16x8 a = *reinterpret_cast<const bf16x8*>(&Ps[pp][(wm + lr) * 72 + ks * 32 + lk]);
#pragma unroll
          for (int j = 0; j < 4; ++j) {
            bf16x8 b = *reinterpret_cast<const bf16x8*>(&Vs[pp][(kh * 64 + j * 16 + lr) * 72 + ks * 32 + lk]);
            accp[j] = __builtin_amdgcn_mfma_f32_16x16x32_bf16(a, b, accp[j], 0, 0, 0);
          }
        }
        __builtin_amdgcn_s_setprio(0);
      }
      ck0 = nk0; ck1 = nk1; ck2 = nk2; cv0 = nv0; cv1 = nv1;
      cur ^= 1;
      pb = (pb == 2) ? 0 : pb + 1;
    }
    lgkm_barrier();
    {
      const int pp = (pb == 0) ? 2 : pb - 1;
#pragma unroll
      for (int ks = 0; ks < 2; ++ks) {
        bf16x8 a = *reinterpret_cast<const bf16x8*>(&Ps[pp][(wm + lr) * 72 + ks * 32 + lk]);
#pragma unroll
        for (int j = 0; j < 4; ++j) {
          bf16x8 b = *reinterpret_cast<const bf16x8*>(&Vs[pp][(kh * 64 + j * 16 + lr) * 72 + ks * 32 + lk]);
          accp[j] = __builtin_amdgcn_mfma_f32_16x16x32_bf16(a, b, accp[j], 0, 0, 0);
        }
      }
    }

    // zero-fill causal tail [kend, S)
    const float4 zz = make_float4(0.f, 0.f, 0.f, 0.f);
    {
      const int zr = t >> 3, zc0 = (t & 7) * 4;
      float* zrow = Ah + (size_t)(m0 + zr) * S;
      for (int k = kend + zc0; k < S; k += 32) *reinterpret_cast<float4*>(zrow + k) = zz;
    }

    // ctx epilogue
#pragma unroll
    for (int j = 0; j < 4; ++j) {
      const int d = kh * 64 + j * 16 + lr;
#pragma unroll
      for (int q = 0; q < 4; ++q) {
        const int rowg = m0 + wm + hi * 4 + q;
        C[(size_t)rowg * Hdim + d] = (bf16)accp[j][q];
      }
    }
  }
}

// ---------------- prep: 8 weight transposes (X cast eliminated) -------------
struct TJobs {
  const float* src[8];
  bf16* dst[8];
  int R[8], C[8], tiles[8];
};

__global__ __launch_bounds__(256) void prep(TJobs J) {
  const int t = threadIdx.x;
  int tile = blockIdx.x;
  int j = 0;
  while (tile >= J.tiles[j]) { tile -= J.tiles[j]; ++j; }
  const int C = J.C[j], R = J.R[j];
  int tcn = C >> 5;
  int rb = (tile / tcn) * 32, cb = (tile % tcn) * 32;
  const float* in = J.src[j];
  bf16* out = J.dst[j];
  __shared__ float tl[32][33];
  int tx = t & 31, ty = t >> 5;
#pragma unroll
  for (int q = 0; q < 32; q += 8)
    tl[ty + q][tx] = in[(size_t)(rb + ty + q) * C + cb + tx];
  __syncthreads();
#pragma unroll
  for (int q = 0; q < 32; q += 8)
    out[(size_t)(cb + ty + q) * R + rb + tx] = (bf16)tl[tx][ty + q];
}

// fused RMSNorm for cq (y==0) and ckv (y==1) reading merged dproj
__global__ __launch_bounds__(256) void rmsnorm_fused(const float* __restrict__ dproj,
                                                     const float* __restrict__ qw,
                                                     const float* __restrict__ kw,
                                                     bf16* __restrict__ cqb,
                                                     bf16* __restrict__ ckvb) {
  int row = blockIdx.x;
  bool isq = (blockIdx.y == 0);
  int C = isq ? QC : KVC;
  const float* p = dproj + (size_t)row * DN + (isq ? 0 : QC);
  const float* w = isq ? qw : kw;
  bf16* out = (isq ? cqb : ckvb) + (size_t)row * C;
  float ss = 0.f;
  for (int i = threadIdx.x * 4; i < C; i += 1024) {
    float4 v = *reinterpret_cast<const float4*>(p + i);
    ss += v.x * v.x + v.y * v.y + v.z * v.z + v.w * v.w;
  }
  ss = block_sum(ss);
  float r = rsqrtf(ss / (float)C + RMS_EPS);
  for (int i = threadIdx.x * 4; i < C; i += 1024) {
    float4 v = *reinterpret_cast<const float4*>(p + i);
    float4 g = *reinterpret_cast<const float4*>(w + i);
    bf16x4 o;
    o[0] = (bf16)(v.x * r * g.x); o[1] = (bf16)(v.y * r * g.y);
    o[2] = (bf16)(v.z * r * g.z); o[3] = (bf16)(v.w * r * g.w);
    *reinterpret_cast<bf16x4*>(out + i) = o;
  }
}

// ---------------- fused pack: qpack + kpack + V transpose ----------------
__global__ __launch_bounds__(256) void pack_all(const bf16* __restrict__ up1,
                                                const bf16* __restrict__ up2,
                                                const float* __restrict__ dproj,
                                                const float* __restrict__ cosp,
                                                const float* __restrict__ sinp,
                                                bf16* __restrict__ qpack,
                                                bf16* __restrict__ kpack,
                                                bf16* __restrict__ vt) {
  const int t = threadIdx.x;
  int id = blockIdx.x;
  if (id < 3072) {  // ---- qpack ----
    int idx = id * 256 + t;
    const int P = NH * S * 16;
    if (idx < P) {
      int d8 = idx & 15, s = (idx >> 4) & (S - 1), h = idx >> 15;
      int4 v = *reinterpret_cast<const int4*>(up1 + (size_t)s * 3072 + h * HD + d8 * 8);
      *reinterpret_cast<int4*>(qpack + ((size_t)h * S + s) * QKD + d8 * 8) = v;
    } else {
      int j = idx - P;
      int d0 = (j & 7) * 8, s = (j >> 3) & (S - 1), h = j >> 14;
      const bf16* xr = up1 + (size_t)s * 3072 + 2048 + h * RHD;
      bf16x8 xa = *reinterpret_cast<const bf16x8*>(xr + d0);
      bf16x8 xb = *reinterpret_cast<const bf16x8*>(xr + (d0 ^ 32));
      float sign = (d0 < 32) ? -1.f : 1.f;
      const float* cr = cosp + s * RHD + d0;
      const float* sr = sinp + s * RHD + d0;
      bf16x8 o;
#pragma unroll
      for (int i = 0; i < 8; i++)
        o[i] = (bf16)((float)xa[i] * cr[i] + sign * (float)xb[i] * sr[i]);
      *reinterpret_cast<bf16x8*>(qpack + ((size_t)h * S + s) * QKD + HD + d0) = o;
    }
    return;
  }
  if (id < 3648) {  // ---- kpack ----
    int idx = (id - 3072) * 256 + t;
    const int P = NKV * S * 16;
    if (idx < P) {
      int d8 = idx & 15, s = (idx >> 4) & (S - 1), g = idx >> 15;
      int4 v = *reinterpret_cast<const int4*>(up2 + (size_t)s * 1024 + g * HD + d8 * 8);
      *reinterpret_cast<int4*>(kpack + ((size_t)g * S + s) * QKD + d8 * 8) = v;
    } else {
      int j = idx - P;
      int d0 = (j & 7) * 8, s = j >> 3;
      const float* xr = dproj + (size_t)s * DN + 2048;
      float4 a0 = *reinterpret_cast<const float4*>(xr + d0);
      float4 a1 = *reinterpret_cast<const float4*>(xr + d0 + 4);
      float4 b0 = *reinterpret_cast<const float4*>(xr + (d0 ^ 32));
      float4 b1 = *reinterpret_cast<const float4*>(xr + (d0 ^ 32) + 4);
      float sign = (d0 < 32) ? -1.f : 1.f;
      const float* cr = cosp + s * RHD + d0;
      const float* sr = sinp + s * RHD + d0;
      float xa[8] = {a0.x, a0.y, a0.z, a0.w, a1.x, a1.y, a1.z, a1.w};
      float xb[8] = {b0.x, b0.y, b0.z, b0.w, b1.x, b1.y, b1.z, b1.w};
      bf16x8 o;
#pragma unroll
      for (int i = 0; i < 8; i++)
        o[i] = (bf16)(xa[i] * cr[i] + sign * xb[i] * sr[i]);
#pragma unroll
      for (int g = 0; g < NKV; g++)
        *reinterpret_cast<bf16x8*>(kpack + ((size_t)g * S + s) * QKD + HD + d0) = o;
    }
    return;
  }
  // ---- V transpose: up2[s][512+c] -> vt[c][s] ----
  int tile = id - 3648;
  int cb = (tile & 15) * 32;
  int rb = (tile >> 4) * 32;
  __shared__ float tl[32][33];
  int tx = t & 31, ty = t >> 5;
  const bf16* in = up2 + 512;
#pragma unroll
  for (int q = 0; q < 32; q += 8)
    tl[ty + q][tx] = (float)in[(size_t)(rb + ty + q) * 1024 + cb + tx];
  __syncthreads();
#pragma unroll
  for (int q = 0; q < 32; q += 8)
    vt[(size_t)(cb + ty + q) * S + rb + tx] = (bf16)tl[tx][ty + q];
}

// ---------------- launcher ----------------
extern "C" void kernel_launch(void* const* d_in, const int* in_sizes, int n_in, void* d_out,
                              int out_size, void* d_ws, size_t ws_size, hipStream_t stream) {
  const float* Xf = (const float*)d_in[0];
  const float* cosp = (const float*)d_in[1];
  const float* sinp = (const float*)d_in[2];
  const float* w_down_q = (const float*)d_in[4];
  const float* w_up_q = (const float*)d_in[5];
  const float* w_qr = (const float*)d_in[6];
  const float* w_down_kv = (const float*)d_in[7];
  const float* w_up_k = (const float*)d_in[8];
  const float* w_up_v = (const float*)d_in[9];
  const float* w_kr = (const float*)d_in[10];
  const float* w_o = (const float*)d_in[11];
  const float* q_norm_w = (const float*)d_in[12];
  const float* k_norm_w = (const float*)d_in[13];

  float* out0 = (float*)d_out;
  float* attn = out0 + (size_t)S * Hdim;

  char* base = (char*)d_ws;
  size_t off = 0;
  auto carve = [&](size_t bytes) -> void* {
    void* p = base + off;
    off += (bytes + 255) & ~(size_t)255;
    return p;
  };
  bf16* wt_down = (bf16*)carve((size_t)2176 * 2048 * 2);
  bf16* wt_up1  = (bf16*)carve((size_t)3072 * QC * 2);
  bf16* wt_up2  = (bf16*)carve((size_t)1024 * KVC * 2);
  bf16* wt_o    = (bf16*)carve((size_t)Hdim * Hdim * 2);
  float* dproj  = (float*)carve((size_t)S * DN * 4);
  bf16* cqb     = (bf16*)carve((size_t)S * QC * 2);
  bf16* ckvb    = (bf16*)carve((size_t)S * KVC * 2);
  bf16* up1     = (bf16*)carve((size_t)S * 3072 * 2);
  bf16* up2     = (bf16*)carve((size_t)S * 1024 * 2);
  bf16* qpack   = (bf16*)carve((size_t)NH * S * QKD * 2);
  bf16* kpack   = (bf16*)carve((size_t)NKV * S * QKD * 2);
  bf16* vt      = (bf16*)carve((size_t)NKV * HD * S * 2);
  bf16* ctxb    = (bf16*)carve((size_t)S * Hdim * 2);
  (void)in_sizes; (void)n_in; (void)out_size; (void)ws_size;

  TJobs J;
  const float* srcs[8] = {w_down_q, w_down_kv, w_kr, w_up_q, w_qr, w_up_k, w_up_v, w_o};
  bf16* dsts[8] = {wt_down, wt_down + (size_t)QC * 2048, wt_down + (size_t)2048 * 2048,
                   wt_up1, wt_up1 + (size_t)2048 * QC, wt_up2, wt_up2 + (size_t)512 * KVC, wt_o};
  int Rs[8] = {2048, 2048, 2048, 1536, 1536, 512, 512, 2048};
  int Cs[8] = {1536, 512, 64, 2048, 1024, 512, 512, 2048};
  int total_tiles = 0;
  for (int j = 0; j < 8; j++) {
    J.src[j] = srcs[j]; J.dst[j] = dsts[j]; J.R[j] = Rs[j]; J.C[j] = Cs[j];
    J.tiles[j] = (Rs[j] / 32) * (Cs[j] / 32);
    total_tiles += J.tiles[j];
  }

  // 1. prep: all weight transposes
  prep<<<total_tiles, 256, 0, stream>>>(J);
  // 2. merged down projection, reading fp32 X directly (in-staging cast)
  gemm_nt<float, float><<<dim3(17, 16), 256, 0, stream>>>(Xf, wt_down, dproj, DN, Hdim, Hdim, Hdim, DN, 1.f);
  // 3. both RMSNorms
  rmsnorm_fused<<<dim3(S, 2), 256, 0, stream>>>(dproj, q_norm_w, k_norm_w, cqb, ckvb);
  // 4. both up projections
  gemm_up_both<<<512, 256, 0, stream>>>(cqb, ckvb, wt_up1, wt_up2, up1, up2);
  // 5. pack q/k + RoPE + V transpose
  pack_all<<<4672, 256, 0, stream>>>(up1, up2, dproj, cosp, sinp, qpack, kpack, vt);
  // 6. fused flash attention (round-13 structure)
  fa_fused<<<dim3(16, NH), 512, 0, stream>>>(qpack, kpack, vt, attn, ctxb);
  // 7. output projection
  gemm_nt<bf16, float><<<dim3(16, 16), 256, 0, stream>>>(ctxb, wt_o, out0, Hdim, Hdim, Hdim, Hdim, Hdim, 1.f);
}

// Round 17
// 316.728 us; speedup vs baseline: 1.0939x; 1.0374x over previous
//
#include <hip/hip_runtime.h>
#include <stdint.h>

typedef __bf16 bf16;
typedef __bf16 bf16x8 __attribute__((ext_vector_type(8)));
typedef __bf16 bf16x4 __attribute__((ext_vector_type(4)));
typedef float f32x4 __attribute__((ext_vector_type(4)));

#define DEVFN static __device__ __forceinline__

constexpr int S = 2048, Hdim = 2048, NH = 16, NKV = 4, HD = 128, RHD = 64, QC = 1536, KVC = 512;
constexpr int QKD = HD + RHD;                 // 192
constexpr int DN = 2112;                      // merged down-proj width: QC + KVC + RHD
constexpr float RMS_EPS = 1e-6f;
constexpr float ATT_SCALE = 0.07216878364870323f;  // 1/sqrt(192)

// ---------------- reductions ----------------
DEVFN float wave_sum(float v) {
#pragma unroll
  for (int o = 32; o > 0; o >>= 1) v += __shfl_xor(v, o, 64);
  return v;
}
DEVFN float block_sum(float v) {
  __shared__ float red_s[4];
  v = wave_sum(v);
  int lane = threadIdx.x & 63, wid = threadIdx.x >> 6;
  if (lane == 0) red_s[wid] = v;
  __syncthreads();
  v = red_s[0] + red_s[1] + red_s[2] + red_s[3];
  __syncthreads();
  return v;
}

DEVFN void lgkm_barrier() {
  asm volatile("s_waitcnt lgkmcnt(0)" ::: "memory");
  __builtin_amdgcn_s_barrier();
}

// ---------------- pipelined GEMM core: C = A[M,K] * Bt[N,K]^T ----------------
// 128x128 tile, BK=32, 4 waves 2x2. Reg-staged double-buffered staging:
// next K-step's global loads issue BEFORE this step's ds_writes; ONE
// lgkm-only barrier per step. No setprio (m190: negative on lockstep GEMM).
template <typename OT>
DEVFN void gemm_core_pipe(const bf16* __restrict__ A, const bf16* __restrict__ Bt,
                          OT* __restrict__ C, int N, int lda, int ldb, int ldc,
                          int m0, int n0, float scale, int kend) {
  __shared__ alignas(16) bf16 As[2][128 * 32];
  __shared__ alignas(16) bf16 Bs[2][128 * 32];
  const int t = threadIdx.x;
  const int lane = t & 63;
  const int wm = ((t >> 7) & 1) * 64;
  const int wn = ((t >> 6) & 1) * 64;
  const int lr = lane & 15;
  const int lk = (lane >> 4) * 8;
  const int srow = t >> 2;
  const int scol = (t & 3) * 8;
  const bf16* A0 = A + (size_t)(m0 + srow) * lda + scol;
  const bf16* A1 = A + (size_t)(m0 + 64 + srow) * lda + scol;
  const bf16* B0 = Bt + (size_t)(n0 + srow) * ldb + scol;
  const bf16* B1 = Bt + (size_t)(n0 + 64 + srow) * ldb + scol;

  f32x4 acc[4][4];
#pragma unroll
  for (int i = 0; i < 4; i++)
#pragma unroll
    for (int j = 0; j < 4; j++) { f32x4 z = {0.f, 0.f, 0.f, 0.f}; acc[i][j] = z; }

  bf16x8 ca0 = *reinterpret_cast<const bf16x8*>(A0);
  bf16x8 ca1 = *reinterpret_cast<const bf16x8*>(A1);
  bf16x8 cb0 = *reinterpret_cast<const bf16x8*>(B0);
  bf16x8 cb1 = *reinterpret_cast<const bf16x8*>(B1);
  int cur = 0;
  for (int kk = 0; kk < kend; kk += 32) {
    bf16x8 na0, na1, nb0, nb1;
    if (kk + 32 < kend) {
      na0 = *reinterpret_cast<const bf16x8*>(A0 + kk + 32);
      na1 = *reinterpret_cast<const bf16x8*>(A1 + kk + 32);
      nb0 = *reinterpret_cast<const bf16x8*>(B0 + kk + 32);
      nb1 = *reinterpret_cast<const bf16x8*>(B1 + kk + 32);
    }
    *reinterpret_cast<bf16x8*>(&As[cur][t * 8]) = ca0;
    *reinterpret_cast<bf16x8*>(&As[cur][t * 8 + 2048]) = ca1;
    *reinterpret_cast<bf16x8*>(&Bs[cur][t * 8]) = cb0;
    *reinterpret_cast<bf16x8*>(&Bs[cur][t * 8 + 2048]) = cb1;
    lgkm_barrier();
    bf16x8 a[4], b[4];
#pragma unroll
    for (int i = 0; i < 4; i++)
      a[i] = *reinterpret_cast<const bf16x8*>(&As[cur][(wm + i * 16 + lr) * 32 + lk]);
#pragma unroll
    for (int i = 0; i < 4; i++)
      b[i] = *reinterpret_cast<const bf16x8*>(&Bs[cur][(wn + i * 16 + lr) * 32 + lk]);
#pragma unroll
    for (int i = 0; i < 4; i++)
#pragma unroll
      for (int j = 0; j < 4; j++)
        acc[i][j] = __builtin_amdgcn_mfma_f32_16x16x32_bf16(a[i], b[j], acc[i][j], 0, 0, 0);
    ca0 = na0; ca1 = na1; cb0 = nb0; cb1 = nb1;
    cur ^= 1;
  }
  const int orow = (lane >> 4) * 4;
#pragma unroll
  for (int i = 0; i < 4; i++) {
#pragma unroll
    for (int j = 0; j < 4; j++) {
      int col = n0 + wn + j * 16 + lr;
      if (col < N) {
#pragma unroll
        for (int q = 0; q < 4; q++) {
          int row = m0 + wm + i * 16 + orow + q;
          C[(size_t)row * ldc + col] = (OT)(acc[i][j][q] * scale);
        }
      }
    }
  }
}

template <typename OT>
__global__ __launch_bounds__(256) void gemm_nt(const bf16* __restrict__ A, const bf16* __restrict__ Bt,
                                               OT* __restrict__ C, int N, int K, int lda,
                                               int ldb, int ldc, float scale) {
  gemm_core_pipe<OT>(A, Bt, C, N, lda, ldb, ldc, blockIdx.y * 128, blockIdx.x * 128, scale, K);
}

// up1 (384 blocks) + up2 (128 blocks) in one launch
__global__ __launch_bounds__(256) void gemm_up_both(const bf16* __restrict__ cqb,
                                                    const bf16* __restrict__ ckvb,
                                                    const bf16* __restrict__ wt_up1,
                                                    const bf16* __restrict__ wt_up2,
                                                    bf16* __restrict__ up1,
                                                    bf16* __restrict__ up2) {
  int id = blockIdx.x;
  if (id < 384) {
    gemm_core_pipe<bf16>(cqb, wt_up1, up1, 3072, QC, QC, 3072, (id / 24) * 128, (id % 24) * 128, 1.f, QC);
  } else {
    id -= 384;
    gemm_core_pipe<bf16>(ckvb, wt_up2, up2, 1024, KVC, KVC, 1024, (id / 8) * 128, (id % 8) * 128, 1.f, KVC);
  }
}

// ============== Fused flash attention, deep-pipelined (round-13 proven) =====
// Grid (16, NH), 512 threads (8 waves: 4 row-groups x 2 k-halves).
// Block = balanced strip pair (64*i rows and 1984-64*i), 33 k-tiles total.
// Q fragments in REGISTERS; K double-buffered, V/Ps TRIPLE-buffered;
// reg-staged async split; deferred PV -> ONE lgkm barrier per tile.
__global__ __launch_bounds__(512) void fa_fused(const bf16* __restrict__ qpack,
                                                const bf16* __restrict__ kpack,
                                                const bf16* __restrict__ vt,
                                                float* __restrict__ attn,
                                                bf16* __restrict__ ctxb) {
  const int h = blockIdx.y;
  const int g = h >> 2;
  __shared__ alignas(16) bf16 Ks[2][64 * 200];
  __shared__ alignas(16) bf16 Vs[3][128 * 72];
  __shared__ alignas(16) bf16 Ps[3][64 * 72];
  float2* sb = reinterpret_cast<float2*>(&Vs[0][0]);   // [0..127] per-half merge
  float2* statf = sb + 128;                            // [0..63] final (m, 1/l)

  const int t = threadIdx.x;
  const int lane = t & 63;
  const int w = t >> 6;
  const int wm = (w & 3) * 16;
  const int kh = w >> 2;
  const int lr = lane & 15;
  const int hi = lane >> 4;
  const int lk = hi * 8;
  const int kr0 = t / 24, kc0 = (t % 24) * 8;
  const int kr1 = (t + 512) / 24, kc1 = ((t + 512) % 24) * 8;
  const int kr2 = (t + 1024) / 24, kc2 = ((t + 1024) % 24) * 8;
  const int vr0 = t >> 3, vc0 = (t & 7) * 8;
  const int vr1 = (t + 512) >> 3, vc1 = ((t + 512) & 7) * 8;

  const bf16* Qg = qpack + (size_t)h * S * QKD;
  const bf16* Kg = kpack + (size_t)g * S * QKD;
  const bf16* Vg = vt + (size_t)g * HD * S;
  float* Ah = attn + (size_t)h * S * S;
  bf16* C = ctxb + h * HD;

  for (int sub = 0; sub < 2; ++sub) {
    const int m0 = sub ? (1984 - 64 * blockIdx.x) : (64 * blockIdx.x);
    const int ntiles = sub ? (32 - blockIdx.x) : (blockIdx.x + 1);
    const int kend = m0 + 64;
    __syncthreads();

    bf16x8 qf[6];
#pragma unroll
    for (int ks = 0; ks < 6; ++ks)
      qf[ks] = *reinterpret_cast<const bf16x8*>(&Qg[(size_t)(m0 + wm + lr) * QKD + ks * 32 + lk]);

    // ---------- loop 1: stats ----------
    float mreg[4] = {-1e30f, -1e30f, -1e30f, -1e30f};
    float lreg[4] = {0.f, 0.f, 0.f, 0.f};
    bf16x8 ck0 = *reinterpret_cast<const bf16x8*>(&Kg[(size_t)kr0 * QKD + kc0]);
    bf16x8 ck1 = *reinterpret_cast<const bf16x8*>(&Kg[(size_t)kr1 * QKD + kc1]);
    bf16x8 ck2 = *reinterpret_cast<const bf16x8*>(&Kg[(size_t)kr2 * QKD + kc2]);
    int cur = 0;
    for (int ti = 0; ti < ntiles; ++ti) {
      const int kt = ti * 64;
      bf16x8 nk0, nk1, nk2;
      if (ti + 1 < ntiles) {
        nk0 = *reinterpret_cast<const bf16x8*>(&Kg[(size_t)(kt + 64 + kr0) * QKD + kc0]);
        nk1 = *reinterpret_cast<const bf16x8*>(&Kg[(size_t)(kt + 64 + kr1) * QKD + kc1]);
        nk2 = *reinterpret_cast<const bf16x8*>(&Kg[(size_t)(kt + 64 + kr2) * QKD + kc2]);
      }
      *reinterpret_cast<bf16x8*>(&Ks[cur][kr0 * 200 + kc0]) = ck0;
      *reinterpret_cast<bf16x8*>(&Ks[cur][kr1 * 200 + kc1]) = ck1;
      *reinterpret_cast<bf16x8*>(&Ks[cur][kr2 * 200 + kc2]) = ck2;
      lgkm_barrier();
      f32x4 acc[2];
#pragma unroll
      for (int kb = 0; kb < 2; kb++) { f32x4 z = {0.f, 0.f, 0.f, 0.f}; acc[kb] = z; }
      __builtin_amdgcn_s_setprio(1);
#pragma unroll
      for (int ks = 0; ks < 6; ++ks) {
#pragma unroll
        for (int kb = 0; kb < 2; ++kb) {
          bf16x8 b = *reinterpret_cast<const bf16x8*>(&Ks[cur][(kh * 32 + kb * 16 + lr) * 200 + ks * 32 + lk]);
          acc[kb] = __builtin_amdgcn_mfma_f32_16x16x32_bf16(qf[ks], b, acc[kb], 0, 0, 0);
        }
      }
      __builtin_amdgcn_s_setprio(0);
      const int colb = kt + kh * 32 + lr;
#pragma unroll
      for (int q = 0; q < 4; ++q) {
        const int rowg = m0 + wm + hi * 4 + q;
        bool u0 = (colb <= rowg), u1 = (colb + 16 <= rowg);
        float s0 = u0 ? acc[0][q] * ATT_SCALE : -1e30f;
        float s1 = u1 ? acc[1][q] * ATT_SCALE : -1e30f;
        float nm = fmaxf(mreg[q], fmaxf(s0, s1));
        float e0 = u0 ? __expf(s0 - nm) : 0.f;
        float e1 = u1 ? __expf(s1 - nm) : 0.f;
        lreg[q] = lreg[q] * __expf(mreg[q] - nm) + e0 + e1;
        mreg[q] = nm;
      }
      ck0 = nk0; ck1 = nk1; ck2 = nk2;
      cur ^= 1;
    }
#pragma unroll
    for (int q = 0; q < 4; ++q) {
      float m = mreg[q], l = lreg[q];
#pragma unroll
      for (int o = 1; o < 16; o <<= 1) {
        float mo = __shfl_xor(m, o, 64);
        float lo = __shfl_xor(l, o, 64);
        float M = fmaxf(m, mo);
        l = l * __expf(m - M) + lo * __expf(mo - M);
        m = M;
      }
      mreg[q] = m; lreg[q] = l;
    }
    __syncthreads();
    if (lr == 0) {
#pragma unroll
      for (int q = 0; q < 4; ++q)
        sb[kh * 64 + wm + hi * 4 + q] = make_float2(mreg[q], lreg[q]);
    }
    __syncthreads();
    if (w < 4 && lr == 0) {
#pragma unroll
      for (int q = 0; q < 4; ++q) {
        int r = wm + hi * 4 + q;
        float2 a = sb[r], b = sb[64 + r];
        float M = fmaxf(a.x, b.x);
        float L = a.y * __expf(a.x - M) + b.y * __expf(b.x - M);
        statf[r] = make_float2(M, 1.0f / L);
      }
    }
    __syncthreads();
    float mr[4], invl[4];
#pragma unroll
    for (int q = 0; q < 4; ++q) {
      float2 sv = statf[wm + hi * 4 + q];
      mr[q] = sv.x; invl[q] = sv.y;
    }
    __syncthreads();

    // ---------- loop 2: normalize + attn write + deferred PV ----------
    f32x4 accp[4];
#pragma unroll
    for (int j = 0; j < 4; j++) { f32x4 z = {0.f, 0.f, 0.f, 0.f}; accp[j] = z; }
    ck0 = *reinterpret_cast<const bf16x8*>(&Kg[(size_t)kr0 * QKD + kc0]);
    ck1 = *reinterpret_cast<const bf16x8*>(&Kg[(size_t)kr1 * QKD + kc1]);
    ck2 = *reinterpret_cast<const bf16x8*>(&Kg[(size_t)kr2 * QKD + kc2]);
    bf16x8 cv0 = *reinterpret_cast<const bf16x8*>(&Vg[(size_t)vr0 * S + vc0]);
    bf16x8 cv1 = *reinterpret_cast<const bf16x8*>(&Vg[(size_t)vr1 * S + vc1]);
    cur = 0;
    int pb = 0;
    for (int ti = 0; ti < ntiles; ++ti) {
      const int kt = ti * 64;
      bf16x8 nk0, nk1, nk2, nv0, nv1;
      if (ti + 1 < ntiles) {
        nk0 = *reinterpret_cast<const bf16x8*>(&Kg[(size_t)(kt + 64 + kr0) * QKD + kc0]);
        nk1 = *reinterpret_cast<const bf16x8*>(&Kg[(size_t)(kt + 64 + kr1) * QKD + kc1]);
        nk2 = *reinterpret_cast<const bf16x8*>(&Kg[(size_t)(kt + 64 + kr2) * QKD + kc2]);
        nv0 = *reinterpret_cast<const bf16x8*>(&Vg[(size_t)vr0 * S + kt + 64 + vc0]);
        nv1 = *reinterpret_cast<const bf16x8*>(&Vg[(size_t)vr1 * S + kt + 64 + vc1]);
      }
      *reinterpret_cast<bf16x8*>(&Ks[cur][kr0 * 200 + kc0]) = ck0;
      *reinterpret_cast<bf16x8*>(&Ks[cur][kr1 * 200 + kc1]) = ck1;
      *reinterpret_cast<bf16x8*>(&Ks[cur][kr2 * 200 + kc2]) = ck2;
      *reinterpret_cast<bf16x8*>(&Vs[pb][vr0 * 72 + vc0]) = cv0;
      *reinterpret_cast<bf16x8*>(&Vs[pb][vr1 * 72 + vc1]) = cv1;
      lgkm_barrier();
      f32x4 acc[2];
#pragma unroll
      for (int kb = 0; kb < 2; kb++) { f32x4 z = {0.f, 0.f, 0.f, 0.f}; acc[kb] = z; }
      __builtin_amdgcn_s_setprio(1);
#pragma unroll
      for (int ks = 0; ks < 6; ++ks) {
#pragma unroll
        for (int kb = 0; kb < 2; ++kb) {
          bf16x8 b = *reinterpret_cast<const bf16x8*>(&Ks[cur][(kh * 32 + kb * 16 + lr) * 200 + ks * 32 + lk]);
          acc[kb] = __builtin_amdgcn_mfma_f32_16x16x32_bf16(qf[ks], b, acc[kb], 0, 0, 0);
        }
      }
      __builtin_amdgcn_s_setprio(0);
      const int colb = kt + kh * 32 + lr;
#pragma unroll
      for (int kb = 0; kb < 2; ++kb) {
#pragma unroll
        for (int q = 0; q < 4; ++q) {
          const int rloc = wm + hi * 4 + q;
          const int rowg = m0 + rloc;
          const int col = colb + kb * 16;
          float s = acc[kb][q] * ATT_SCALE;
          float p = (col <= rowg) ? __expf(s - mr[q]) * invl[q] : 0.f;
          Ah[(size_t)rowg * S + col] = p;
          Ps[pb][rloc * 72 + kh * 32 + kb * 16 + lr] = (bf16)p;
        }
      }
      if (ti > 0) {
        const int pp = (pb == 0) ? 2 : pb - 1;
        __builtin_amdgcn_s_setprio(1);
#pragma unroll
        for (int ks = 0; ks < 2; ++ks) {
          bf16x8 a = *reinterpret_cast<const bf16x8*>(&Ps[pp][(wm + lr) * 72 + ks * 32 + lk]);
#pragma unroll
          for (int j = 0; j < 4; ++j) {
            bf16x8 b = *reinterpret_cast<const bf16x8*>(&Vs[pp][(kh * 64 + j * 16 + lr) * 72 + ks * 32 + lk]);
            accp[j] = __builtin_amdgcn_mfma_f32_16x16x32_bf16(a, b, accp[j], 0, 0, 0);
          }
        }
        __builtin_amdgcn_s_setprio(0);
      }
      ck0 = nk0; ck1 = nk1; ck2 = nk2; cv0 = nv0; cv1 = nv1;
      cur ^= 1;
      pb = (pb == 2) ? 0 : pb + 1;
    }
    lgkm_barrier();
    {
      const int pp = (pb == 0) ? 2 : pb - 1;
#pragma unroll
      for (int ks = 0; ks < 2; ++ks) {
        bf16x8 a = *reinterpret_cast<const bf16x8*>(&Ps[pp][(wm + lr) * 72 + ks * 32 + lk]);
#pragma unroll
        for (int j = 0; j < 4; ++j) {
          bf16x8 b = *reinterpret_cast<const bf16x8*>(&Vs[pp][(kh * 64 + j * 16 + lr) * 72 + ks * 32 + lk]);
          accp[j] = __builtin_amdgcn_mfma_f32_16x16x32_bf16(a, b, accp[j], 0, 0, 0);
        }
      }
    }

    // zero-fill causal tail [kend, S)
    const float4 zz = make_float4(0.f, 0.f, 0.f, 0.f);
    {
      const int zr = t >> 3, zc0 = (t & 7) * 4;
      float* zrow = Ah + (size_t)(m0 + zr) * S;
      for (int k = kend + zc0; k < S; k += 32) *reinterpret_cast<float4*>(zrow + k) = zz;
    }

    // ctx epilogue
#pragma unroll
    for (int j = 0; j < 4; ++j) {
      const int d = kh * 64 + j * 16 + lr;
#pragma unroll
      for (int q = 0; q < 4; ++q) {
        const int rowg = m0 + wm + hi * 4 + q;
        C[(size_t)rowg * Hdim + d] = (bf16)accp[j][q];
      }
    }
  }
}

// ---------------- fused prep: X cast + 8 weight transposes ----------------
struct TJobs {
  const float* src[8];
  bf16* dst[8];
  int R[8], C[8], tiles[8];
};

__global__ __launch_bounds__(256) void prep(const float* __restrict__ Xf,
                                            bf16* __restrict__ Xb, TJobs J) {
  const int t = threadIdx.x;
  int id = blockIdx.x;
  if (id < 2048) {  // cast: 2048 blocks x 256 threads x 8 elems = S*Hdim
    size_t i = (size_t)id * 256 + t;
    float4 f0 = *reinterpret_cast<const float4*>(Xf + i * 8);
    float4 f1 = *reinterpret_cast<const float4*>(Xf + i * 8 + 4);
    bf16x8 v;
    v[0] = (bf16)f0.x; v[1] = (bf16)f0.y; v[2] = (bf16)f0.z; v[3] = (bf16)f0.w;
    v[4] = (bf16)f1.x; v[5] = (bf16)f1.y; v[6] = (bf16)f1.z; v[7] = (bf16)f1.w;
    *reinterpret_cast<bf16x8*>(Xb + i * 8) = v;
    return;
  }
  int tile = id - 2048;
  int j = 0;
  while (tile >= J.tiles[j]) { tile -= J.tiles[j]; ++j; }
  const int C = J.C[j], R = J.R[j];
  int tcn = C >> 5;
  int rb = (tile / tcn) * 32, cb = (tile % tcn) * 32;
  const float* in = J.src[j];
  bf16* out = J.dst[j];
  __shared__ float tl[32][33];
  int tx = t & 31, ty = t >> 5;
#pragma unroll
  for (int q = 0; q < 32; q += 8)
    tl[ty + q][tx] = in[(size_t)(rb + ty + q) * C + cb + tx];
  __syncthreads();
#pragma unroll
  for (int q = 0; q < 32; q += 8)
    out[(size_t)(cb + ty + q) * R + rb + tx] = (bf16)tl[tx][ty + q];
}

// fused RMSNorm for cq (y==0) and ckv (y==1) reading merged dproj
__global__ __launch_bounds__(256) void rmsnorm_fused(const float* __restrict__ dproj,
                                                     const float* __restrict__ qw,
                                                     const float* __restrict__ kw,
                                                     bf16* __restrict__ cqb,
                                                     bf16* __restrict__ ckvb) {
  int row = blockIdx.x;
  bool isq = (blockIdx.y == 0);
  int C = isq ? QC : KVC;
  const float* p = dproj + (size_t)row * DN + (isq ? 0 : QC);
  const float* w = isq ? qw : kw;
  bf16* out = (isq ? cqb : ckvb) + (size_t)row * C;
  float ss = 0.f;
  for (int i = threadIdx.x * 4; i < C; i += 1024) {
    float4 v = *reinterpret_cast<const float4*>(p + i);
    ss += v.x * v.x + v.y * v.y + v.z * v.z + v.w * v.w;
  }
  ss = block_sum(ss);
  float r = rsqrtf(ss / (float)C + RMS_EPS);
  for (int i = threadIdx.x * 4; i < C; i += 1024) {
    float4 v = *reinterpret_cast<const float4*>(p + i);
    float4 g = *reinterpret_cast<const float4*>(w + i);
    bf16x4 o;
    o[0] = (bf16)(v.x * r * g.x); o[1] = (bf16)(v.y * r * g.y);
    o[2] = (bf16)(v.z * r * g.z); o[3] = (bf16)(v.w * r * g.w);
    *reinterpret_cast<bf16x4*>(out + i) = o;
  }
}

// ---------------- fused pack: qpack + kpack + V transpose ----------------
__global__ __launch_bounds__(256) void pack_all(const bf16* __restrict__ up1,
                                                const bf16* __restrict__ up2,
                                                const float* __restrict__ dproj,
                                                const float* __restrict__ cosp,
                                                const float* __restrict__ sinp,
                                                bf16* __restrict__ qpack,
                                                bf16* __restrict__ kpack,
                                                bf16* __restrict__ vt) {
  const int t = threadIdx.x;
  int id = blockIdx.x;
  if (id < 3072) {  // ---- qpack ----
    int idx = id * 256 + t;
    const int P = NH * S * 16;
    if (idx < P) {
      int d8 = idx & 15, s = (idx >> 4) & (S - 1), h = idx >> 15;
      int4 v = *reinterpret_cast<const int4*>(up1 + (size_t)s * 3072 + h * HD + d8 * 8);
      *reinterpret_cast<int4*>(qpack + ((size_t)h * S + s) * QKD + d8 * 8) = v;
    } else {
      int j = idx - P;
      int d0 = (j & 7) * 8, s = (j >> 3) & (S - 1), h = j >> 14;
      const bf16* xr = up1 + (size_t)s * 3072 + 2048 + h * RHD;
      bf16x8 xa = *reinterpret_cast<const bf16x8*>(xr + d0);
      bf16x8 xb = *reinterpret_cast<const bf16x8*>(xr + (d0 ^ 32));
      float sign = (d0 < 32) ? -1.f : 1.f;
      const float* cr = cosp + s * RHD + d0;
      const float* sr = sinp + s * RHD + d0;
      bf16x8 o;
#pragma unroll
      for (int i = 0; i < 8; i++)
        o[i] = (bf16)((float)xa[i] * cr[i] + sign * (float)xb[i] * sr[i]);
      *reinterpret_cast<bf16x8*>(qpack + ((size_t)h * S + s) * QKD + HD + d0) = o;
    }
    return;
  }
  if (id < 3648) {  // ---- kpack ----
    int idx = (id - 3072) * 256 + t;
    const int P = NKV * S * 16;
    if (idx < P) {
      int d8 = idx & 15, s = (idx >> 4) & (S - 1), g = idx >> 15;
      int4 v = *reinterpret_cast<const int4*>(up2 + (size_t)s * 1024 + g * HD + d8 * 8);
      *reinterpret_cast<int4*>(kpack + ((size_t)g * S + s) * QKD + d8 * 8) = v;
    } else {
      int j = idx - P;
      int d0 = (j & 7) * 8, s = j >> 3;
      const float* xr = dproj + (size_t)s * DN + 2048;
      float4 a0 = *reinterpret_cast<const float4*>(xr + d0);
      float4 a1 = *reinterpret_cast<const float4*>(xr + d0 + 4);
      float4 b0 = *reinterpret_cast<const float4*>(xr + (d0 ^ 32));
      float4 b1 = *reinterpret_cast<const float4*>(xr + (d0 ^ 32) + 4);
      float sign = (d0 < 32) ? -1.f : 1.f;
      const float* cr = cosp + s * RHD + d0;
      const float* sr = sinp + s * RHD + d0;
      float xa[8] = {a0.x, a0.y, a0.z, a0.w, a1.x, a1.y, a1.z, a1.w};
      float xb[8] = {b0.x, b0.y, b0.z, b0.w, b1.x, b1.y, b1.z, b1.w};
      bf16x8 o;
#pragma unroll
      for (int i = 0; i < 8; i++)
        o[i] = (bf16)(xa[i] * cr[i] + sign * xb[i] * sr[i]);
#pragma unroll
      for (int g = 0; g < NKV; g++)
        *reinterpret_cast<bf16x8*>(kpack + ((size_t)g * S + s) * QKD + HD + d0) = o;
    }
    return;
  }
  // ---- V transpose: up2[s][512+c] -> vt[c][s] ----
  int tile = id - 3648;
  int cb = (tile & 15) * 32;
  int rb = (tile >> 4) * 32;
  __shared__ float tl[32][33];
  int tx = t & 31, ty = t >> 5;
  const bf16* in = up2 + 512;
#pragma unroll
  for (int q = 0; q < 32; q += 8)
    tl[ty + q][tx] = (float)in[(size_t)(rb + ty + q) * 1024 + cb + tx];
  __syncthreads();
#pragma unroll
  for (int q = 0; q < 32; q += 8)
    vt[(size_t)(cb + ty + q) * S + rb + tx] = (bf16)tl[tx][ty + q];
}

// ---------------- launcher ----------------
extern "C" void kernel_launch(void* const* d_in, const int* in_sizes, int n_in, void* d_out,
                              int out_size, void* d_ws, size_t ws_size, hipStream_t stream) {
  const float* Xf = (const float*)d_in[0];
  const float* cosp = (const float*)d_in[1];
  const float* sinp = (const float*)d_in[2];
  const float* w_down_q = (const float*)d_in[4];
  const float* w_up_q = (const float*)d_in[5];
  const float* w_qr = (const float*)d_in[6];
  const float* w_down_kv = (const float*)d_in[7];
  const float* w_up_k = (const float*)d_in[8];
  const float* w_up_v = (const float*)d_in[9];
  const float* w_kr = (const float*)d_in[10];
  const float* w_o = (const float*)d_in[11];
  const float* q_norm_w = (const float*)d_in[12];
  const float* k_norm_w = (const float*)d_in[13];

  float* out0 = (float*)d_out;
  float* attn = out0 + (size_t)S * Hdim;

  char* base = (char*)d_ws;
  size_t off = 0;
  auto carve = [&](size_t bytes) -> void* {
    void* p = base + off;
    off += (bytes + 255) & ~(size_t)255;
    return p;
  };
  bf16* Xb      = (bf16*)carve((size_t)S * Hdim * 2);
  bf16* wt_down = (bf16*)carve((size_t)2176 * 2048 * 2);
  bf16* wt_up1  = (bf16*)carve((size_t)3072 * QC * 2);
  bf16* wt_up2  = (bf16*)carve((size_t)1024 * KVC * 2);
  bf16* wt_o    = (bf16*)carve((size_t)Hdim * Hdim * 2);
  float* dproj  = (float*)carve((size_t)S * DN * 4);
  bf16* cqb     = (bf16*)carve((size_t)S * QC * 2);
  bf16* ckvb    = (bf16*)carve((size_t)S * KVC * 2);
  bf16* up1     = (bf16*)carve((size_t)S * 3072 * 2);
  bf16* up2     = (bf16*)carve((size_t)S * 1024 * 2);
  bf16* qpack   = (bf16*)carve((size_t)NH * S * QKD * 2);
  bf16* kpack   = (bf16*)carve((size_t)NKV * S * QKD * 2);
  bf16* vt      = (bf16*)carve((size_t)NKV * HD * S * 2);
  bf16* ctxb    = (bf16*)carve((size_t)S * Hdim * 2);
  (void)in_sizes; (void)n_in; (void)out_size; (void)ws_size;

  TJobs J;
  const float* srcs[8] = {w_down_q, w_down_kv, w_kr, w_up_q, w_qr, w_up_k, w_up_v, w_o};
  bf16* dsts[8] = {wt_down, wt_down + (size_t)QC * 2048, wt_down + (size_t)2048 * 2048,
                   wt_up1, wt_up1 + (size_t)2048 * QC, wt_up2, wt_up2 + (size_t)512 * KVC, wt_o};
  int Rs[8] = {2048, 2048, 2048, 1536, 1536, 512, 512, 2048};
  int Cs[8] = {1536, 512, 64, 2048, 1024, 512, 512, 2048};
  int total_tiles = 0;
  for (int j = 0; j < 8; j++) {
    J.src[j] = srcs[j]; J.dst[j] = dsts[j]; J.R[j] = Rs[j]; J.C[j] = Cs[j];
    J.tiles[j] = (Rs[j] / 32) * (Cs[j] / 32);
    total_tiles += J.tiles[j];
  }

  // 1. prep: X cast + all weight transposes
  prep<<<2048 + total_tiles, 256, 0, stream>>>(Xf, Xb, J);
  // 2. merged down projection: [S][2112] = Xb @ [wdq | wdkv | wkr]
  gemm_nt<float><<<dim3(17, 16), 256, 0, stream>>>(Xb, wt_down, dproj, DN, Hdim, Hdim, Hdim, DN, 1.f);
  // 3. both RMSNorms
  rmsnorm_fused<<<dim3(S, 2), 256, 0, stream>>>(dproj, q_norm_w, k_norm_w, cqb, ckvb);
  // 4. both up projections
  gemm_up_both<<<512, 256, 0, stream>>>(cqb, ckvb, wt_up1, wt_up2, up1, up2);
  // 5. pack q/k + RoPE + V transpose
  pack_all<<<4672, 256, 0, stream>>>(up1, up2, dproj, cosp, sinp, qpack, kpack, vt);
  // 6. fused flash attention (round-13 structure)
  fa_fused<<<dim3(16, NH), 512, 0, stream>>>(qpack, kpack, vt, attn, ctxb);
  // 7. output projection
  gemm_nt<float><<<dim3(16, 16), 256, 0, stream>>>(ctxb, wt_o, out0, Hdim, Hdim, Hdim, Hdim, Hdim, 1.f);
}

// Round 18
// 306.525 us; speedup vs baseline: 1.1303x; 1.0333x over previous
//
#include <hip/hip_runtime.h>
#include <stdint.h>

typedef __bf16 bf16;
typedef __bf16 bf16x8 __attribute__((ext_vector_type(8)));
typedef __bf16 bf16x4 __attribute__((ext_vector_type(4)));
typedef float f32x4 __attribute__((ext_vector_type(4)));

#define DEVFN static __device__ __forceinline__

constexpr int S = 2048, Hdim = 2048, NH = 16, NKV = 4, HD = 128, RHD = 64, QC = 1536, KVC = 512;
constexpr int QKD = HD + RHD;                 // 192
constexpr int DN = 2112;                      // merged down-proj width: QC + KVC + RHD
constexpr float RMS_EPS = 1e-6f;
constexpr float ATT_SCALE = 0.07216878364870323f;  // 1/sqrt(192)

// ---------------- reductions ----------------
DEVFN float wave_sum(float v) {
#pragma unroll
  for (int o = 32; o > 0; o >>= 1) v += __shfl_xor(v, o, 64);
  return v;
}
DEVFN float block_sum(float v) {
  __shared__ float red_s[4];
  v = wave_sum(v);
  int lane = threadIdx.x & 63, wid = threadIdx.x >> 6;
  if (lane == 0) red_s[wid] = v;
  __syncthreads();
  v = red_s[0] + red_s[1] + red_s[2] + red_s[3];
  __syncthreads();
  return v;
}

DEVFN void lgkm_barrier() {
  asm volatile("s_waitcnt lgkmcnt(0)" ::: "memory");
  __builtin_amdgcn_s_barrier();
}

// ---------------- pipelined GEMM core: C = A[M,K] * Bt[N,K]^T ----------------
// 128x128 tile, BK=32, 4 waves 2x2. Reg-staged double-buffered staging:
// next K-step's global loads issue BEFORE this step's ds_writes; ONE
// lgkm-only barrier per step (vmcnt for reg loads overlaps 16 MFMA).
template <typename OT>
DEVFN void gemm_core_pipe(const bf16* __restrict__ A, const bf16* __restrict__ Bt,
                          OT* __restrict__ C, int N, int lda, int ldb, int ldc,
                          int m0, int n0, float scale, int kend) {
  __shared__ alignas(16) bf16 As[2][128 * 32];
  __shared__ alignas(16) bf16 Bs[2][128 * 32];
  const int t = threadIdx.x;
  const int lane = t & 63;
  const int wm = ((t >> 7) & 1) * 64;
  const int wn = ((t >> 6) & 1) * 64;
  const int lr = lane & 15;
  const int lk = (lane >> 4) * 8;
  const int srow = t >> 2;
  const int scol = (t & 3) * 8;
  const bf16* A0 = A + (size_t)(m0 + srow) * lda + scol;
  const bf16* A1 = A + (size_t)(m0 + 64 + srow) * lda + scol;
  const bf16* B0 = Bt + (size_t)(n0 + srow) * ldb + scol;
  const bf16* B1 = Bt + (size_t)(n0 + 64 + srow) * ldb + scol;

  f32x4 acc[4][4];
#pragma unroll
  for (int i = 0; i < 4; i++)
#pragma unroll
    for (int j = 0; j < 4; j++) { f32x4 z = {0.f, 0.f, 0.f, 0.f}; acc[i][j] = z; }

  bf16x8 ca0 = *reinterpret_cast<const bf16x8*>(A0);
  bf16x8 ca1 = *reinterpret_cast<const bf16x8*>(A1);
  bf16x8 cb0 = *reinterpret_cast<const bf16x8*>(B0);
  bf16x8 cb1 = *reinterpret_cast<const bf16x8*>(B1);
  int cur = 0;
  for (int kk = 0; kk < kend; kk += 32) {
    bf16x8 na0, na1, nb0, nb1;
    if (kk + 32 < kend) {  // issue next step's loads before this step's stores
      na0 = *reinterpret_cast<const bf16x8*>(A0 + kk + 32);
      na1 = *reinterpret_cast<const bf16x8*>(A1 + kk + 32);
      nb0 = *reinterpret_cast<const bf16x8*>(B0 + kk + 32);
      nb1 = *reinterpret_cast<const bf16x8*>(B1 + kk + 32);
    }
    *reinterpret_cast<bf16x8*>(&As[cur][t * 8]) = ca0;
    *reinterpret_cast<bf16x8*>(&As[cur][t * 8 + 2048]) = ca1;
    *reinterpret_cast<bf16x8*>(&Bs[cur][t * 8]) = cb0;
    *reinterpret_cast<bf16x8*>(&Bs[cur][t * 8 + 2048]) = cb1;
    lgkm_barrier();
    bf16x8 a[4], b[4];
#pragma unroll
    for (int i = 0; i < 4; i++)
      a[i] = *reinterpret_cast<const bf16x8*>(&As[cur][(wm + i * 16 + lr) * 32 + lk]);
#pragma unroll
    for (int i = 0; i < 4; i++)
      b[i] = *reinterpret_cast<const bf16x8*>(&Bs[cur][(wn + i * 16 + lr) * 32 + lk]);
    __builtin_amdgcn_s_setprio(1);
#pragma unroll
    for (int i = 0; i < 4; i++)
#pragma unroll
      for (int j = 0; j < 4; j++)
        acc[i][j] = __builtin_amdgcn_mfma_f32_16x16x32_bf16(a[i], b[j], acc[i][j], 0, 0, 0);
    __builtin_amdgcn_s_setprio(0);
    ca0 = na0; ca1 = na1; cb0 = nb0; cb1 = nb1;
    cur ^= 1;
  }
  const int orow = (lane >> 4) * 4;
#pragma unroll
  for (int i = 0; i < 4; i++) {
#pragma unroll
    for (int j = 0; j < 4; j++) {
      int col = n0 + wn + j * 16 + lr;
      if (col < N) {
#pragma unroll
        for (int q = 0; q < 4; q++) {
          int row = m0 + wm + i * 16 + orow + q;
          C[(size_t)row * ldc + col] = (OT)(acc[i][j][q] * scale);
        }
      }
    }
  }
}

template <typename OT>
__global__ __launch_bounds__(256) void gemm_nt(const bf16* __restrict__ A, const bf16* __restrict__ Bt,
                                               OT* __restrict__ C, int N, int K, int lda,
                                               int ldb, int ldc, float scale) {
  gemm_core_pipe<OT>(A, Bt, C, N, lda, ldb, ldc, blockIdx.y * 128, blockIdx.x * 128, scale, K);
}

// up1 (384 blocks) + up2 (128 blocks) in one launch
__global__ __launch_bounds__(256) void gemm_up_both(const bf16* __restrict__ cqb,
                                                    const bf16* __restrict__ ckvb,
                                                    const bf16* __restrict__ wt_up1,
                                                    const bf16* __restrict__ wt_up2,
                                                    bf16* __restrict__ up1,
                                                    bf16* __restrict__ up2) {
  int id = blockIdx.x;
  if (id < 384) {
    gemm_core_pipe<bf16>(cqb, wt_up1, up1, 3072, QC, QC, 3072, (id / 24) * 128, (id % 24) * 128, 1.f, QC);
  } else {
    id -= 384;
    gemm_core_pipe<bf16>(ckvb, wt_up2, up2, 1024, KVC, KVC, 1024, (id / 8) * 128, (id % 8) * 128, 1.f, KVC);
  }
}

// ============== Fused flash attention, deep-pipelined ==============
// Grid (16, NH), 512 threads (8 waves: 4 row-groups x 2 k-halves).
// Block = balanced strip pair (64*i rows and 1984-64*i), 33 k-tiles total.
// Q fragments live in REGISTERS (loaded once per strip). K double-buffered,
// V/Ps TRIPLE-buffered; reg-staged async split (loads for t+1 issue before
// tile t's compute). PV of tile t-1 runs after softmax of tile t -> ONE lgkm
// barrier per tile in both loops. attn stores never drained at barriers.
__global__ __launch_bounds__(512) void fa_fused(const bf16* __restrict__ qpack,
                                                const bf16* __restrict__ kpack,
                                                const bf16* __restrict__ vt,
                                                float* __restrict__ attn,
                                                bf16* __restrict__ ctxb) {
  const int h = blockIdx.y;
  const int g = h >> 2;
  __shared__ alignas(16) bf16 Ks[2][64 * 200];
  __shared__ alignas(16) bf16 Vs[3][128 * 72];
  __shared__ alignas(16) bf16 Ps[3][64 * 72];
  float2* sb = reinterpret_cast<float2*>(&Vs[0][0]);   // [0..127] per-half merge
  float2* statf = sb + 128;                            // [0..63] final (m, 1/l)

  const int t = threadIdx.x;
  const int lane = t & 63;
  const int w = t >> 6;
  const int wm = (w & 3) * 16;     // row-group base within strip
  const int kh = w >> 2;           // k-half (QK) / d-half (PV)
  const int lr = lane & 15;
  const int hi = lane >> 4;
  const int lk = hi * 8;
  const int kr0 = t / 24, kc0 = (t % 24) * 8;
  const int kr1 = (t + 512) / 24, kc1 = ((t + 512) % 24) * 8;
  const int kr2 = (t + 1024) / 24, kc2 = ((t + 1024) % 24) * 8;
  const int vr0 = t >> 3, vc0 = (t & 7) * 8;
  const int vr1 = (t + 512) >> 3, vc1 = ((t + 512) & 7) * 8;

  const bf16* Qg = qpack + (size_t)h * S * QKD;
  const bf16* Kg = kpack + (size_t)g * S * QKD;
  const bf16* Vg = vt + (size_t)g * HD * S;
  float* Ah = attn + (size_t)h * S * S;
  bf16* C = ctxb + h * HD;

  for (int sub = 0; sub < 2; ++sub) {
    const int m0 = sub ? (1984 - 64 * blockIdx.x) : (64 * blockIdx.x);
    const int ntiles = sub ? (32 - blockIdx.x) : (blockIdx.x + 1);
    const int kend = m0 + 64;
    __syncthreads();  // prev sub's LDS reads done

    // Q fragments -> registers (once per strip)
    bf16x8 qf[6];
#pragma unroll
    for (int ks = 0; ks < 6; ++ks)
      qf[ks] = *reinterpret_cast<const bf16x8*>(&Qg[(size_t)(m0 + wm + lr) * QKD + ks * 32 + lk]);

    // ---------- loop 1: stats ----------
    float mreg[4] = {-1e30f, -1e30f, -1e30f, -1e30f};
    float lreg[4] = {0.f, 0.f, 0.f, 0.f};
    bf16x8 ck0 = *reinterpret_cast<const bf16x8*>(&Kg[(size_t)kr0 * QKD + kc0]);
    bf16x8 ck1 = *reinterpret_cast<const bf16x8*>(&Kg[(size_t)kr1 * QKD + kc1]);
    bf16x8 ck2 = *reinterpret_cast<const bf16x8*>(&Kg[(size_t)kr2 * QKD + kc2]);
    int cur = 0;
    for (int ti = 0; ti < ntiles; ++ti) {
      const int kt = ti * 64;
      bf16x8 nk0, nk1, nk2;
      if (ti + 1 < ntiles) {
        nk0 = *reinterpret_cast<const bf16x8*>(&Kg[(size_t)(kt + 64 + kr0) * QKD + kc0]);
        nk1 = *reinterpret_cast<const bf16x8*>(&Kg[(size_t)(kt + 64 + kr1) * QKD + kc1]);
        nk2 = *reinterpret_cast<const bf16x8*>(&Kg[(size_t)(kt + 64 + kr2) * QKD + kc2]);
      }
      *reinterpret_cast<bf16x8*>(&Ks[cur][kr0 * 200 + kc0]) = ck0;
      *reinterpret_cast<bf16x8*>(&Ks[cur][kr1 * 200 + kc1]) = ck1;
      *reinterpret_cast<bf16x8*>(&Ks[cur][kr2 * 200 + kc2]) = ck2;
      lgkm_barrier();
      f32x4 acc[2];
#pragma unroll
      for (int kb = 0; kb < 2; kb++) { f32x4 z = {0.f, 0.f, 0.f, 0.f}; acc[kb] = z; }
      __builtin_amdgcn_s_setprio(1);
#pragma unroll
      for (int ks = 0; ks < 6; ++ks) {
#pragma unroll
        for (int kb = 0; kb < 2; ++kb) {
          bf16x8 b = *reinterpret_cast<const bf16x8*>(&Ks[cur][(kh * 32 + kb * 16 + lr) * 200 + ks * 32 + lk]);
          acc[kb] = __builtin_amdgcn_mfma_f32_16x16x32_bf16(qf[ks], b, acc[kb], 0, 0, 0);
        }
      }
      __builtin_amdgcn_s_setprio(0);
      const int colb = kt + kh * 32 + lr;
#pragma unroll
      for (int q = 0; q < 4; ++q) {
        const int rowg = m0 + wm + hi * 4 + q;
        bool u0 = (colb <= rowg), u1 = (colb + 16 <= rowg);
        float s0 = u0 ? acc[0][q] * ATT_SCALE : -1e30f;
        float s1 = u1 ? acc[1][q] * ATT_SCALE : -1e30f;
        float nm = fmaxf(mreg[q], fmaxf(s0, s1));
        float e0 = u0 ? __expf(s0 - nm) : 0.f;
        float e1 = u1 ? __expf(s1 - nm) : 0.f;
        lreg[q] = lreg[q] * __expf(mreg[q] - nm) + e0 + e1;
        mreg[q] = nm;
      }
      ck0 = nk0; ck1 = nk1; ck2 = nk2;
      cur ^= 1;
    }
    // cross-lane merge over lane bits 0-3 (cols)
#pragma unroll
    for (int q = 0; q < 4; ++q) {
      float m = mreg[q], l = lreg[q];
#pragma unroll
      for (int o = 1; o < 16; o <<= 1) {
        float mo = __shfl_xor(m, o, 64);
        float lo = __shfl_xor(l, o, 64);
        float M = fmaxf(m, mo);
        l = l * __expf(m - M) + lo * __expf(mo - M);
        m = M;
      }
      mreg[q] = m; lreg[q] = l;
    }
    __syncthreads();  // last tile's Ks reads done; Vs[0] alias safe to write
    if (lr == 0) {
#pragma unroll
      for (int q = 0; q < 4; ++q)
        sb[kh * 64 + wm + hi * 4 + q] = make_float2(mreg[q], lreg[q]);
    }
    __syncthreads();
    if (w < 4 && lr == 0) {
#pragma unroll
      for (int q = 0; q < 4; ++q) {
        int r = wm + hi * 4 + q;
        float2 a = sb[r], b = sb[64 + r];
        float M = fmaxf(a.x, b.x);
        float L = a.y * __expf(a.x - M) + b.y * __expf(b.x - M);
        statf[r] = make_float2(M, 1.0f / L);
      }
    }
    __syncthreads();
    float mr[4], invl[4];
#pragma unroll
    for (int q = 0; q < 4; ++q) {
      float2 sv = statf[wm + hi * 4 + q];
      mr[q] = sv.x; invl[q] = sv.y;
    }
    __syncthreads();  // stats in regs; Vs[0] free for loop 2

    // ---------- loop 2: normalize + attn write + deferred PV ----------
    f32x4 accp[4];
#pragma unroll
    for (int j = 0; j < 4; j++) { f32x4 z = {0.f, 0.f, 0.f, 0.f}; accp[j] = z; }
    ck0 = *reinterpret_cast<const bf16x8*>(&Kg[(size_t)kr0 * QKD + kc0]);
    ck1 = *reinterpret_cast<const bf16x8*>(&Kg[(size_t)kr1 * QKD + kc1]);
    ck2 = *reinterpret_cast<const bf16x8*>(&Kg[(size_t)kr2 * QKD + kc2]);
    bf16x8 cv0 = *reinterpret_cast<const bf16x8*>(&Vg[(size_t)vr0 * S + vc0]);
    bf16x8 cv1 = *reinterpret_cast<const bf16x8*>(&Vg[(size_t)vr1 * S + vc1]);
    cur = 0;
    int pb = 0;  // triple-buffer index = ti % 3
    for (int ti = 0; ti < ntiles; ++ti) {
      const int kt = ti * 64;
      bf16x8 nk0, nk1, nk2, nv0, nv1;
      if (ti + 1 < ntiles) {  // loads for t+1 issued before this tile's stores
        nk0 = *reinterpret_cast<const bf16x8*>(&Kg[(size_t)(kt + 64 + kr0) * QKD + kc0]);
        nk1 = *reinterpret_cast<const bf16x8*>(&Kg[(size_t)(kt + 64 + kr1) * QKD + kc1]);
        nk2 = *reinterpret_cast<const bf16x8*>(&Kg[(size_t)(kt + 64 + kr2) * QKD + kc2]);
        nv0 = *reinterpret_cast<const bf16x8*>(&Vg[(size_t)vr0 * S + kt + 64 + vc0]);
        nv1 = *reinterpret_cast<const bf16x8*>(&Vg[(size_t)vr1 * S + kt + 64 + vc1]);
      }
      *reinterpret_cast<bf16x8*>(&Ks[cur][kr0 * 200 + kc0]) = ck0;
      *reinterpret_cast<bf16x8*>(&Ks[cur][kr1 * 200 + kc1]) = ck1;
      *reinterpret_cast<bf16x8*>(&Ks[cur][kr2 * 200 + kc2]) = ck2;
      *reinterpret_cast<bf16x8*>(&Vs[pb][vr0 * 72 + vc0]) = cv0;
      *reinterpret_cast<bf16x8*>(&Vs[pb][vr1 * 72 + vc1]) = cv1;
      lgkm_barrier();  // K, V(pb) visible; Ps(prev) visible
      f32x4 acc[2];
#pragma unroll
      for (int kb = 0; kb < 2; kb++) { f32x4 z = {0.f, 0.f, 0.f, 0.f}; acc[kb] = z; }
      __builtin_amdgcn_s_setprio(1);
#pragma unroll
      for (int ks = 0; ks < 6; ++ks) {
#pragma unroll
        for (int kb = 0; kb < 2; ++kb) {
          bf16x8 b = *reinterpret_cast<const bf16x8*>(&Ks[cur][(kh * 32 + kb * 16 + lr) * 200 + ks * 32 + lk]);
          acc[kb] = __builtin_amdgcn_mfma_f32_16x16x32_bf16(qf[ks], b, acc[kb], 0, 0, 0);
        }
      }
      __builtin_amdgcn_s_setprio(0);
      const int colb = kt + kh * 32 + lr;
#pragma unroll
      for (int kb = 0; kb < 2; ++kb) {
#pragma unroll
        for (int q = 0; q < 4; ++q) {
          const int rloc = wm + hi * 4 + q;
          const int rowg = m0 + rloc;
          const int col = colb + kb * 16;
          float s = acc[kb][q] * ATT_SCALE;
          float p = (col <= rowg) ? __expf(s - mr[q]) * invl[q] : 0.f;
          Ah[(size_t)rowg * S + col] = p;
          Ps[pb][rloc * 72 + kh * 32 + kb * 16 + lr] = (bf16)p;
        }
      }
      if (ti > 0) {  // deferred PV for tile ti-1
        const int pp = (pb == 0) ? 2 : pb - 1;
        __builtin_amdgcn_s_setprio(1);
#pragma unroll
        for (int ks = 0; ks < 2; ++ks) {
          bf16x8 a = *reinterpret_cast<const bf16x8*>(&Ps[pp][(wm + lr) * 72 + ks * 32 + lk]);
#pragma unroll
          for (int j = 0; j < 4; ++j) {
            bf16x8 b = *reinterpret_cast<const bf16x8*>(&Vs[pp][(kh * 64 + j * 16 + lr) * 72 + ks * 32 + lk]);
            accp[j] = __builtin_amdgcn_mfma_f32_16x16x32_bf16(a, b, accp[j], 0, 0, 0);
          }
        }
        __builtin_amdgcn_s_setprio(0);
      }
      ck0 = nk0; ck1 = nk1; ck2 = nk2; cv0 = nv0; cv1 = nv1;
      cur ^= 1;
      pb = (pb == 2) ? 0 : pb + 1;
    }
    // epilogue: PV for the last tile
    lgkm_barrier();
    {
      const int pp = (pb == 0) ? 2 : pb - 1;
#pragma unroll
      for (int ks = 0; ks < 2; ++ks) {
        bf16x8 a = *reinterpret_cast<const bf16x8*>(&Ps[pp][(wm + lr) * 72 + ks * 32 + lk]);
#pragma unroll
        for (int j = 0; j < 4; ++j) {
          bf16x8 b = *reinterpret_cast<const bf16x8*>(&Vs[pp][(kh * 64 + j * 16 + lr) * 72 + ks * 32 + lk]);
          accp[j] = __builtin_amdgcn_mfma_f32_16x16x32_bf16(a, b, accp[j], 0, 0, 0);
        }
      }
    }

    // zero-fill causal tail [kend, S) for the strip's 64 rows
    const float4 zz = make_float4(0.f, 0.f, 0.f, 0.f);
    {
      const int zr = t >> 3, zc0 = (t & 7) * 4;
      float* zrow = Ah + (size_t)(m0 + zr) * S;
      for (int k = kend + zc0; k < S; k += 32) *reinterpret_cast<float4*>(zrow + k) = zz;
    }

    // ctx epilogue: wave's 16 rows x 64-d half
#pragma unroll
    for (int j = 0; j < 4; ++j) {
      const int d = kh * 64 + j * 16 + lr;
#pragma unroll
      for (int q = 0; q < 4; ++q) {
        const int rowg = m0 + wm + hi * 4 + q;
        C[(size_t)rowg * Hdim + d] = (bf16)accp[j][q];
      }
    }
  }
}

// ---------------- fused prep: X cast + 8 weight transposes ----------------
struct TJobs {
  const float* src[8];
  bf16* dst[8];
  int R[8], C[8], tiles[8];
};

__global__ __launch_bounds__(256) void prep(const float* __restrict__ Xf,
                                            bf16* __restrict__ Xb, TJobs J) {
  const int t = threadIdx.x;
  int id = blockIdx.x;
  if (id < 2048) {  // cast: 2048 blocks x 256 threads x 8 elems = S*Hdim
    size_t i = (size_t)id * 256 + t;
    float4 f0 = *reinterpret_cast<const float4*>(Xf + i * 8);
    float4 f1 = *reinterpret_cast<const float4*>(Xf + i * 8 + 4);
    bf16x8 v;
    v[0] = (bf16)f0.x; v[1] = (bf16)f0.y; v[2] = (bf16)f0.z; v[3] = (bf16)f0.w;
    v[4] = (bf16)f1.x; v[5] = (bf16)f1.y; v[6] = (bf16)f1.z; v[7] = (bf16)f1.w;
    *reinterpret_cast<bf16x8*>(Xb + i * 8) = v;
    return;
  }
  int tile = id - 2048;
  int j = 0;
  while (tile >= J.tiles[j]) { tile -= J.tiles[j]; ++j; }
  const int C = J.C[j], R = J.R[j];
  int tcn = C >> 5;
  int rb = (tile / tcn) * 32, cb = (tile % tcn) * 32;
  const float* in = J.src[j];
  bf16* out = J.dst[j];
  __shared__ float tl[32][33];
  int tx = t & 31, ty = t >> 5;
#pragma unroll
  for (int q = 0; q < 32; q += 8)
    tl[ty + q][tx] = in[(size_t)(rb + ty + q) * C + cb + tx];
  __syncthreads();
#pragma unroll
  for (int q = 0; q < 32; q += 8)
    out[(size_t)(cb + ty + q) * R + rb + tx] = (bf16)tl[tx][ty + q];
}

// fused RMSNorm for cq (y==0) and ckv (y==1) reading merged dproj
__global__ __launch_bounds__(256) void rmsnorm_fused(const float* __restrict__ dproj,
                                                     const float* __restrict__ qw,
                                                     const float* __restrict__ kw,
                                                     bf16* __restrict__ cqb,
                                                     bf16* __restrict__ ckvb) {
  int row = blockIdx.x;
  bool isq = (blockIdx.y == 0);
  int C = isq ? QC : KVC;
  const float* p = dproj + (size_t)row * DN + (isq ? 0 : QC);
  const float* w = isq ? qw : kw;
  bf16* out = (isq ? cqb : ckvb) + (size_t)row * C;
  float ss = 0.f;
  for (int i = threadIdx.x * 4; i < C; i += 1024) {
    float4 v = *reinterpret_cast<const float4*>(p + i);
    ss += v.x * v.x + v.y * v.y + v.z * v.z + v.w * v.w;
  }
  ss = block_sum(ss);
  float r = rsqrtf(ss / (float)C + RMS_EPS);
  for (int i = threadIdx.x * 4; i < C; i += 1024) {
    float4 v = *reinterpret_cast<const float4*>(p + i);
    float4 g = *reinterpret_cast<const float4*>(w + i);
    bf16x4 o;
    o[0] = (bf16)(v.x * r * g.x); o[1] = (bf16)(v.y * r * g.y);
    o[2] = (bf16)(v.z * r * g.z); o[3] = (bf16)(v.w * r * g.w);
    *reinterpret_cast<bf16x4*>(out + i) = o;
  }
}

// ---------------- fused pack: qpack + kpack + V transpose ----------------
// blocks [0,3072): build_qpack; [3072,3648): build_kpack; [3648,4672): vt
__global__ __launch_bounds__(256) void pack_all(const bf16* __restrict__ up1,
                                                const bf16* __restrict__ up2,
                                                const float* __restrict__ dproj,
                                                const float* __restrict__ cosp,
                                                const float* __restrict__ sinp,
                                                bf16* __restrict__ qpack,
                                                bf16* __restrict__ kpack,
                                                bf16* __restrict__ vt) {
  const int t = threadIdx.x;
  int id = blockIdx.x;
  if (id < 3072) {  // ---- qpack ----
    int idx = id * 256 + t;
    const int P = NH * S * 16;
    if (idx < P) {
      int d8 = idx & 15, s = (idx >> 4) & (S - 1), h = idx >> 15;
      int4 v = *reinterpret_cast<const int4*>(up1 + (size_t)s * 3072 + h * HD + d8 * 8);
      *reinterpret_cast<int4*>(qpack + ((size_t)h * S + s) * QKD + d8 * 8) = v;
    } else {
      int j = idx - P;
      int d0 = (j & 7) * 8, s = (j >> 3) & (S - 1), h = j >> 14;
      const bf16* xr = up1 + (size_t)s * 3072 + 2048 + h * RHD;
      bf16x8 xa = *reinterpret_cast<const bf16x8*>(xr + d0);
      bf16x8 xb = *reinterpret_cast<const bf16x8*>(xr + (d0 ^ 32));
      float sign = (d0 < 32) ? -1.f : 1.f;
      const float* cr = cosp + s * RHD + d0;
      const float* sr = sinp + s * RHD + d0;
      bf16x8 o;
#pragma unroll
      for (int i = 0; i < 8; i++)
        o[i] = (bf16)((float)xa[i] * cr[i] + sign * (float)xb[i] * sr[i]);
      *reinterpret_cast<bf16x8*>(qpack + ((size_t)h * S + s) * QKD + HD + d0) = o;
    }
    return;
  }
  if (id < 3648) {  // ---- kpack ----
    int idx = (id - 3072) * 256 + t;
    const int P = NKV * S * 16;
    if (idx < P) {
      int d8 = idx & 15, s = (idx >> 4) & (S - 1), g = idx >> 15;
      int4 v = *reinterpret_cast<const int4*>(up2 + (size_t)s * 1024 + g * HD + d8 * 8);
      *reinterpret_cast<int4*>(kpack + ((size_t)g * S + s) * QKD + d8 * 8) = v;
    } else {
      int j = idx - P;
      int d0 = (j & 7) * 8, s = j >> 3;
      const float* xr = dproj + (size_t)s * DN + 2048;
      float4 a0 = *reinterpret_cast<const float4*>(xr + d0);
      float4 a1 = *reinterpret_cast<const float4*>(xr + d0 + 4);
      float4 b0 = *reinterpret_cast<const float4*>(xr + (d0 ^ 32));
      float4 b1 = *reinterpret_cast<const float4*>(xr + (d0 ^ 32) + 4);
      float sign = (d0 < 32) ? -1.f : 1.f;
      const float* cr = cosp + s * RHD + d0;
      const float* sr = sinp + s * RHD + d0;
      float xa[8] = {a0.x, a0.y, a0.z, a0.w, a1.x, a1.y, a1.z, a1.w};
      float xb[8] = {b0.x, b0.y, b0.z, b0.w, b1.x, b1.y, b1.z, b1.w};
      bf16x8 o;
#pragma unroll
      for (int i = 0; i < 8; i++)
        o[i] = (bf16)(xa[i] * cr[i] + sign * xb[i] * sr[i]);
#pragma unroll
      for (int g = 0; g < NKV; g++)
        *reinterpret_cast<bf16x8*>(kpack + ((size_t)g * S + s) * QKD + HD + d0) = o;
    }
    return;
  }
  // ---- V transpose: up2[s][512+c] -> vt[c][s], tiles 16 x 64 ----
  int tile = id - 3648;
  int cb = (tile & 15) * 32;   // source col block (0..511)
  int rb = (tile >> 4) * 32;   // source row block (0..2047)
  __shared__ float tl[32][33];
  int tx = t & 31, ty = t >> 5;
  const bf16* in = up2 + 512;
#pragma unroll
  for (int q = 0; q < 32; q += 8)
    tl[ty + q][tx] = (float)in[(size_t)(rb + ty + q) * 1024 + cb + tx];
  __syncthreads();
#pragma unroll
  for (int q = 0; q < 32; q += 8)
    vt[(size_t)(cb + ty + q) * S + rb + tx] = (bf16)tl[tx][ty + q];
}

// ---------------- launcher ----------------
extern "C" void kernel_launch(void* const* d_in, const int* in_sizes, int n_in, void* d_out,
                              int out_size, void* d_ws, size_t ws_size, hipStream_t stream) {
  const float* Xf = (const float*)d_in[0];
  const float* cosp = (const float*)d_in[1];
  const float* sinp = (const float*)d_in[2];
  const float* w_down_q = (const float*)d_in[4];
  const float* w_up_q = (const float*)d_in[5];
  const float* w_qr = (const float*)d_in[6];
  const float* w_down_kv = (const float*)d_in[7];
  const float* w_up_k = (const float*)d_in[8];
  const float* w_up_v = (const float*)d_in[9];
  const float* w_kr = (const float*)d_in[10];
  const float* w_o = (const float*)d_in[11];
  const float* q_norm_w = (const float*)d_in[12];
  const float* k_norm_w = (const float*)d_in[13];

  float* out0 = (float*)d_out;
  float* attn = out0 + (size_t)S * Hdim;

  char* base = (char*)d_ws;
  size_t off = 0;
  auto carve = [&](size_t bytes) -> void* {
    void* p = base + off;
    off += (bytes + 255) & ~(size_t)255;
    return p;
  };
  bf16* Xb      = (bf16*)carve((size_t)S * Hdim * 2);
  bf16* wt_down = (bf16*)carve((size_t)2176 * 2048 * 2);  // [2112(+pad)][2048]
  bf16* wt_up1  = (bf16*)carve((size_t)3072 * QC * 2);    // [3072][1536]
  bf16* wt_up2  = (bf16*)carve((size_t)1024 * KVC * 2);   // [1024][512]
  bf16* wt_o    = (bf16*)carve((size_t)Hdim * Hdim * 2);
  float* dproj  = (float*)carve((size_t)S * DN * 4);      // [2048][2112]
  bf16* cqb     = (bf16*)carve((size_t)S * QC * 2);
  bf16* ckvb    = (bf16*)carve((size_t)S * KVC * 2);
  bf16* up1     = (bf16*)carve((size_t)S * 3072 * 2);     // [s][qc 0:2048 | qr 2048:3072]
  bf16* up2     = (bf16*)carve((size_t)S * 1024 * 2);     // [s][kc 0:512 | v 512:1024]
  bf16* qpack   = (bf16*)carve((size_t)NH * S * QKD * 2);
  bf16* kpack   = (bf16*)carve((size_t)NKV * S * QKD * 2);
  bf16* vt      = (bf16*)carve((size_t)NKV * HD * S * 2);
  bf16* ctxb    = (bf16*)carve((size_t)S * Hdim * 2);
  (void)in_sizes; (void)n_in; (void)out_size; (void)ws_size;

  TJobs J;
  const float* srcs[8] = {w_down_q, w_down_kv, w_kr, w_up_q, w_qr, w_up_k, w_up_v, w_o};
  bf16* dsts[8] = {wt_down, wt_down + (size_t)QC * 2048, wt_down + (size_t)2048 * 2048,
                   wt_up1, wt_up1 + (size_t)2048 * QC, wt_up2, wt_up2 + (size_t)512 * KVC, wt_o};
  int Rs[8] = {2048, 2048, 2048, 1536, 1536, 512, 512, 2048};
  int Cs[8] = {1536, 512, 64, 2048, 1024, 512, 512, 2048};
  int total_tiles = 0;
  for (int j = 0; j < 8; j++) {
    J.src[j] = srcs[j]; J.dst[j] = dsts[j]; J.R[j] = Rs[j]; J.C[j] = Cs[j];
    J.tiles[j] = (Rs[j] / 32) * (Cs[j] / 32);
    total_tiles += J.tiles[j];
  }

  // 1. prep: X cast + all weight transposes
  prep<<<2048 + total_tiles, 256, 0, stream>>>(Xf, Xb, J);
  // 2. merged down projection: [S][2112] = Xb @ [wdq | wdkv | wkr]
  gemm_nt<float><<<dim3(17, 16), 256, 0, stream>>>(Xb, wt_down, dproj, DN, Hdim, Hdim, Hdim, DN, 1.f);
  // 3. both RMSNorms
  rmsnorm_fused<<<dim3(S, 2), 256, 0, stream>>>(dproj, q_norm_w, k_norm_w, cqb, ckvb);
  // 4. both up projections
  gemm_up_both<<<512, 256, 0, stream>>>(cqb, ckvb, wt_up1, wt_up2, up1, up2);
  // 5. pack q/k + RoPE + V transpose
  pack_all<<<4672, 256, 0, stream>>>(up1, up2, dproj, cosp, sinp, qpack, kpack, vt);
  // 6. fused flash attention (deep-pipelined: Q-in-regs, deferred PV, 1 barrier/tile)
  fa_fused<<<dim3(16, NH), 512, 0, stream>>>(qpack, kpack, vt, attn, ctxb);
  // 7. output projection
  gemm_nt<float><<<dim3(16, 16), 256, 0, stream>>>(ctxb, wt_o, out0, Hdim, Hdim, Hdim, Hdim, Hdim, 1.f);
}

// Round 19
// 290.346 us; speedup vs baseline: 1.1933x; 1.0557x over previous
//
#include <hip/hip_runtime.h>
#include <stdint.h>

typedef __bf16 bf16;
typedef __bf16 bf16x8 __attribute__((ext_vector_type(8)));
typedef __bf16 bf16x4 __attribute__((ext_vector_type(4)));
typedef float f32x4 __attribute__((ext_vector_type(4)));

#define DEVFN static __device__ __forceinline__

constexpr int S = 2048, Hdim = 2048, NH = 16, NKV = 4, HD = 128, RHD = 64, QC = 1536, KVC = 512;
constexpr int QKD = HD + RHD;                 // 192
constexpr int DN = 2112;                      // merged down-proj width: QC + KVC + RHD
constexpr float RMS_EPS = 1e-6f;
constexpr float ATT_SCALE = 0.07216878364870323f;  // 1/sqrt(192)

// ---------------- reductions ----------------
DEVFN float wave_sum(float v) {
#pragma unroll
  for (int o = 32; o > 0; o >>= 1) v += __shfl_xor(v, o, 64);
  return v;
}
DEVFN float block_sum(float v) {
  __shared__ float red_s[4];
  v = wave_sum(v);
  int lane = threadIdx.x & 63, wid = threadIdx.x >> 6;
  if (lane == 0) red_s[wid] = v;
  __syncthreads();
  v = red_s[0] + red_s[1] + red_s[2] + red_s[3];
  __syncthreads();
  return v;
}

DEVFN void lgkm_barrier() {
  asm volatile("s_waitcnt lgkmcnt(0)" ::: "memory");
  __builtin_amdgcn_s_barrier();
}

// ---------------- pipelined GEMM core: C = A[M,K] * Bt[N,K]^T ----------------
// 128x128 tile, BK=32, 4 waves 2x2. Reg-staged DEPTH-2 prefetch: loads for
// step t+2 issue at step t (two in-flight register sets -> ~256+ cycles of
// latency cover), LDS double-buffered, ONE lgkm-only barrier per step.
// WAR safe: buf rewrite at t+2 separated from read at t by barrier at t+1.
template <typename OT>
DEVFN void gemm_core_pipe(const bf16* __restrict__ A, const bf16* __restrict__ Bt,
                          OT* __restrict__ C, int N, int lda, int ldb, int ldc,
                          int m0, int n0, float scale, int kend) {
  __shared__ alignas(16) bf16 As[2][128 * 32];
  __shared__ alignas(16) bf16 Bs[2][128 * 32];
  const int t = threadIdx.x;
  const int lane = t & 63;
  const int wm = ((t >> 7) & 1) * 64;
  const int wn = ((t >> 6) & 1) * 64;
  const int lr = lane & 15;
  const int lk = (lane >> 4) * 8;
  const int srow = t >> 2;
  const int scol = (t & 3) * 8;
  const bf16* A0 = A + (size_t)(m0 + srow) * lda + scol;
  const bf16* A1 = A + (size_t)(m0 + 64 + srow) * lda + scol;
  const bf16* B0 = Bt + (size_t)(n0 + srow) * ldb + scol;
  const bf16* B1 = Bt + (size_t)(n0 + 64 + srow) * ldb + scol;

  f32x4 acc[4][4];
#pragma unroll
  for (int i = 0; i < 4; i++)
#pragma unroll
    for (int j = 0; j < 4; j++) { f32x4 z = {0.f, 0.f, 0.f, 0.f}; acc[i][j] = z; }

  // depth-2 prologue: steps 0 and 1 in flight
  bf16x8 ca0 = *reinterpret_cast<const bf16x8*>(A0);
  bf16x8 ca1 = *reinterpret_cast<const bf16x8*>(A1);
  bf16x8 cb0 = *reinterpret_cast<const bf16x8*>(B0);
  bf16x8 cb1 = *reinterpret_cast<const bf16x8*>(B1);
  bf16x8 ma0, ma1, mb0, mb1;
  if (32 < kend) {
    ma0 = *reinterpret_cast<const bf16x8*>(A0 + 32);
    ma1 = *reinterpret_cast<const bf16x8*>(A1 + 32);
    mb0 = *reinterpret_cast<const bf16x8*>(B0 + 32);
    mb1 = *reinterpret_cast<const bf16x8*>(B1 + 32);
  }
  int cur = 0;
  for (int kk = 0; kk < kend; kk += 32) {
    bf16x8 na0, na1, nb0, nb1;
    if (kk + 64 < kend) {  // issue loads for step t+2 before this step's stores
      na0 = *reinterpret_cast<const bf16x8*>(A0 + kk + 64);
      na1 = *reinterpret_cast<const bf16x8*>(A1 + kk + 64);
      nb0 = *reinterpret_cast<const bf16x8*>(B0 + kk + 64);
      nb1 = *reinterpret_cast<const bf16x8*>(B1 + kk + 64);
    }
    *reinterpret_cast<bf16x8*>(&As[cur][t * 8]) = ca0;
    *reinterpret_cast<bf16x8*>(&As[cur][t * 8 + 2048]) = ca1;
    *reinterpret_cast<bf16x8*>(&Bs[cur][t * 8]) = cb0;
    *reinterpret_cast<bf16x8*>(&Bs[cur][t * 8 + 2048]) = cb1;
    lgkm_barrier();
    bf16x8 a[4], b[4];
#pragma unroll
    for (int i = 0; i < 4; i++)
      a[i] = *reinterpret_cast<const bf16x8*>(&As[cur][(wm + i * 16 + lr) * 32 + lk]);
#pragma unroll
    for (int i = 0; i < 4; i++)
      b[i] = *reinterpret_cast<const bf16x8*>(&Bs[cur][(wn + i * 16 + lr) * 32 + lk]);
    __builtin_amdgcn_s_setprio(1);
#pragma unroll
    for (int i = 0; i < 4; i++)
#pragma unroll
      for (int j = 0; j < 4; j++)
        acc[i][j] = __builtin_amdgcn_mfma_f32_16x16x32_bf16(a[i], b[j], acc[i][j], 0, 0, 0);
    __builtin_amdgcn_s_setprio(0);
    ca0 = ma0; ca1 = ma1; cb0 = mb0; cb1 = mb1;
    ma0 = na0; ma1 = na1; mb0 = nb0; mb1 = nb1;
    cur ^= 1;
  }
  const int orow = (lane >> 4) * 4;
#pragma unroll
  for (int i = 0; i < 4; i++) {
#pragma unroll
    for (int j = 0; j < 4; j++) {
      int col = n0 + wn + j * 16 + lr;
      if (col < N) {
#pragma unroll
        for (int q = 0; q < 4; q++) {
          int row = m0 + wm + i * 16 + orow + q;
          C[(size_t)row * ldc + col] = (OT)(acc[i][j][q] * scale);
        }
      }
    }
  }
}

template <typename OT>
__global__ __launch_bounds__(256) void gemm_nt(const bf16* __restrict__ A, const bf16* __restrict__ Bt,
                                               OT* __restrict__ C, int N, int K, int lda,
                                               int ldb, int ldc, float scale) {
  gemm_core_pipe<OT>(A, Bt, C, N, lda, ldb, ldc, blockIdx.y * 128, blockIdx.x * 128, scale, K);
}

// up1 (384 blocks) + up2 (128 blocks) in one launch
__global__ __launch_bounds__(256) void gemm_up_both(const bf16* __restrict__ cqb,
                                                    const bf16* __restrict__ ckvb,
                                                    const bf16* __restrict__ wt_up1,
                                                    const bf16* __restrict__ wt_up2,
                                                    bf16* __restrict__ up1,
                                                    bf16* __restrict__ up2) {
  int id = blockIdx.x;
  if (id < 384) {
    gemm_core_pipe<bf16>(cqb, wt_up1, up1, 3072, QC, QC, 3072, (id / 24) * 128, (id % 24) * 128, 1.f, QC);
  } else {
    id -= 384;
    gemm_core_pipe<bf16>(ckvb, wt_up2, up2, 1024, KVC, KVC, 1024, (id / 8) * 128, (id % 8) * 128, 1.f, KVC);
  }
}

// ============== Fused flash attention, deep-pipelined (round-13 proven) =====
// Grid (16, NH), 512 threads (8 waves: 4 row-groups x 2 k-halves).
// Block = balanced strip pair (64*i rows and 1984-64*i), 33 k-tiles total.
// Q fragments in REGISTERS; K double-buffered, V/Ps TRIPLE-buffered;
// reg-staged async split; deferred PV -> ONE lgkm barrier per tile.
__global__ __launch_bounds__(512) void fa_fused(const bf16* __restrict__ qpack,
                                                const bf16* __restrict__ kpack,
                                                const bf16* __restrict__ vt,
                                                float* __restrict__ attn,
                                                bf16* __restrict__ ctxb) {
  const int h = blockIdx.y;
  const int g = h >> 2;
  __shared__ alignas(16) bf16 Ks[2][64 * 200];
  __shared__ alignas(16) bf16 Vs[3][128 * 72];
  __shared__ alignas(16) bf16 Ps[3][64 * 72];
  float2* sb = reinterpret_cast<float2*>(&Vs[0][0]);   // [0..127] per-half merge
  float2* statf = sb + 128;                            // [0..63] final (m, 1/l)

  const int t = threadIdx.x;
  const int lane = t & 63;
  const int w = t >> 6;
  const int wm = (w & 3) * 16;     // row-group base within strip
  const int kh = w >> 2;           // k-half (QK) / d-half (PV)
  const int lr = lane & 15;
  const int hi = lane >> 4;
  const int lk = hi * 8;
  const int kr0 = t / 24, kc0 = (t % 24) * 8;
  const int kr1 = (t + 512) / 24, kc1 = ((t + 512) % 24) * 8;
  const int kr2 = (t + 1024) / 24, kc2 = ((t + 1024) % 24) * 8;
  const int vr0 = t >> 3, vc0 = (t & 7) * 8;
  const int vr1 = (t + 512) >> 3, vc1 = ((t + 512) & 7) * 8;

  const bf16* Qg = qpack + (size_t)h * S * QKD;
  const bf16* Kg = kpack + (size_t)g * S * QKD;
  const bf16* Vg = vt + (size_t)g * HD * S;
  float* Ah = attn + (size_t)h * S * S;
  bf16* C = ctxb + h * HD;

  for (int sub = 0; sub < 2; ++sub) {
    const int m0 = sub ? (1984 - 64 * blockIdx.x) : (64 * blockIdx.x);
    const int ntiles = sub ? (32 - blockIdx.x) : (blockIdx.x + 1);
    const int kend = m0 + 64;
    __syncthreads();  // prev sub's LDS reads done

    // Q fragments -> registers (once per strip)
    bf16x8 qf[6];
#pragma unroll
    for (int ks = 0; ks < 6; ++ks)
      qf[ks] = *reinterpret_cast<const bf16x8*>(&Qg[(size_t)(m0 + wm + lr) * QKD + ks * 32 + lk]);

    // ---------- loop 1: stats ----------
    float mreg[4] = {-1e30f, -1e30f, -1e30f, -1e30f};
    float lreg[4] = {0.f, 0.f, 0.f, 0.f};
    bf16x8 ck0 = *reinterpret_cast<const bf16x8*>(&Kg[(size_t)kr0 * QKD + kc0]);
    bf16x8 ck1 = *reinterpret_cast<const bf16x8*>(&Kg[(size_t)kr1 * QKD + kc1]);
    bf16x8 ck2 = *reinterpret_cast<const bf16x8*>(&Kg[(size_t)kr2 * QKD + kc2]);
    int cur = 0;
    for (int ti = 0; ti < ntiles; ++ti) {
      const int kt = ti * 64;
      bf16x8 nk0, nk1, nk2;
      if (ti + 1 < ntiles) {
        nk0 = *reinterpret_cast<const bf16x8*>(&Kg[(size_t)(kt + 64 + kr0) * QKD + kc0]);
        nk1 = *reinterpret_cast<const bf16x8*>(&Kg[(size_t)(kt + 64 + kr1) * QKD + kc1]);
        nk2 = *reinterpret_cast<const bf16x8*>(&Kg[(size_t)(kt + 64 + kr2) * QKD + kc2]);
      }
      *reinterpret_cast<bf16x8*>(&Ks[cur][kr0 * 200 + kc0]) = ck0;
      *reinterpret_cast<bf16x8*>(&Ks[cur][kr1 * 200 + kc1]) = ck1;
      *reinterpret_cast<bf16x8*>(&Ks[cur][kr2 * 200 + kc2]) = ck2;
      lgkm_barrier();
      f32x4 acc[2];
#pragma unroll
      for (int kb = 0; kb < 2; kb++) { f32x4 z = {0.f, 0.f, 0.f, 0.f}; acc[kb] = z; }
      __builtin_amdgcn_s_setprio(1);
#pragma unroll
      for (int ks = 0; ks < 6; ++ks) {
#pragma unroll
        for (int kb = 0; kb < 2; ++kb) {
          bf16x8 b = *reinterpret_cast<const bf16x8*>(&Ks[cur][(kh * 32 + kb * 16 + lr) * 200 + ks * 32 + lk]);
          acc[kb] = __builtin_amdgcn_mfma_f32_16x16x32_bf16(qf[ks], b, acc[kb], 0, 0, 0);
        }
      }
      __builtin_amdgcn_s_setprio(0);
      const int colb = kt + kh * 32 + lr;
#pragma unroll
      for (int q = 0; q < 4; ++q) {
        const int rowg = m0 + wm + hi * 4 + q;
        bool u0 = (colb <= rowg), u1 = (colb + 16 <= rowg);
        float s0 = u0 ? acc[0][q] * ATT_SCALE : -1e30f;
        float s1 = u1 ? acc[1][q] * ATT_SCALE : -1e30f;
        float nm = fmaxf(mreg[q], fmaxf(s0, s1));
        float e0 = u0 ? __expf(s0 - nm) : 0.f;
        float e1 = u1 ? __expf(s1 - nm) : 0.f;
        lreg[q] = lreg[q] * __expf(mreg[q] - nm) + e0 + e1;
        mreg[q] = nm;
      }
      ck0 = nk0; ck1 = nk1; ck2 = nk2;
      cur ^= 1;
    }
    // cross-lane merge over lane bits 0-3 (cols)
#pragma unroll
    for (int q = 0; q < 4; ++q) {
      float m = mreg[q], l = lreg[q];
#pragma unroll
      for (int o = 1; o < 16; o <<= 1) {
        float mo = __shfl_xor(m, o, 64);
        float lo = __shfl_xor(l, o, 64);
        float M = fmaxf(m, mo);
        l = l * __expf(m - M) + lo * __expf(mo - M);
        m = M;
      }
      mreg[q] = m; lreg[q] = l;
    }
    __syncthreads();  // last tile's Ks reads done; Vs[0] alias safe to write
    if (lr == 0) {
#pragma unroll
      for (int q = 0; q < 4; ++q)
        sb[kh * 64 + wm + hi * 4 + q] = make_float2(mreg[q], lreg[q]);
    }
    __syncthreads();
    if (w < 4 && lr == 0) {
#pragma unroll
      for (int q = 0; q < 4; ++q) {
        int r = wm + hi * 4 + q;
        float2 a = sb[r], b = sb[64 + r];
        float M = fmaxf(a.x, b.x);
        float L = a.y * __expf(a.x - M) + b.y * __expf(b.x - M);
        statf[r] = make_float2(M, 1.0f / L);
      }
    }
    __syncthreads();
    float mr[4], invl[4];
#pragma unroll
    for (int q = 0; q < 4; ++q) {
      float2 sv = statf[wm + hi * 4 + q];
      mr[q] = sv.x; invl[q] = sv.y;
    }
    __syncthreads();  // stats in regs; Vs[0] free for loop 2

    // ---------- loop 2: normalize + attn write + deferred PV ----------
    f32x4 accp[4];
#pragma unroll
    for (int j = 0; j < 4; j++) { f32x4 z = {0.f, 0.f, 0.f, 0.f}; accp[j] = z; }
    ck0 = *reinterpret_cast<const bf16x8*>(&Kg[(size_t)kr0 * QKD + kc0]);
    ck1 = *reinterpret_cast<const bf16x8*>(&Kg[(size_t)kr1 * QKD + kc1]);
    ck2 = *reinterpret_cast<const bf16x8*>(&Kg[(size_t)kr2 * QKD + kc2]);
    bf16x8 cv0 = *reinterpret_cast<const bf16x8*>(&Vg[(size_t)vr0 * S + vc0]);
    bf16x8 cv1 = *reinterpret_cast<const bf16x8*>(&Vg[(size_t)vr1 * S + vc1]);
    cur = 0;
    int pb = 0;  // triple-buffer index = ti % 3
    for (int ti = 0; ti < ntiles; ++ti) {
      const int kt = ti * 64;
      bf16x8 nk0, nk1, nk2, nv0, nv1;
      if (ti + 1 < ntiles) {  // loads for t+1 issued before this tile's stores
        nk0 = *reinterpret_cast<const bf16x8*>(&Kg[(size_t)(kt + 64 + kr0) * QKD + kc0]);
        nk1 = *reinterpret_cast<const bf16x8*>(&Kg[(size_t)(kt + 64 + kr1) * QKD + kc1]);
        nk2 = *reinterpret_cast<const bf16x8*>(&Kg[(size_t)(kt + 64 + kr2) * QKD + kc2]);
        nv0 = *reinterpret_cast<const bf16x8*>(&Vg[(size_t)vr0 * S + kt + 64 + vc0]);
        nv1 = *reinterpret_cast<const bf16x8*>(&Vg[(size_t)vr1 * S + kt + 64 + vc1]);
      }
      *reinterpret_cast<bf16x8*>(&Ks[cur][kr0 * 200 + kc0]) = ck0;
      *reinterpret_cast<bf16x8*>(&Ks[cur][kr1 * 200 + kc1]) = ck1;
      *reinterpret_cast<bf16x8*>(&Ks[cur][kr2 * 200 + kc2]) = ck2;
      *reinterpret_cast<bf16x8*>(&Vs[pb][vr0 * 72 + vc0]) = cv0;
      *reinterpret_cast<bf16x8*>(&Vs[pb][vr1 * 72 + vc1]) = cv1;
      lgkm_barrier();  // K, V(pb) visible; Ps(prev) visible
      f32x4 acc[2];
#pragma unroll
      for (int kb = 0; kb < 2; kb++) { f32x4 z = {0.f, 0.f, 0.f, 0.f}; acc[kb] = z; }
      __builtin_amdgcn_s_setprio(1);
#pragma unroll
      for (int ks = 0; ks < 6; ++ks) {
#pragma unroll
        for (int kb = 0; kb < 2; ++kb) {
          bf16x8 b = *reinterpret_cast<const bf16x8*>(&Ks[cur][(kh * 32 + kb * 16 + lr) * 200 + ks * 32 + lk]);
          acc[kb] = __builtin_amdgcn_mfma_f32_16x16x32_bf16(qf[ks], b, acc[kb], 0, 0, 0);
        }
      }
      __builtin_amdgcn_s_setprio(0);
      const int colb = kt + kh * 32 + lr;
#pragma unroll
      for (int kb = 0; kb < 2; ++kb) {
#pragma unroll
        for (int q = 0; q < 4; ++q) {
          const int rloc = wm + hi * 4 + q;
          const int rowg = m0 + rloc;
          const int col = colb + kb * 16;
          float s = acc[kb][q] * ATT_SCALE;
          float p = (col <= rowg) ? __expf(s - mr[q]) * invl[q] : 0.f;
          Ah[(size_t)rowg * S + col] = p;
          Ps[pb][rloc * 72 + kh * 32 + kb * 16 + lr] = (bf16)p;
        }
      }
      if (ti > 0) {  // deferred PV for tile ti-1
        const int pp = (pb == 0) ? 2 : pb - 1;
        __builtin_amdgcn_s_setprio(1);
#pragma unroll
        for (int ks = 0; ks < 2; ++ks) {
          bf16x8 a = *reinterpret_cast<const bf16x8*>(&Ps[pp][(wm + lr) * 72 + ks * 32 + lk]);
#pragma unroll
          for (int j = 0; j < 4; ++j) {
            bf16x8 b = *reinterpret_cast<const bf16x8*>(&Vs[pp][(kh * 64 + j * 16 + lr) * 72 + ks * 32 + lk]);
            accp[j] = __builtin_amdgcn_mfma_f32_16x16x32_bf16(a, b, accp[j], 0, 0, 0);
          }
        }
        __builtin_amdgcn_s_setprio(0);
      }
      ck0 = nk0; ck1 = nk1; ck2 = nk2; cv0 = nv0; cv1 = nv1;
      cur ^= 1;
      pb = (pb == 2) ? 0 : pb + 1;
    }
    // epilogue: PV for the last tile
    lgkm_barrier();
    {
      const int pp = (pb == 0) ? 2 : pb - 1;
#pragma unroll
      for (int ks = 0; ks < 2; ++ks) {
        bf16x8 a = *reinterpret_cast<const bf16x8*>(&Ps[pp][(wm + lr) * 72 + ks * 32 + lk]);
#pragma unroll
        for (int j = 0; j < 4; ++j) {
          bf16x8 b = *reinterpret_cast<const bf16x8*>(&Vs[pp][(kh * 64 + j * 16 + lr) * 72 + ks * 32 + lk]);
          accp[j] = __builtin_amdgcn_mfma_f32_16x16x32_bf16(a, b, accp[j], 0, 0, 0);
        }
      }
    }

    // zero-fill causal tail [kend, S) for the strip's 64 rows
    const float4 zz = make_float4(0.f, 0.f, 0.f, 0.f);
    {
      const int zr = t >> 3, zc0 = (t & 7) * 4;
      float* zrow = Ah + (size_t)(m0 + zr) * S;
      for (int k = kend + zc0; k < S; k += 32) *reinterpret_cast<float4*>(zrow + k) = zz;
    }

    // ctx epilogue: wave's 16 rows x 64-d half
#pragma unroll
    for (int j = 0; j < 4; ++j) {
      const int d = kh * 64 + j * 16 + lr;
#pragma unroll
      for (int q = 0; q < 4; ++q) {
        const int rowg = m0 + wm + hi * 4 + q;
        C[(size_t)rowg * Hdim + d] = (bf16)accp[j][q];
      }
    }
  }
}

// ---------------- fused prep: X cast + 8 weight transposes ----------------
struct TJobs {
  const float* src[8];
  bf16* dst[8];
  int R[8], C[8], tiles[8];
};

__global__ __launch_bounds__(256) void prep(const float* __restrict__ Xf,
                                            bf16* __restrict__ Xb, TJobs J) {
  const int t = threadIdx.x;
  int id = blockIdx.x;
  if (id < 2048) {  // cast: 2048 blocks x 256 threads x 8 elems = S*Hdim
    size_t i = (size_t)id * 256 + t;
    float4 f0 = *reinterpret_cast<const float4*>(Xf + i * 8);
    float4 f1 = *reinterpret_cast<const float4*>(Xf + i * 8 + 4);
    bf16x8 v;
    v[0] = (bf16)f0.x; v[1] = (bf16)f0.y; v[2] = (bf16)f0.z; v[3] = (bf16)f0.w;
    v[4] = (bf16)f1.x; v[5] = (bf16)f1.y; v[6] = (bf16)f1.z; v[7] = (bf16)f1.w;
    *reinterpret_cast<bf16x8*>(Xb + i * 8) = v;
    return;
  }
  int tile = id - 2048;
  int j = 0;
  while (tile >= J.tiles[j]) { tile -= J.tiles[j]; ++j; }
  const int C = J.C[j], R = J.R[j];
  int tcn = C >> 5;
  int rb = (tile / tcn) * 32, cb = (tile % tcn) * 32;
  const float* in = J.src[j];
  bf16* out = J.dst[j];
  __shared__ float tl[32][33];
  int tx = t & 31, ty = t >> 5;
#pragma unroll
  for (int q = 0; q < 32; q += 8)
    tl[ty + q][tx] = in[(size_t)(rb + ty + q) * C + cb + tx];
  __syncthreads();
#pragma unroll
  for (int q = 0; q < 32; q += 8)
    out[(size_t)(cb + ty + q) * R + rb + tx] = (bf16)tl[tx][ty + q];
}

// fused RMSNorm for cq (y==0) and ckv (y==1) reading merged dproj
__global__ __launch_bounds__(256) void rmsnorm_fused(const float* __restrict__ dproj,
                                                     const float* __restrict__ qw,
                                                     const float* __restrict__ kw,
                                                     bf16* __restrict__ cqb,
                                                     bf16* __restrict__ ckvb) {
  int row = blockIdx.x;
  bool isq = (blockIdx.y == 0);
  int C = isq ? QC : KVC;
  const float* p = dproj + (size_t)row * DN + (isq ? 0 : QC);
  const float* w = isq ? qw : kw;
  bf16* out = (isq ? cqb : ckvb) + (size_t)row * C;
  float ss = 0.f;
  for (int i = threadIdx.x * 4; i < C; i += 1024) {
    float4 v = *reinterpret_cast<const float4*>(p + i);
    ss += v.x * v.x + v.y * v.y + v.z * v.z + v.w * v.w;
  }
  ss = block_sum(ss);
  float r = rsqrtf(ss / (float)C + RMS_EPS);
  for (int i = threadIdx.x * 4; i < C; i += 1024) {
    float4 v = *reinterpret_cast<const float4*>(p + i);
    float4 g = *reinterpret_cast<const float4*>(w + i);
    bf16x4 o;
    o[0] = (bf16)(v.x * r * g.x); o[1] = (bf16)(v.y * r * g.y);
    o[2] = (bf16)(v.z * r * g.z); o[3] = (bf16)(v.w * r * g.w);
    *reinterpret_cast<bf16x4*>(out + i) = o;
  }
}

// ---------------- fused pack: qpack + kpack + V transpose ----------------
// blocks [0,3072): build_qpack; [3072,3648): build_kpack; [3648,4672): vt
__global__ __launch_bounds__(256) void pack_all(const bf16* __restrict__ up1,
                                                const bf16* __restrict__ up2,
                                                const float* __restrict__ dproj,
                                                const float* __restrict__ cosp,
                                                const float* __restrict__ sinp,
                                                bf16* __restrict__ qpack,
                                                bf16* __restrict__ kpack,
                                                bf16* __restrict__ vt) {
  const int t = threadIdx.x;
  int id = blockIdx.x;
  if (id < 3072) {  // ---- qpack ----
    int idx = id * 256 + t;
    const int P = NH * S * 16;
    if (idx < P) {
      int d8 = idx & 15, s = (idx >> 4) & (S - 1), h = idx >> 15;
      int4 v = *reinterpret_cast<const int4*>(up1 + (size_t)s * 3072 + h * HD + d8 * 8);
      *reinterpret_cast<int4*>(qpack + ((size_t)h * S + s) * QKD + d8 * 8) = v;
    } else {
      int j = idx - P;
      int d0 = (j & 7) * 8, s = (j >> 3) & (S - 1), h = j >> 14;
      const bf16* xr = up1 + (size_t)s * 3072 + 2048 + h * RHD;
      bf16x8 xa = *reinterpret_cast<const bf16x8*>(xr + d0);
      bf16x8 xb = *reinterpret_cast<const bf16x8*>(xr + (d0 ^ 32));
      float sign = (d0 < 32) ? -1.f : 1.f;
      const float* cr = cosp + s * RHD + d0;
      const float* sr = sinp + s * RHD + d0;
      bf16x8 o;
#pragma unroll
      for (int i = 0; i < 8; i++)
        o[i] = (bf16)((float)xa[i] * cr[i] + sign * (float)xb[i] * sr[i]);
      *reinterpret_cast<bf16x8*>(qpack + ((size_t)h * S + s) * QKD + HD + d0) = o;
    }
    return;
  }
  if (id < 3648) {  // ---- kpack ----
    int idx = (id - 3072) * 256 + t;
    const int P = NKV * S * 16;
    if (idx < P) {
      int d8 = idx & 15, s = (idx >> 4) & (S - 1), g = idx >> 15;
      int4 v = *reinterpret_cast<const int4*>(up2 + (size_t)s * 1024 + g * HD + d8 * 8);
      *reinterpret_cast<int4*>(kpack + ((size_t)g * S + s) * QKD + d8 * 8) = v;
    } else {
      int j = idx - P;
      int d0 = (j & 7) * 8, s = j >> 3;
      const float* xr = dproj + (size_t)s * DN + 2048;
      float4 a0 = *reinterpret_cast<const float4*>(xr + d0);
      float4 a1 = *reinterpret_cast<const float4*>(xr + d0 + 4);
      float4 b0 = *reinterpret_cast<const float4*>(xr + (d0 ^ 32));
      float4 b1 = *reinterpret_cast<const float4*>(xr + (d0 ^ 32) + 4);
      float sign = (d0 < 32) ? -1.f : 1.f;
      const float* cr = cosp + s * RHD + d0;
      const float* sr = sinp + s * RHD + d0;
      float xa[8] = {a0.x, a0.y, a0.z, a0.w, a1.x, a1.y, a1.z, a1.w};
      float xb[8] = {b0.x, b0.y, b0.z, b0.w, b1.x, b1.y, b1.z, b1.w};
      bf16x8 o;
#pragma unroll
      for (int i = 0; i < 8; i++)
        o[i] = (bf16)(xa[i] * cr[i] + sign * xb[i] * sr[i]);
#pragma unroll
      for (int g = 0; g < NKV; g++)
        *reinterpret_cast<bf16x8*>(kpack + ((size_t)g * S + s) * QKD + HD + d0) = o;
    }
    return;
  }
  // ---- V transpose: up2[s][512+c] -> vt[c][s], tiles 16 x 64 ----
  int tile = id - 3648;
  int cb = (tile & 15) * 32;   // source col block (0..511)
  int rb = (tile >> 4) * 32;   // source row block (0..2047)
  __shared__ float tl[32][33];
  int tx = t & 31, ty = t >> 5;
  const bf16* in = up2 + 512;
#pragma unroll
  for (int q = 0; q < 32; q += 8)
    tl[ty + q][tx] = (float)in[(size_t)(rb + ty + q) * 1024 + cb + tx];
  __syncthreads();
#pragma unroll
  for (int q = 0; q < 32; q += 8)
    vt[(size_t)(cb + ty + q) * S + rb + tx] = (bf16)tl[tx][ty + q];
}

// ---------------- launcher ----------------
extern "C" void kernel_launch(void* const* d_in, const int* in_sizes, int n_in, void* d_out,
                              int out_size, void* d_ws, size_t ws_size, hipStream_t stream) {
  const float* Xf = (const float*)d_in[0];
  const float* cosp = (const float*)d_in[1];
  const float* sinp = (const float*)d_in[2];
  const float* w_down_q = (const float*)d_in[4];
  const float* w_up_q = (const float*)d_in[5];
  const float* w_qr = (const float*)d_in[6];
  const float* w_down_kv = (const float*)d_in[7];
  const float* w_up_k = (const float*)d_in[8];
  const float* w_up_v = (const float*)d_in[9];
  const float* w_kr = (const float*)d_in[10];
  const float* w_o = (const float*)d_in[11];
  const float* q_norm_w = (const float*)d_in[12];
  const float* k_norm_w = (const float*)d_in[13];

  float* out0 = (float*)d_out;
  float* attn = out0 + (size_t)S * Hdim;

  char* base = (char*)d_ws;
  size_t off = 0;
  auto carve = [&](size_t bytes) -> void* {
    void* p = base + off;
    off += (bytes + 255) & ~(size_t)255;
    return p;
  };
  bf16* Xb      = (bf16*)carve((size_t)S * Hdim * 2);
  bf16* wt_down = (bf16*)carve((size_t)2176 * 2048 * 2);  // [2112(+pad)][2048]
  bf16* wt_up1  = (bf16*)carve((size_t)3072 * QC * 2);    // [3072][1536]
  bf16* wt_up2  = (bf16*)carve((size_t)1024 * KVC * 2);   // [1024][512]
  bf16* wt_o    = (bf16*)carve((size_t)Hdim * Hdim * 2);
  float* dproj  = (float*)carve((size_t)S * DN * 4);      // [2048][2112]
  bf16* cqb     = (bf16*)carve((size_t)S * QC * 2);
  bf16* ckvb    = (bf16*)carve((size_t)S * KVC * 2);
  bf16* up1     = (bf16*)carve((size_t)S * 3072 * 2);     // [s][qc 0:2048 | qr 2048:3072]
  bf16* up2     = (bf16*)carve((size_t)S * 1024 * 2);     // [s][kc 0:512 | v 512:1024]
  bf16* qpack   = (bf16*)carve((size_t)NH * S * QKD * 2);
  bf16* kpack   = (bf16*)carve((size_t)NKV * S * QKD * 2);
  bf16* vt      = (bf16*)carve((size_t)NKV * HD * S * 2);
  bf16* ctxb    = (bf16*)carve((size_t)S * Hdim * 2);
  (void)in_sizes; (void)n_in; (void)out_size; (void)ws_size;

  TJobs J;
  const float* srcs[8] = {w_down_q, w_down_kv, w_kr, w_up_q, w_qr, w_up_k, w_up_v, w_o};
  bf16* dsts[8] = {wt_down, wt_down + (size_t)QC * 2048, wt_down + (size_t)2048 * 2048,
                   wt_up1, wt_up1 + (size_t)2048 * QC, wt_up2, wt_up2 + (size_t)512 * KVC, wt_o};
  int Rs[8] = {2048, 2048, 2048, 1536, 1536, 512, 512, 2048};
  int Cs[8] = {1536, 512, 64, 2048, 1024, 512, 512, 2048};
  int total_tiles = 0;
  for (int j = 0; j < 8; j++) {
    J.src[j] = srcs[j]; J.dst[j] = dsts[j]; J.R[j] = Rs[j]; J.C[j] = Cs[j];
    J.tiles[j] = (Rs[j] / 32) * (Cs[j] / 32);
    total_tiles += J.tiles[j];
  }

  // 1. prep: X cast + all weight transposes
  prep<<<2048 + total_tiles, 256, 0, stream>>>(Xf, Xb, J);
  // 2. merged down projection: [S][2112] = Xb @ [wdq | wdkv | wkr]
  gemm_nt<float><<<dim3(17, 16), 256, 0, stream>>>(Xb, wt_down, dproj, DN, Hdim, Hdim, Hdim, DN, 1.f);
  // 3. both RMSNorms
  rmsnorm_fused<<<dim3(S, 2), 256, 0, stream>>>(dproj, q_norm_w, k_norm_w, cqb, ckvb);
  // 4. both up projections
  gemm_up_both<<<512, 256, 0, stream>>>(cqb, ckvb, wt_up1, wt_up2, up1, up2);
  // 5. pack q/k + RoPE + V transpose
  pack_all<<<4672, 256, 0, stream>>>(up1, up2, dproj, cosp, sinp, qpack, kpack, vt);
  // 6. fused flash attention (deep-pipelined: Q-in-regs, deferred PV, 1 barrier/tile)
  fa_fused<<<dim3(16, NH), 512, 0, stream>>>(qpack, kpack, vt, attn, ctxb);
  // 7. output projection
  gemm_nt<float><<<dim3(16, 16), 256, 0, stream>>>(ctxb, wt_o, out0, Hdim, Hdim, Hdim, Hdim, Hdim, 1.f);
}

// Round 20
// 285.368 us; speedup vs baseline: 1.2141x; 1.0174x over previous
//
#include <hip/hip_runtime.h>
#include <stdint.h>

typedef __bf16 bf16;
typedef __bf16 bf16x8 __attribute__((ext_vector_type(8)));
typedef __bf16 bf16x4 __attribute__((ext_vector_type(4)));
typedef float f32x4 __attribute__((ext_vector_type(4)));

#define DEVFN static __device__ __forceinline__

constexpr int S = 2048, Hdim = 2048, NH = 16, NKV = 4, HD = 128, RHD = 64, QC = 1536, KVC = 512;
constexpr int QKD = HD + RHD;                 // 192
constexpr int DN = 2112;                      // merged down-proj width: QC + KVC + RHD
constexpr float RMS_EPS = 1e-6f;
constexpr float ATT_SCALE = 0.07216878364870323f;  // 1/sqrt(192)

// ---------------- reductions ----------------
DEVFN float wave_sum(float v) {
#pragma unroll
  for (int o = 32; o > 0; o >>= 1) v += __shfl_xor(v, o, 64);
  return v;
}
DEVFN float block_sum(float v) {
  __shared__ float red_s[4];
  v = wave_sum(v);
  int lane = threadIdx.x & 63, wid = threadIdx.x >> 6;
  if (lane == 0) red_s[wid] = v;
  __syncthreads();
  v = red_s[0] + red_s[1] + red_s[2] + red_s[3];
  __syncthreads();
  return v;
}

DEVFN void lgkm_barrier() {
  asm volatile("s_waitcnt lgkmcnt(0)" ::: "memory");
  __builtin_amdgcn_s_barrier();
}

// ---------------- pipelined GEMM core: C = A[M,K] * Bt[N,K]^T ----------------
// 128x128 tile, BK=32, 4 waves 2x2. Reg-staged DEPTH-2 prefetch: loads for
// step t+2 issue at step t, LDS double-buffered, ONE lgkm barrier per step.
template <typename OT>
DEVFN void gemm_core_pipe(const bf16* __restrict__ A, const bf16* __restrict__ Bt,
                          OT* __restrict__ C, int N, int lda, int ldb, int ldc,
                          int m0, int n0, float scale, int kend) {
  __shared__ alignas(16) bf16 As[2][128 * 32];
  __shared__ alignas(16) bf16 Bs[2][128 * 32];
  const int t = threadIdx.x;
  const int lane = t & 63;
  const int wm = ((t >> 7) & 1) * 64;
  const int wn = ((t >> 6) & 1) * 64;
  const int lr = lane & 15;
  const int lk = (lane >> 4) * 8;
  const int srow = t >> 2;
  const int scol = (t & 3) * 8;
  const bf16* A0 = A + (size_t)(m0 + srow) * lda + scol;
  const bf16* A1 = A + (size_t)(m0 + 64 + srow) * lda + scol;
  const bf16* B0 = Bt + (size_t)(n0 + srow) * ldb + scol;
  const bf16* B1 = Bt + (size_t)(n0 + 64 + srow) * ldb + scol;

  f32x4 acc[4][4];
#pragma unroll
  for (int i = 0; i < 4; i++)
#pragma unroll
    for (int j = 0; j < 4; j++) { f32x4 z = {0.f, 0.f, 0.f, 0.f}; acc[i][j] = z; }

  // depth-2 prologue: steps 0 and 1 in flight
  bf16x8 ca0 = *reinterpret_cast<const bf16x8*>(A0);
  bf16x8 ca1 = *reinterpret_cast<const bf16x8*>(A1);
  bf16x8 cb0 = *reinterpret_cast<const bf16x8*>(B0);
  bf16x8 cb1 = *reinterpret_cast<const bf16x8*>(B1);
  bf16x8 ma0, ma1, mb0, mb1;
  if (32 < kend) {
    ma0 = *reinterpret_cast<const bf16x8*>(A0 + 32);
    ma1 = *reinterpret_cast<const bf16x8*>(A1 + 32);
    mb0 = *reinterpret_cast<const bf16x8*>(B0 + 32);
    mb1 = *reinterpret_cast<const bf16x8*>(B1 + 32);
  }
  int cur = 0;
  for (int kk = 0; kk < kend; kk += 32) {
    bf16x8 na0, na1, nb0, nb1;
    if (kk + 64 < kend) {  // issue loads for step t+2 before this step's stores
      na0 = *reinterpret_cast<const bf16x8*>(A0 + kk + 64);
      na1 = *reinterpret_cast<const bf16x8*>(A1 + kk + 64);
      nb0 = *reinterpret_cast<const bf16x8*>(B0 + kk + 64);
      nb1 = *reinterpret_cast<const bf16x8*>(B1 + kk + 64);
    }
    *reinterpret_cast<bf16x8*>(&As[cur][t * 8]) = ca0;
    *reinterpret_cast<bf16x8*>(&As[cur][t * 8 + 2048]) = ca1;
    *reinterpret_cast<bf16x8*>(&Bs[cur][t * 8]) = cb0;
    *reinterpret_cast<bf16x8*>(&Bs[cur][t * 8 + 2048]) = cb1;
    lgkm_barrier();
    bf16x8 a[4], b[4];
#pragma unroll
    for (int i = 0; i < 4; i++)
      a[i] = *reinterpret_cast<const bf16x8*>(&As[cur][(wm + i * 16 + lr) * 32 + lk]);
#pragma unroll
    for (int i = 0; i < 4; i++)
      b[i] = *reinterpret_cast<const bf16x8*>(&Bs[cur][(wn + i * 16 + lr) * 32 + lk]);
    __builtin_amdgcn_s_setprio(1);
#pragma unroll
    for (int i = 0; i < 4; i++)
#pragma unroll
      for (int j = 0; j < 4; j++)
        acc[i][j] = __builtin_amdgcn_mfma_f32_16x16x32_bf16(a[i], b[j], acc[i][j], 0, 0, 0);
    __builtin_amdgcn_s_setprio(0);
    ca0 = ma0; ca1 = ma1; cb0 = mb0; cb1 = mb1;
    ma0 = na0; ma1 = na1; mb0 = nb0; mb1 = nb1;
    cur ^= 1;
  }
  const int orow = (lane >> 4) * 4;
#pragma unroll
  for (int i = 0; i < 4; i++) {
#pragma unroll
    for (int j = 0; j < 4; j++) {
      int col = n0 + wn + j * 16 + lr;
      if (col < N) {
#pragma unroll
        for (int q = 0; q < 4; q++) {
          int row = m0 + wm + i * 16 + orow + q;
          C[(size_t)row * ldc + col] = (OT)(acc[i][j][q] * scale);
        }
      }
    }
  }
}

template <typename OT>
__global__ __launch_bounds__(256) void gemm_nt(const bf16* __restrict__ A, const bf16* __restrict__ Bt,
                                               OT* __restrict__ C, int N, int K, int lda,
                                               int ldb, int ldc, float scale) {
  gemm_core_pipe<OT>(A, Bt, C, N, lda, ldb, ldc, blockIdx.y * 128, blockIdx.x * 128, scale, K);
}

// up1 (384 blocks) + up2 (128 blocks) in one launch
__global__ __launch_bounds__(256) void gemm_up_both(const bf16* __restrict__ cqb,
                                                    const bf16* __restrict__ ckvb,
                                                    const bf16* __restrict__ wt_up1,
                                                    const bf16* __restrict__ wt_up2,
                                                    bf16* __restrict__ up1,
                                                    bf16* __restrict__ up2) {
  int id = blockIdx.x;
  if (id < 384) {
    gemm_core_pipe<bf16>(cqb, wt_up1, up1, 3072, QC, QC, 3072, (id / 24) * 128, (id % 24) * 128, 1.f, QC);
  } else {
    id -= 384;
    gemm_core_pipe<bf16>(ckvb, wt_up2, up2, 1024, KVC, KVC, 1024, (id / 8) * 128, (id % 8) * 128, 1.f, KVC);
  }
}

// ============== Fused flash attention, deep-pipelined, DEPTH-2 prefetch =====
// Grid (16, NH), 512 threads (8 waves: 4 row-groups x 2 k-halves).
// Block = balanced strip pair (64*i rows and 1984-64*i), 33 k-tiles total.
// Q fragments in REGISTERS; K double-buffered, V/Ps TRIPLE-buffered.
// DEPTH-2 reg prefetch: loads for tile t+2 issue at tile t (covers ~2x the
// latency of depth-1). Deferred PV -> ONE lgkm barrier per tile. attn stores
// never drained at barriers.
__global__ __launch_bounds__(512) void fa_fused(const bf16* __restrict__ qpack,
                                                const bf16* __restrict__ kpack,
                                                const bf16* __restrict__ vt,
                                                float* __restrict__ attn,
                                                bf16* __restrict__ ctxb) {
  const int h = blockIdx.y;
  const int g = h >> 2;
  __shared__ alignas(16) bf16 Ks[2][64 * 200];
  __shared__ alignas(16) bf16 Vs[3][128 * 72];
  __shared__ alignas(16) bf16 Ps[3][64 * 72];
  float2* sb = reinterpret_cast<float2*>(&Vs[0][0]);   // [0..127] per-half merge
  float2* statf = sb + 128;                            // [0..63] final (m, 1/l)

  const int t = threadIdx.x;
  const int lane = t & 63;
  const int w = t >> 6;
  const int wm = (w & 3) * 16;     // row-group base within strip
  const int kh = w >> 2;           // k-half (QK) / d-half (PV)
  const int lr = lane & 15;
  const int hi = lane >> 4;
  const int lk = hi * 8;
  const int kr0 = t / 24, kc0 = (t % 24) * 8;
  const int kr1 = (t + 512) / 24, kc1 = ((t + 512) % 24) * 8;
  const int kr2 = (t + 1024) / 24, kc2 = ((t + 1024) % 24) * 8;
  const int vr0 = t >> 3, vc0 = (t & 7) * 8;
  const int vr1 = (t + 512) >> 3, vc1 = ((t + 512) & 7) * 8;

  const bf16* Qg = qpack + (size_t)h * S * QKD;
  const bf16* Kg = kpack + (size_t)g * S * QKD;
  const bf16* Vg = vt + (size_t)g * HD * S;
  float* Ah = attn + (size_t)h * S * S;
  bf16* C = ctxb + h * HD;

  for (int sub = 0; sub < 2; ++sub) {
    const int m0 = sub ? (1984 - 64 * blockIdx.x) : (64 * blockIdx.x);
    const int ntiles = sub ? (32 - blockIdx.x) : (blockIdx.x + 1);
    const int kend = m0 + 64;
    __syncthreads();  // prev sub's LDS reads done

    // Q fragments -> registers (once per strip)
    bf16x8 qf[6];
#pragma unroll
    for (int ks = 0; ks < 6; ++ks)
      qf[ks] = *reinterpret_cast<const bf16x8*>(&Qg[(size_t)(m0 + wm + lr) * QKD + ks * 32 + lk]);

    // ---------- loop 1: stats (depth-2 K prefetch) ----------
    float mreg[4] = {-1e30f, -1e30f, -1e30f, -1e30f};
    float lreg[4] = {0.f, 0.f, 0.f, 0.f};
    bf16x8 ck0 = *reinterpret_cast<const bf16x8*>(&Kg[(size_t)kr0 * QKD + kc0]);
    bf16x8 ck1 = *reinterpret_cast<const bf16x8*>(&Kg[(size_t)kr1 * QKD + kc1]);
    bf16x8 ck2 = *reinterpret_cast<const bf16x8*>(&Kg[(size_t)kr2 * QKD + kc2]);
    bf16x8 mk0, mk1, mk2;
    if (1 < ntiles) {
      mk0 = *reinterpret_cast<const bf16x8*>(&Kg[(size_t)(64 + kr0) * QKD + kc0]);
      mk1 = *reinterpret_cast<const bf16x8*>(&Kg[(size_t)(64 + kr1) * QKD + kc1]);
      mk2 = *reinterpret_cast<const bf16x8*>(&Kg[(size_t)(64 + kr2) * QKD + kc2]);
    }
    int cur = 0;
    for (int ti = 0; ti < ntiles; ++ti) {
      bf16x8 nk0, nk1, nk2;
      if (ti + 2 < ntiles) {  // loads for tile t+2
        const int kt2 = (ti + 2) * 64;
        nk0 = *reinterpret_cast<const bf16x8*>(&Kg[(size_t)(kt2 + kr0) * QKD + kc0]);
        nk1 = *reinterpret_cast<const bf16x8*>(&Kg[(size_t)(kt2 + kr1) * QKD + kc1]);
        nk2 = *reinterpret_cast<const bf16x8*>(&Kg[(size_t)(kt2 + kr2) * QKD + kc2]);
      }
      *reinterpret_cast<bf16x8*>(&Ks[cur][kr0 * 200 + kc0]) = ck0;
      *reinterpret_cast<bf16x8*>(&Ks[cur][kr1 * 200 + kc1]) = ck1;
      *reinterpret_cast<bf16x8*>(&Ks[cur][kr2 * 200 + kc2]) = ck2;
      lgkm_barrier();
      f32x4 acc[2];
#pragma unroll
      for (int kb = 0; kb < 2; kb++) { f32x4 z = {0.f, 0.f, 0.f, 0.f}; acc[kb] = z; }
      __builtin_amdgcn_s_setprio(1);
#pragma unroll
      for (int ks = 0; ks < 6; ++ks) {
#pragma unroll
        for (int kb = 0; kb < 2; ++kb) {
          bf16x8 b = *reinterpret_cast<const bf16x8*>(&Ks[cur][(kh * 32 + kb * 16 + lr) * 200 + ks * 32 + lk]);
          acc[kb] = __builtin_amdgcn_mfma_f32_16x16x32_bf16(qf[ks], b, acc[kb], 0, 0, 0);
        }
      }
      __builtin_amdgcn_s_setprio(0);
      const int colb = ti * 64 + kh * 32 + lr;
#pragma unroll
      for (int q = 0; q < 4; ++q) {
        const int rowg = m0 + wm + hi * 4 + q;
        bool u0 = (colb <= rowg), u1 = (colb + 16 <= rowg);
        float s0 = u0 ? acc[0][q] * ATT_SCALE : -1e30f;
        float s1 = u1 ? acc[1][q] * ATT_SCALE : -1e30f;
        float nm = fmaxf(mreg[q], fmaxf(s0, s1));
        float e0 = u0 ? __expf(s0 - nm) : 0.f;
        float e1 = u1 ? __expf(s1 - nm) : 0.f;
        lreg[q] = lreg[q] * __expf(mreg[q] - nm) + e0 + e1;
        mreg[q] = nm;
      }
      ck0 = mk0; ck1 = mk1; ck2 = mk2;
      mk0 = nk0; mk1 = nk1; mk2 = nk2;
      cur ^= 1;
    }
    // cross-lane merge over lane bits 0-3 (cols)
#pragma unroll
    for (int q = 0; q < 4; ++q) {
      float m = mreg[q], l = lreg[q];
#pragma unroll
      for (int o = 1; o < 16; o <<= 1) {
        float mo = __shfl_xor(m, o, 64);
        float lo = __shfl_xor(l, o, 64);
        float M = fmaxf(m, mo);
        l = l * __expf(m - M) + lo * __expf(mo - M);
        m = M;
      }
      mreg[q] = m; lreg[q] = l;
    }
    __syncthreads();  // last tile's Ks reads done; Vs[0] alias safe to write
    if (lr == 0) {
#pragma unroll
      for (int q = 0; q < 4; ++q)
        sb[kh * 64 + wm + hi * 4 + q] = make_float2(mreg[q], lreg[q]);
    }
    __syncthreads();
    if (w < 4 && lr == 0) {
#pragma unroll
      for (int q = 0; q < 4; ++q) {
        int r = wm + hi * 4 + q;
        float2 a = sb[r], b = sb[64 + r];
        float M = fmaxf(a.x, b.x);
        float L = a.y * __expf(a.x - M) + b.y * __expf(b.x - M);
        statf[r] = make_float2(M, 1.0f / L);
      }
    }
    __syncthreads();
    float mr[4], invl[4];
#pragma unroll
    for (int q = 0; q < 4; ++q) {
      float2 sv = statf[wm + hi * 4 + q];
      mr[q] = sv.x; invl[q] = sv.y;
    }
    __syncthreads();  // stats in regs; Vs[0] free for loop 2

    // ---------- loop 2: normalize + attn write + deferred PV (depth-2) -----
    f32x4 accp[4];
#pragma unroll
    for (int j = 0; j < 4; j++) { f32x4 z = {0.f, 0.f, 0.f, 0.f}; accp[j] = z; }
    ck0 = *reinterpret_cast<const bf16x8*>(&Kg[(size_t)kr0 * QKD + kc0]);
    ck1 = *reinterpret_cast<const bf16x8*>(&Kg[(size_t)kr1 * QKD + kc1]);
    ck2 = *reinterpret_cast<const bf16x8*>(&Kg[(size_t)kr2 * QKD + kc2]);
    bf16x8 cv0 = *reinterpret_cast<const bf16x8*>(&Vg[(size_t)vr0 * S + vc0]);
    bf16x8 cv1 = *reinterpret_cast<const bf16x8*>(&Vg[(size_t)vr1 * S + vc1]);
    bf16x8 mv0, mv1;
    if (1 < ntiles) {
      mk0 = *reinterpret_cast<const bf16x8*>(&Kg[(size_t)(64 + kr0) * QKD + kc0]);
      mk1 = *reinterpret_cast<const bf16x8*>(&Kg[(size_t)(64 + kr1) * QKD + kc1]);
      mk2 = *reinterpret_cast<const bf16x8*>(&Kg[(size_t)(64 + kr2) * QKD + kc2]);
      mv0 = *reinterpret_cast<const bf16x8*>(&Vg[(size_t)vr0 * S + 64 + vc0]);
      mv1 = *reinterpret_cast<const bf16x8*>(&Vg[(size_t)vr1 * S + 64 + vc1]);
    }
    cur = 0;
    int pb = 0;  // triple-buffer index = ti % 3
    for (int ti = 0; ti < ntiles; ++ti) {
      bf16x8 nk0, nk1, nk2, nv0, nv1;
      if (ti + 2 < ntiles) {  // loads for tile t+2, issued before stores
        const int kt2 = (ti + 2) * 64;
        nk0 = *reinterpret_cast<const bf16x8*>(&Kg[(size_t)(kt2 + kr0) * QKD + kc0]);
        nk1 = *reinterpret_cast<const bf16x8*>(&Kg[(size_t)(kt2 + kr1) * QKD + kc1]);
        nk2 = *reinterpret_cast<const bf16x8*>(&Kg[(size_t)(kt2 + kr2) * QKD + kc2]);
        nv0 = *reinterpret_cast<const bf16x8*>(&Vg[(size_t)vr0 * S + kt2 + vc0]);
        nv1 = *reinterpret_cast<const bf16x8*>(&Vg[(size_t)vr1 * S + kt2 + vc1]);
      }
      *reinterpret_cast<bf16x8*>(&Ks[cur][kr0 * 200 + kc0]) = ck0;
      *reinterpret_cast<bf16x8*>(&Ks[cur][kr1 * 200 + kc1]) = ck1;
      *reinterpret_cast<bf16x8*>(&Ks[cur][kr2 * 200 + kc2]) = ck2;
      *reinterpret_cast<bf16x8*>(&Vs[pb][vr0 * 72 + vc0]) = cv0;
      *reinterpret_cast<bf16x8*>(&Vs[pb][vr1 * 72 + vc1]) = cv1;
      lgkm_barrier();  // K, V(pb) visible; Ps(prev) visible
      f32x4 acc[2];
#pragma unroll
      for (int kb = 0; kb < 2; kb++) { f32x4 z = {0.f, 0.f, 0.f, 0.f}; acc[kb] = z; }
      __builtin_amdgcn_s_setprio(1);
#pragma unroll
      for (int ks = 0; ks < 6; ++ks) {
#pragma unroll
        for (int kb = 0; kb < 2; ++kb) {
          bf16x8 b = *reinterpret_cast<const bf16x8*>(&Ks[cur][(kh * 32 + kb * 16 + lr) * 200 + ks * 32 + lk]);
          acc[kb] = __builtin_amdgcn_mfma_f32_16x16x32_bf16(qf[ks], b, acc[kb], 0, 0, 0);
        }
      }
      __builtin_amdgcn_s_setprio(0);
      const int colb = ti * 64 + kh * 32 + lr;
#pragma unroll
      for (int kb = 0; kb < 2; ++kb) {
#pragma unroll
        for (int q = 0; q < 4; ++q) {
          const int rloc = wm + hi * 4 + q;
          const int rowg = m0 + rloc;
          const int col = colb + kb * 16;
          float s = acc[kb][q] * ATT_SCALE;
          float p = (col <= rowg) ? __expf(s - mr[q]) * invl[q] : 0.f;
          Ah[(size_t)rowg * S + col] = p;
          Ps[pb][rloc * 72 + kh * 32 + kb * 16 + lr] = (bf16)p;
        }
      }
      if (ti > 0) {  // deferred PV for tile ti-1
        const int pp = (pb == 0) ? 2 : pb - 1;
        __builtin_amdgcn_s_setprio(1);
#pragma unroll
        for (int ks = 0; ks < 2; ++ks) {
          bf16x8 a = *reinterpret_cast<const bf16x8*>(&Ps[pp][(wm + lr) * 72 + ks * 32 + lk]);
#pragma unroll
          for (int j = 0; j < 4; ++j) {
            bf16x8 b = *reinterpret_cast<const bf16x8*>(&Vs[pp][(kh * 64 + j * 16 + lr) * 72 + ks * 32 + lk]);
            accp[j] = __builtin_amdgcn_mfma_f32_16x16x32_bf16(a, b, accp[j], 0, 0, 0);
          }
        }
        __builtin_amdgcn_s_setprio(0);
      }
      ck0 = mk0; ck1 = mk1; ck2 = mk2; cv0 = mv0; cv1 = mv1;
      mk0 = nk0; mk1 = nk1; mk2 = nk2; mv0 = nv0; mv1 = nv1;
      cur ^= 1;
      pb = (pb == 2) ? 0 : pb + 1;
    }
    // epilogue: PV for the last tile
    lgkm_barrier();
    {
      const int pp = (pb == 0) ? 2 : pb - 1;
#pragma unroll
      for (int ks = 0; ks < 2; ++ks) {
        bf16x8 a = *reinterpret_cast<const bf16x8*>(&Ps[pp][(wm + lr) * 72 + ks * 32 + lk]);
#pragma unroll
        for (int j = 0; j < 4; ++j) {
          bf16x8 b = *reinterpret_cast<const bf16x8*>(&Vs[pp][(kh * 64 + j * 16 + lr) * 72 + ks * 32 + lk]);
          accp[j] = __builtin_amdgcn_mfma_f32_16x16x32_bf16(a, b, accp[j], 0, 0, 0);
        }
      }
    }

    // zero-fill causal tail [kend, S) for the strip's 64 rows
    const float4 zz = make_float4(0.f, 0.f, 0.f, 0.f);
    {
      const int zr = t >> 3, zc0 = (t & 7) * 4;
      float* zrow = Ah + (size_t)(m0 + zr) * S;
      for (int k = kend + zc0; k < S; k += 32) *reinterpret_cast<float4*>(zrow + k) = zz;
    }

    // ctx epilogue: wave's 16 rows x 64-d half
#pragma unroll
    for (int j = 0; j < 4; ++j) {
      const int d = kh * 64 + j * 16 + lr;
#pragma unroll
      for (int q = 0; q < 4; ++q) {
        const int rowg = m0 + wm + hi * 4 + q;
        C[(size_t)rowg * Hdim + d] = (bf16)accp[j][q];
      }
    }
  }
}

// ---------------- fused prep: X cast + 8 weight transposes ----------------
struct TJobs {
  const float* src[8];
  bf16* dst[8];
  int R[8], C[8], tiles[8];
};

__global__ __launch_bounds__(256) void prep(const float* __restrict__ Xf,
                                            bf16* __restrict__ Xb, TJobs J) {
  const int t = threadIdx.x;
  int id = blockIdx.x;
  if (id < 2048) {  // cast: 2048 blocks x 256 threads x 8 elems = S*Hdim
    size_t i = (size_t)id * 256 + t;
    float4 f0 = *reinterpret_cast<const float4*>(Xf + i * 8);
    float4 f1 = *reinterpret_cast<const float4*>(Xf + i * 8 + 4);
    bf16x8 v;
    v[0] = (bf16)f0.x; v[1] = (bf16)f0.y; v[2] = (bf16)f0.z; v[3] = (bf16)f0.w;
    v[4] = (bf16)f1.x; v[5] = (bf16)f1.y; v[6] = (bf16)f1.z; v[7] = (bf16)f1.w;
    *reinterpret_cast<bf16x8*>(Xb + i * 8) = v;
    return;
  }
  int tile = id - 2048;
  int j = 0;
  while (tile >= J.tiles[j]) { tile -= J.tiles[j]; ++j; }
  const int C = J.C[j], R = J.R[j];
  int tcn = C >> 5;
  int rb = (tile / tcn) * 32, cb = (tile % tcn) * 32;
  const float* in = J.src[j];
  bf16* out = J.dst[j];
  __shared__ float tl[32][33];
  int tx = t & 31, ty = t >> 5;
#pragma unroll
  for (int q = 0; q < 32; q += 8)
    tl[ty + q][tx] = in[(size_t)(rb + ty + q) * C + cb + tx];
  __syncthreads();
#pragma unroll
  for (int q = 0; q < 32; q += 8)
    out[(size_t)(cb + ty + q) * R + rb + tx] = (bf16)tl[tx][ty + q];
}

// fused RMSNorm for cq (y==0) and ckv (y==1) reading merged dproj
__global__ __launch_bounds__(256) void rmsnorm_fused(const float* __restrict__ dproj,
                                                     const float* __restrict__ qw,
                                                     const float* __restrict__ kw,
                                                     bf16* __restrict__ cqb,
                                                     bf16* __restrict__ ckvb) {
  int row = blockIdx.x;
  bool isq = (blockIdx.y == 0);
  int C = isq ? QC : KVC;
  const float* p = dproj + (size_t)row * DN + (isq ? 0 : QC);
  const float* w = isq ? qw : kw;
  bf16* out = (isq ? cqb : ckvb) + (size_t)row * C;
  float ss = 0.f;
  for (int i = threadIdx.x * 4; i < C; i += 1024) {
    float4 v = *reinterpret_cast<const float4*>(p + i);
    ss += v.x * v.x + v.y * v.y + v.z * v.z + v.w * v.w;
  }
  ss = block_sum(ss);
  float r = rsqrtf(ss / (float)C + RMS_EPS);
  for (int i = threadIdx.x * 4; i < C; i += 1024) {
    float4 v = *reinterpret_cast<const float4*>(p + i);
    float4 g = *reinterpret_cast<const float4*>(w + i);
    bf16x4 o;
    o[0] = (bf16)(v.x * r * g.x); o[1] = (bf16)(v.y * r * g.y);
    o[2] = (bf16)(v.z * r * g.z); o[3] = (bf16)(v.w * r * g.w);
    *reinterpret_cast<bf16x4*>(out + i) = o;
  }
}

// ---------------- fused pack: qpack + kpack + V transpose ----------------
// blocks [0,3072): build_qpack; [3072,3648): build_kpack; [3648,4672): vt
__global__ __launch_bounds__(256) void pack_all(const bf16* __restrict__ up1,
                                                const bf16* __restrict__ up2,
                                                const float* __restrict__ dproj,
                                                const float* __restrict__ cosp,
                                                const float* __restrict__ sinp,
                                                bf16* __restrict__ qpack,
                                                bf16* __restrict__ kpack,
                                                bf16* __restrict__ vt) {
  const int t = threadIdx.x;
  int id = blockIdx.x;
  if (id < 3072) {  // ---- qpack ----
    int idx = id * 256 + t;
    const int P = NH * S * 16;
    if (idx < P) {
      int d8 = idx & 15, s = (idx >> 4) & (S - 1), h = idx >> 15;
      int4 v = *reinterpret_cast<const int4*>(up1 + (size_t)s * 3072 + h * HD + d8 * 8);
      *reinterpret_cast<int4*>(qpack + ((size_t)h * S + s) * QKD + d8 * 8) = v;
    } else {
      int j = idx - P;
      int d0 = (j & 7) * 8, s = (j >> 3) & (S - 1), h = j >> 14;
      const bf16* xr = up1 + (size_t)s * 3072 + 2048 + h * RHD;
      bf16x8 xa = *reinterpret_cast<const bf16x8*>(xr + d0);
      bf16x8 xb = *reinterpret_cast<const bf16x8*>(xr + (d0 ^ 32));
      float sign = (d0 < 32) ? -1.f : 1.f;
      const float* cr = cosp + s * RHD + d0;
      const float* sr = sinp + s * RHD + d0;
      bf16x8 o;
#pragma unroll
      for (int i = 0; i < 8; i++)
        o[i] = (bf16)((float)xa[i] * cr[i] + sign * (float)xb[i] * sr[i]);
      *reinterpret_cast<bf16x8*>(qpack + ((size_t)h * S + s) * QKD + HD + d0) = o;
    }
    return;
  }
  if (id < 3648) {  // ---- kpack ----
    int idx = (id - 3072) * 256 + t;
    const int P = NKV * S * 16;
    if (idx < P) {
      int d8 = idx & 15, s = (idx >> 4) & (S - 1), g = idx >> 15;
      int4 v = *reinterpret_cast<const int4*>(up2 + (size_t)s * 1024 + g * HD + d8 * 8);
      *reinterpret_cast<int4*>(kpack + ((size_t)g * S + s) * QKD + d8 * 8) = v;
    } else {
      int j = idx - P;
      int d0 = (j & 7) * 8, s = j >> 3;
      const float* xr = dproj + (size_t)s * DN + 2048;
      float4 a0 = *reinterpret_cast<const float4*>(xr + d0);
      float4 a1 = *reinterpret_cast<const float4*>(xr + d0 + 4);
      float4 b0 = *reinterpret_cast<const float4*>(xr + (d0 ^ 32));
      float4 b1 = *reinterpret_cast<const float4*>(xr + (d0 ^ 32) + 4);
      float sign = (d0 < 32) ? -1.f : 1.f;
      const float* cr = cosp + s * RHD + d0;
      const float* sr = sinp + s * RHD + d0;
      float xa[8] = {a0.x, a0.y, a0.z, a0.w, a1.x, a1.y, a1.z, a1.w};
      float xb[8] = {b0.x, b0.y, b0.z, b0.w, b1.x, b1.y, b1.z, b1.w};
      bf16x8 o;
#pragma unroll
      for (int i = 0; i < 8; i++)
        o[i] = (bf16)(xa[i] * cr[i] + sign * xb[i] * sr[i]);
#pragma unroll
      for (int g = 0; g < NKV; g++)
        *reinterpret_cast<bf16x8*>(kpack + ((size_t)g * S + s) * QKD + HD + d0) = o;
    }
    return;
  }
  // ---- V transpose: up2[s][512+c] -> vt[c][s], tiles 16 x 64 ----
  int tile = id - 3648;
  int cb = (tile & 15) * 32;   // source col block (0..511)
  int rb = (tile >> 4) * 32;   // source row block (0..2047)
  __shared__ float tl[32][33];
  int tx = t & 31, ty = t >> 5;
  const bf16* in = up2 + 512;
#pragma unroll
  for (int q = 0; q < 32; q += 8)
    tl[ty + q][tx] = (float)in[(size_t)(rb + ty + q) * 1024 + cb + tx];
  __syncthreads();
#pragma unroll
  for (int q = 0; q < 32; q += 8)
    vt[(size_t)(cb + ty + q) * S + rb + tx] = (bf16)tl[tx][ty + q];
}

// ---------------- launcher ----------------
extern "C" void kernel_launch(void* const* d_in, const int* in_sizes, int n_in, void* d_out,
                              int out_size, void* d_ws, size_t ws_size, hipStream_t stream) {
  const float* Xf = (const float*)d_in[0];
  const float* cosp = (const float*)d_in[1];
  const float* sinp = (const float*)d_in[2];
  const float* w_down_q = (const float*)d_in[4];
  const float* w_up_q = (const float*)d_in[5];
  const float* w_qr = (const float*)d_in[6];
  const float* w_down_kv = (const float*)d_in[7];
  const float* w_up_k = (const float*)d_in[8];
  const float* w_up_v = (const float*)d_in[9];
  const float* w_kr = (const float*)d_in[10];
  const float* w_o = (const float*)d_in[11];
  const float* q_norm_w = (const float*)d_in[12];
  const float* k_norm_w = (const float*)d_in[13];

  float* out0 = (float*)d_out;
  float* attn = out0 + (size_t)S * Hdim;

  char* base = (char*)d_ws;
  size_t off = 0;
  auto carve = [&](size_t bytes) -> void* {
    void* p = base + off;
    off += (bytes + 255) & ~(size_t)255;
    return p;
  };
  bf16* Xb      = (bf16*)carve((size_t)S * Hdim * 2);
  bf16* wt_down = (bf16*)carve((size_t)2176 * 2048 * 2);  // [2112(+pad)][2048]
  bf16* wt_up1  = (bf16*)carve((size_t)3072 * QC * 2);    // [3072][1536]
  bf16* wt_up2  = (bf16*)carve((size_t)1024 * KVC * 2);   // [1024][512]
  bf16* wt_o    = (bf16*)carve((size_t)Hdim * Hdim * 2);
  float* dproj  = (float*)carve((size_t)S * DN * 4);      // [2048][2112]
  bf16* cqb     = (bf16*)carve((size_t)S * QC * 2);
  bf16* ckvb    = (bf16*)carve((size_t)S * KVC * 2);
  bf16* up1     = (bf16*)carve((size_t)S * 3072 * 2);     // [s][qc 0:2048 | qr 2048:3072]
  bf16* up2     = (bf16*)carve((size_t)S * 1024 * 2);     // [s][kc 0:512 | v 512:1024]
  bf16* qpack   = (bf16*)carve((size_t)NH * S * QKD * 2);
  bf16* kpack   = (bf16*)carve((size_t)NKV * S * QKD * 2);
  bf16* vt      = (bf16*)carve((size_t)NKV * HD * S * 2);
  bf16* ctxb    = (bf16*)carve((size_t)S * Hdim * 2);
  (void)in_sizes; (void)n_in; (void)out_size; (void)ws_size;

  TJobs J;
  const float* srcs[8] = {w_down_q, w_down_kv, w_kr, w_up_q, w_qr, w_up_k, w_up_v, w_o};
  bf16* dsts[8] = {wt_down, wt_down + (size_t)QC * 2048, wt_down + (size_t)2048 * 2048,
                   wt_up1, wt_up1 + (size_t)2048 * QC, wt_up2, wt_up2 + (size_t)512 * KVC, wt_o};
  int Rs[8] = {2048, 2048, 2048, 1536, 1536, 512, 512, 2048};
  int Cs[8] = {1536, 512, 64, 2048, 1024, 512, 512, 2048};
  int total_tiles = 0;
  for (int j = 0; j < 8; j++) {
    J.src[j] = srcs[j]; J.dst[j] = dsts[j]; J.R[j] = Rs[j]; J.C[j] = Cs[j];
    J.tiles[j] = (Rs[j] / 32) * (Cs[j] / 32);
    total_tiles += J.tiles[j];
  }

  // 1. prep: X cast + all weight transposes
  prep<<<2048 + total_tiles, 256, 0, stream>>>(Xf, Xb, J);
  // 2. merged down projection: [S][2112] = Xb @ [wdq | wdkv | wkr]
  gemm_nt<float><<<dim3(17, 16), 256, 0, stream>>>(Xb, wt_down, dproj, DN, Hdim, Hdim, Hdim, DN, 1.f);
  // 3. both RMSNorms
  rmsnorm_fused<<<dim3(S, 2), 256, 0, stream>>>(dproj, q_norm_w, k_norm_w, cqb, ckvb);
  // 4. both up projections
  gemm_up_both<<<512, 256, 0, stream>>>(cqb, ckvb, wt_up1, wt_up2, up1, up2);
  // 5. pack q/k + RoPE + V transpose
  pack_all<<<4672, 256, 0, stream>>>(up1, up2, dproj, cosp, sinp, qpack, kpack, vt);
  // 6. fused flash attention (depth-2 prefetch, deferred PV, 1 barrier/tile)
  fa_fused<<<dim3(16, NH), 512, 0, stream>>>(qpack, kpack, vt, attn, ctxb);
  // 7. output projection
  gemm_nt<float><<<dim3(16, 16), 256, 0, stream>>>(ctxb, wt_o, out0, Hdim, Hdim, Hdim, Hdim, Hdim, 1.f);
}